// Round 8
// baseline (523.186 us; speedup 1.0000x reference)
//
#include <hip/hip_runtime.h>
#include <hip/hip_bf16.h>
#include <math.h>
#include <stdint.h>

// Problem constants
#define BB 2
#define TT 2048
#define DD 1024
#define HH 16
#define DK 64
#define HD 1024   // H*DK
#define NC 32     // chunks per sequence (TT/64)
#define CL 64     // chunk length
#define PAD 68    // padded LDS row stride (floats)
#define PADA 67   // A_s row stride (R16)
#define VS 16     // v-splits in hrec_k

typedef short bf16x8 __attribute__((ext_vector_type(8)));     // 8 bf16 (4 VGPRs)
typedef float f32x4 __attribute__((ext_vector_type(4)));      // MFMA acc
typedef unsigned short u16x8 __attribute__((ext_vector_type(8)));
typedef unsigned short u16x4 __attribute__((ext_vector_type(4)));

#define GAS __attribute__((address_space(1)))
#define LAS __attribute__((address_space(3)))

#define DOT4(a, b) ((a).x*(b).x + (a).y*(b).y + (a).z*(b).z + (a).w*(b).w)

// acc[i][j] += kf[i-component] * wv[j-component]   (one contraction step)
#define OUT16(acc, kf, wv) \
    acc[0][0] += kf.x * wv.x; acc[0][1] += kf.x * wv.y; acc[0][2] += kf.x * wv.z; acc[0][3] += kf.x * wv.w; \
    acc[1][0] += kf.y * wv.x; acc[1][1] += kf.y * wv.y; acc[1][2] += kf.y * wv.z; acc[1][3] += kf.y * wv.w; \
    acc[2][0] += kf.z * wv.x; acc[2][1] += kf.z * wv.y; acc[2][2] += kf.z * wv.z; acc[2][3] += kf.z * wv.w; \
    acc[3][0] += kf.w * wv.x; acc[3][1] += kf.w * wv.y; acc[3][2] += kf.w * wv.z; acc[3][3] += kf.w * wv.w;

// acc[i][j] -= wa_i.c * hv[j]   (c = component selecting m)
#define WSUB(c, hv) \
    acc[0][0] -= wa0.c * hv.x; acc[0][1] -= wa0.c * hv.y; acc[0][2] -= wa0.c * hv.z; acc[0][3] -= wa0.c * hv.w; \
    acc[1][0] -= wa1.c * hv.x; acc[1][1] -= wa1.c * hv.y; acc[1][2] -= wa1.c * hv.z; acc[1][3] -= wa1.c * hv.w; \
    acc[2][0] -= wa2.c * hv.x; acc[2][1] -= wa2.c * hv.y; acc[2][2] -= wa2.c * hv.z; acc[2][3] -= wa2.c * hv.w; \
    acc[3][0] -= wa3.c * hv.x; acc[3][1] -= wa3.c * hv.y; acc[3][2] -= wa3.c * hv.z; acc[3][3] -= wa3.c * hv.w;

// acc[i][j] += sa_i.c * wv[j]   (c = component selecting the contraction idx)
#define ACC16(c, wv) \
    acc[0][0] += sa0.c * wv.x; acc[0][1] += sa0.c * wv.y; acc[0][2] += sa0.c * wv.z; acc[0][3] += sa0.c * wv.w; \
    acc[1][0] += sa1.c * wv.x; acc[1][1] += sa1.c * wv.y; acc[1][2] += sa1.c * wv.z; acc[1][3] += sa1.c * wv.w; \
    acc[2][0] += sa2.c * wv.x; acc[2][1] += sa2.c * wv.y; acc[2][2] += sa2.c * wv.z; acc[2][3] += sa2.c * wv.w; \
    acc[3][0] += sa3.c * wv.x; acc[3][1] += sa3.c * wv.y; acc[3][2] += sa3.c * wv.z; acc[3][3] += sa3.c * wv.w;

__device__ __forceinline__ float sigmoidf_(float x) { return 1.0f / (1.0f + expf(-x)); }
__device__ __forceinline__ float siluf_(float x) { return x * sigmoidf_(x); }

// round-to-nearest-even fp32 -> bf16
__device__ __forceinline__ unsigned short f2bf(float f) {
    unsigned int u = __builtin_bit_cast(unsigned int, f);
    u = (u + 0x7fffu + ((u >> 16) & 1u)) >> 16;
    return (unsigned short)u;
}

// ---------------------------------------------------------------------------
// Cast x (fp32) -> bf16, flat.
// ---------------------------------------------------------------------------
__global__ __launch_bounds__(256) void castx_k(const float* __restrict__ src,
                                               unsigned short* __restrict__ dst) {
    const size_t idx = (size_t)blockIdx.x * 256 + threadIdx.x;
    float4 a = *(const float4*)&src[idx * 8];
    float4 b = *(const float4*)&src[idx * 8 + 4];
    u16x8 o;
    o[0] = f2bf(a.x); o[1] = f2bf(a.y); o[2] = f2bf(a.z); o[3] = f2bf(a.w);
    o[4] = f2bf(b.x); o[5] = f2bf(b.y); o[6] = f2bf(b.z); o[7] = f2bf(b.w);
    *(u16x8*)&dst[idx * 8] = o;
}

// ---------------------------------------------------------------------------
// Transpose+cast weight: W[K=1024][N=1024] fp32 -> Wt[N][K] bf16.
// ---------------------------------------------------------------------------
__global__ __launch_bounds__(256) void castw_k(const float* __restrict__ W,
                                               unsigned short* __restrict__ Wt) {
    __shared__ float t_s[64][65];
    const int tid = threadIdx.x;
    const int rr = tid >> 4;
    const int cc = tid & 15;
    const int r0 = blockIdx.y * 64;
    const int c0 = blockIdx.x * 64;
#pragma unroll
    for (int i = 0; i < 4; ++i) {
        const int row = rr + i * 16;
        float4 v = *(const float4*)&W[(size_t)(r0 + row) * 1024 + c0 + cc * 4];
        t_s[row][cc * 4 + 0] = v.x;
        t_s[row][cc * 4 + 1] = v.y;
        t_s[row][cc * 4 + 2] = v.z;
        t_s[row][cc * 4 + 3] = v.w;
    }
    __syncthreads();
#pragma unroll
    for (int i = 0; i < 4; ++i) {
        const int nr = rr + i * 16;
        u16x4 o;
#pragma unroll
        for (int d = 0; d < 4; ++d) o[d] = f2bf(t_s[cc * 4 + d][nr]);
        *(u16x4*)&Wt[(size_t)(c0 + nr) * 1024 + r0 + cc * 4] = o;
    }
}

// ---------------------------------------------------------------------------
// transpose Wa|Wb [1024][16] -> Wab_t [32][1024] fp32 (R8)
// ---------------------------------------------------------------------------
__global__ __launch_bounds__(256) void tw_k(const float* __restrict__ Wa,
                                            const float* __restrict__ Wb,
                                            float* __restrict__ Wt) {
    const int o = blockIdx.x;          // 0..31
    const int h = o & 15;
    const float* W = (o < 16) ? Wa : Wb;
    const int tid = threadIdx.x;
    float4 v;
    v.x = W[(size_t)(tid * 4 + 0) * HH + h];
    v.y = W[(size_t)(tid * 4 + 1) * HH + h];
    v.z = W[(size_t)(tid * 4 + 2) * HH + h];
    v.w = W[(size_t)(tid * 4 + 3) * HH + h];
    *(float4*)&Wt[(size_t)o * DD + tid * 4] = v;
}

// ---------------------------------------------------------------------------
// bf16 MFMA GEMM (m97 structure) — generic single-output (used for Wo).
// ---------------------------------------------------------------------------
__global__ __launch_bounds__(256) void gemm_bf16_k(const unsigned short* __restrict__ A,
                                                   const unsigned short* __restrict__ Bt,
                                                   float* __restrict__ C,
                                                   int M, int N, int Kd) {
    __shared__ unsigned short a_s[128 * 32];
    __shared__ unsigned short b_s[128 * 32];

    const int tid = threadIdx.x;
    const int wave = tid >> 6;
    const int lane = tid & 63;
    const int m0 = blockIdx.y * 128;
    const int n0 = blockIdx.x * 128;

    const int quad = lane >> 4;
    const int l16 = lane & 15;
    const int wr = wave >> 1;
    const int wc = wave & 1;

    const int srow = lane >> 2;
    const int sseg = lane & 3;

    f32x4 acc[4][4];
#pragma unroll
    for (int i = 0; i < 4; ++i)
#pragma unroll
        for (int j = 0; j < 4; ++j) acc[i][j] = (f32x4){0.f, 0.f, 0.f, 0.f};

    for (int k0 = 0; k0 < Kd; k0 += 32) {
        __syncthreads();
#pragma unroll
        for (int c = 0; c < 2; ++c) {
            const int region = wave * 2 + c;
            const int r0t = region * 16;
            const int ra = r0t + srow;
            const unsigned short* ga = A + (size_t)(m0 + ra) * Kd + k0 + sseg * 8;
            const unsigned short* gb = Bt + (size_t)(n0 + ra) * Kd + k0 + sseg * 8;
            __builtin_amdgcn_global_load_lds((const GAS unsigned int*)ga,
                                             (LAS unsigned int*)&a_s[r0t * 32], 16, 0, 0);
            __builtin_amdgcn_global_load_lds((const GAS unsigned int*)gb,
                                             (LAS unsigned int*)&b_s[r0t * 32], 16, 0, 0);
        }
        __syncthreads();

        bf16x8 af[4], bfr[4];
#pragma unroll
        for (int i = 0; i < 4; ++i)
            af[i] = *(const bf16x8*)&a_s[(wr * 64 + i * 16 + l16) * 32 + quad * 8];
#pragma unroll
        for (int j = 0; j < 4; ++j)
            bfr[j] = *(const bf16x8*)&b_s[(wc * 64 + j * 16 + l16) * 32 + quad * 8];
#pragma unroll
        for (int i = 0; i < 4; ++i)
#pragma unroll
            for (int j = 0; j < 4; ++j)
                acc[i][j] = __builtin_amdgcn_mfma_f32_16x16x32_bf16(af[i], bfr[j], acc[i][j], 0, 0, 0);
    }

#pragma unroll
    for (int i = 0; i < 4; ++i)
#pragma unroll
        for (int j = 0; j < 4; ++j) {
            const int col = n0 + wc * 64 + j * 16 + l16;
#pragma unroll
            for (int r = 0; r < 4; ++r) {
                const int row = m0 + wr * 64 + i * 16 + quad * 4 + r;
                C[(size_t)row * N + col] = acc[i][j][r];
            }
        }
}

// ---------------------------------------------------------------------------
// Fused QKVG projection GEMM — R13 structure (unchanged): 256x256 tile,
// 8 waves, BK=64, swizzled LDS, counted vmcnt/lgkmcnt, setprio.
// ---------------------------------------------------------------------------
#define DSRQ(D, P, OFF) asm volatile("ds_read_b128 %0, %1 offset:" OFF \
                                     : "=v"(D) : "v"(P))

__global__ __launch_bounds__(512, 2) void gemm_qkvg_k(const unsigned short* __restrict__ A,
                                                      const unsigned short* __restrict__ Bt,
                                                      float* __restrict__ Oq,
                                                      float* __restrict__ Ok,
                                                      float* __restrict__ Ov,
                                                      float* __restrict__ Og) {
    __shared__ __align__(16) unsigned char lds_all[131072];   // 128 KiB

    const int tid = threadIdx.x;
    const int w = tid >> 6;           // wave 0..7
    const int lane = tid & 63;
    const int l16 = lane & 15;
    const int quad = lane >> 4;
    const int wr = w >> 2;            // 0..1 : 128-row half
    const int wc = w & 3;             // 0..3 : 64-col quarter

    // XCD-aware block swizzle (bijective: 256 % 8 == 0)
    const int bid = blockIdx.x;
    const int wg = (bid & 7) * 32 + (bid >> 3);
    const int m0 = (wg >> 4) * 256;
    const int n0 = (wg & 15) * 256;

    // staging: lane (lr,ls) sources the PRE-SWIZZLED slot ls^lr so the
    // swizzled read finds logical data (rule #21).
    const int lr = lane >> 3;
    const int ls = lane & 7;
    const int sslot = ls ^ lr;
    const unsigned short* srcA = A + (size_t)(m0 + lr) * DD + sslot * 8 + (size_t)w * 8 * DD;
    const unsigned short* srcB = Bt + (size_t)(n0 + lr) * DD + sslot * 8 + (size_t)w * 8 * DD;

    const LAS unsigned char* LB = (const LAS unsigned char*)&lds_all[0];

    // swizzled read base (buf0, ksub0); ^64 toggles ksub, +32768 toggles buf
    const unsigned int xq = (unsigned int)((quad ^ (l16 & 7)) << 4);
    const unsigned int uA0 = (unsigned int)((wr * 128 + l16) * 128) + xq;
    const unsigned int uB0 = 65536u + (unsigned int)((wc * 64 + l16) * 128) + xq;

    f32x4 acc[8][4];
#pragma unroll
    for (int i = 0; i < 8; ++i)
#pragma unroll
        for (int j = 0; j < 4; ++j) acc[i][j] = (f32x4){0.f, 0.f, 0.f, 0.f};

#define STG1Q(T, IA) \
    __builtin_amdgcn_global_load_lds( \
        (const GAS unsigned int*)(srcA + (size_t)(IA) * 65536 + (size_t)(T) * 64), \
        (LAS unsigned int*)(LB + (((unsigned)((T) & 1)) << 15) + ((IA) * 8 + w) * 1024), 16, 0, 0); \
    __builtin_amdgcn_global_load_lds( \
        (const GAS unsigned int*)(srcB + (size_t)(IA) * 65536 + (size_t)(T) * 64), \
        (LAS unsigned int*)(LB + 65536u + (((unsigned)((T) & 1)) << 15) + ((IA) * 8 + w) * 1024), 16, 0, 0);
#define STGQ(T) { STG1Q(T, 0) STG1Q(T, 1) STG1Q(T, 2) STG1Q(T, 3) }

    STGQ(0);                           // prologue: stage K-step 0 into buf0

    bf16x8 aG0[4], aG1[4], b0[4], b1[4];

#pragma unroll 1
    for (int t = 0; t < 16; ++t) {
        if (t + 1 < 16) {
            STGQ(t + 1);               // 8 loads for next K-step -> other buf
            asm volatile("s_waitcnt vmcnt(8)" ::: "memory");   // stage(t) done
        } else {
            asm volatile("s_waitcnt vmcnt(0)" ::: "memory");
        }
        __builtin_amdgcn_s_barrier();  // buf(t&1) staged by ALL waves

        const unsigned int boff = ((unsigned)(t & 1)) << 15;
        const LAS unsigned char* pA0 = LB + (uA0 + boff);
        const LAS unsigned char* pA1 = LB + ((uA0 ^ 64u) + boff);
        const LAS unsigned char* pB0 = LB + (uB0 + boff);
        const LAS unsigned char* pB1 = LB + ((uB0 ^ 64u) + boff);

        // issue 16 reads: b0, aG0(k0), aG1(k0), b1
        DSRQ(b0[0], pB0, "0");    DSRQ(b0[1], pB0, "2048");
        DSRQ(b0[2], pB0, "4096"); DSRQ(b0[3], pB0, "6144");
        DSRQ(aG0[0], pA0, "0");    DSRQ(aG0[1], pA0, "2048");
        DSRQ(aG0[2], pA0, "4096"); DSRQ(aG0[3], pA0, "6144");
        DSRQ(aG1[0], pA0, "8192");  DSRQ(aG1[1], pA0, "10240");
        DSRQ(aG1[2], pA0, "12288"); DSRQ(aG1[3], pA0, "14336");
        DSRQ(b1[0], pB1, "0");    DSRQ(b1[1], pB1, "2048");
        DSRQ(b1[2], pB1, "4096"); DSRQ(b1[3], pB1, "6144");

        asm volatile("s_waitcnt lgkmcnt(8)" ::: "memory");   // b0,aG0 ready
        __builtin_amdgcn_sched_barrier(0);
        __builtin_amdgcn_s_setprio(1);
#pragma unroll
        for (int ia = 0; ia < 4; ++ia)
#pragma unroll
            for (int j = 0; j < 4; ++j)
                acc[ia][j] = __builtin_amdgcn_mfma_f32_16x16x32_bf16(aG0[ia], b0[j], acc[ia][j], 0, 0, 0);
        __builtin_amdgcn_s_setprio(0);

        DSRQ(aG0[0], pA1, "0");    DSRQ(aG0[1], pA1, "2048");   // aG0 <- ksub1
        DSRQ(aG0[2], pA1, "4096"); DSRQ(aG0[3], pA1, "6144");
        asm volatile("s_waitcnt lgkmcnt(4)" ::: "memory");   // aG1(k0),b1 ready
        __builtin_amdgcn_sched_barrier(0);
        __builtin_amdgcn_s_setprio(1);
#pragma unroll
        for (int ia = 0; ia < 4; ++ia)
#pragma unroll
            for (int j = 0; j < 4; ++j)
                acc[4 + ia][j] = __builtin_amdgcn_mfma_f32_16x16x32_bf16(aG1[ia], b0[j], acc[4 + ia][j], 0, 0, 0);
        __builtin_amdgcn_s_setprio(0);

        DSRQ(aG1[0], pA1, "8192");  DSRQ(aG1[1], pA1, "10240"); // aG1 <- ksub1
        DSRQ(aG1[2], pA1, "12288"); DSRQ(aG1[3], pA1, "14336");
        asm volatile("s_waitcnt lgkmcnt(4)" ::: "memory");   // aG0(k1) ready
        __builtin_amdgcn_sched_barrier(0);
        __builtin_amdgcn_s_setprio(1);
#pragma unroll
        for (int ia = 0; ia < 4; ++ia)
#pragma unroll
            for (int j = 0; j < 4; ++j)
                acc[ia][j] = __builtin_amdgcn_mfma_f32_16x16x32_bf16(aG0[ia], b1[j], acc[ia][j], 0, 0, 0);
        __builtin_amdgcn_s_setprio(0);

        asm volatile("s_waitcnt lgkmcnt(0)" ::: "memory");   // aG1(k1) ready
        __builtin_amdgcn_sched_barrier(0);
        __builtin_amdgcn_s_setprio(1);
#pragma unroll
        for (int ia = 0; ia < 4; ++ia)
#pragma unroll
            for (int j = 0; j < 4; ++j)
                acc[4 + ia][j] = __builtin_amdgcn_mfma_f32_16x16x32_bf16(aG1[ia], b1[j], acc[4 + ia][j], 0, 0, 0);
        __builtin_amdgcn_s_setprio(0);

        __builtin_amdgcn_s_barrier();  // all reads of buf(t&1) done before
                                       // next iteration overwrites it
    }
#undef STGQ
#undef STG1Q

    float* Cd = (n0 < 1024) ? Oq : (n0 < 2048) ? Ok : (n0 < 3072) ? Ov : Og;
    const int nl = n0 & 1023;
    const int rbase = m0 + wr * 128 + quad * 4;
    const int cbase = nl + wc * 64 + l16;
#pragma unroll
    for (int ia = 0; ia < 8; ++ia)
#pragma unroll
        for (int j = 0; j < 4; ++j) {
            const int col = cbase + j * 16;
#pragma unroll
            for (int r = 0; r < 4; ++r)
                Cd[(size_t)(rbase + ia * 16 + r) * HD + col] = acc[ia][j][r];
        }
}

// ---------------------------------------------------------------------------
// g / beta kernel (R8, unchanged)
// ---------------------------------------------------------------------------
__global__ __launch_bounds__(256) void gbeta_k(const float* __restrict__ x,
                                               const float* __restrict__ Wt,
                                               const float* __restrict__ A_log,
                                               const float* __restrict__ dt_bias,
                                               float* __restrict__ g,
                                               float* __restrict__ beta) {
    __shared__ __align__(16) float xs[8][DD];
    const int r0 = blockIdx.x * 8;
    const int tid = threadIdx.x;

#pragma unroll
    for (int i = 0; i < 8; ++i) {
        const int f = tid + i * 256;
        const int r = f >> 8;
        const int col = (f & 255) * 4;
        *(float4*)&xs[r][col] = *(const float4*)&x[((size_t)r0 + r) * DD + col];
    }
    __syncthreads();

    const int out = tid >> 3;
    const int part = tid & 7;
    const int h = out & 15;
    const float* Wrow = Wt + (size_t)out * DD;

    float a0 = 0, a1 = 0, a2 = 0, a3 = 0, a4 = 0, a5 = 0, a6 = 0, a7 = 0;
#pragma unroll 4
    for (int i = 0; i < 32; ++i) {
        const int d = i * 32 + part * 4;
        const float4 wv = *(const float4*)&Wrow[d];
        float4 x0 = *(const float4*)&xs[0][d];
        float4 x1 = *(const float4*)&xs[1][d];
        float4 x2 = *(const float4*)&xs[2][d];
        float4 x3 = *(const float4*)&xs[3][d];
        float4 x4 = *(const float4*)&xs[4][d];
        float4 x5 = *(const float4*)&xs[5][d];
        float4 x6 = *(const float4*)&xs[6][d];
        float4 x7 = *(const float4*)&xs[7][d];
        a0 += DOT4(x0, wv); a1 += DOT4(x1, wv);
        a2 += DOT4(x2, wv); a3 += DOT4(x3, wv);
        a4 += DOT4(x4, wv); a5 += DOT4(x5, wv);
        a6 += DOT4(x6, wv); a7 += DOT4(x7, wv);
    }
#pragma unroll
    for (int s = 1; s <= 4; s <<= 1) {
        a0 += __shfl_xor(a0, s); a1 += __shfl_xor(a1, s);
        a2 += __shfl_xor(a2, s); a3 += __shfl_xor(a3, s);
        a4 += __shfl_xor(a4, s); a5 += __shfl_xor(a5, s);
        a6 += __shfl_xor(a6, s); a7 += __shfl_xor(a7, s);
    }

    if (part == 0) {
        float sv[8] = {a0, a1, a2, a3, a4, a5, a6, a7};
        if (out < 16) {
            const float ae = -expf(A_log[h]);
            const float db = dt_bias[h];
#pragma unroll
            for (int r = 0; r < 8; ++r) {
                float v = sv[r] + db;
                float sp = (v > 20.0f) ? v : log1pf(expf(v));
                g[((size_t)r0 + r) * HH + h] = ae * sp;
            }
        } else {
#pragma unroll
            for (int r = 0; r < 8; ++r)
                beta[((size_t)r0 + r) * HH + h] = sigmoidf_(sv[r]);
        }
    }
}

// ---------------------------------------------------------------------------
// Phase A1: stage normalized q,k (conv+silu+l2norm) and cumsum(g). (unchanged)
// ---------------------------------------------------------------------------
__global__ __launch_bounds__(64) void stage_k(const float* __restrict__ q_pre,
                                              const float* __restrict__ k_pre,
                                              const float* __restrict__ cq,
                                              const float* __restrict__ ck,
                                              const float* __restrict__ g,
                                              float* __restrict__ Qc,
                                              float* __restrict__ Kc,
                                              float* __restrict__ bcum) {
    const int blk = blockIdx.x;
    const int bh = blk >> 5;
    const int c = blk & 31;
    const int b = bh >> 4;
    const int h = bh & 15;
    const int lane = threadIdx.x;
    const int ch = h * DK + lane;

    const float4 wq4 = *(const float4*)&cq[ch * 4];
    const float4 wk4 = *(const float4*)&ck[ch * 4];

    float qw0 = 0, qw1 = 0, qw2 = 0, kw0 = 0, kw1 = 0, kw2 = 0;
    {
        const int t0 = c * CL;
        if (t0 - 3 >= 0) { size_t bi = ((size_t)b * TT + t0 - 3) * HD + ch; qw0 = q_pre[bi]; kw0 = k_pre[bi]; }
        if (t0 - 2 >= 0) { size_t bi = ((size_t)b * TT + t0 - 2) * HD + ch; qw1 = q_pre[bi]; kw1 = k_pre[bi]; }
        if (t0 - 1 >= 0) { size_t bi = ((size_t)b * TT + t0 - 1) * HD + ch; qw2 = q_pre[bi]; kw2 = k_pre[bi]; }
    }
    float* Qo = Qc + (size_t)blk * 4096;
    float* Ko = Kc + (size_t)blk * 4096;

    for (int tt = 0; tt < CL; ++tt) {
        const int t = c * CL + tt;
        const size_t bi = ((size_t)b * TT + t) * HD + ch;
        const float qc_ = q_pre[bi];
        const float kc_ = k_pre[bi];
        float qa = qw0 * wq4.x + qw1 * wq4.y + qw2 * wq4.z + qc_ * wq4.w;
        float ka = kw0 * wk4.x + kw1 * wk4.y + kw2 * wk4.z + kc_ * wk4.w;
        qw0 = qw1; qw1 = qw2; qw2 = qc_;
        kw0 = kw1; kw1 = kw2; kw2 = kc_;
        qa = siluf_(qa);
        ka = siluf_(ka);
        float qs2 = qa * qa, ks2 = ka * ka;
#pragma unroll
        for (int s = 32; s > 0; s >>= 1) {
            qs2 += __shfl_xor(qs2, s);
            ks2 += __shfl_xor(ks2, s);
        }
        Qo[tt * 64 + lane] = qa * rsqrtf(qs2 + 1e-6f) * 0.125f;
        Ko[tt * 64 + lane] = ka * rsqrtf(ks2 + 1e-6f);
    }

    float cum = g[((size_t)b * TT + c * CL + lane) * HH + h];
#pragma unroll
    for (int s = 1; s < 64; s <<= 1) {
        float u = __shfl_up(cum, s);
        if (lane >= s) cum += u;
    }
    bcum[(size_t)blk * 64 + lane] = cum;
}

// ---------------------------------------------------------------------------
// Phase A2 (R18): triangular solve + fused ab, now at 512 THREADS.
// R17 post-mortem: VALUBusy 46.8% at 8 waves/CU — prep is VALU-throughput
// bound. Same LDS (2 blocks/CU) but 8 waves/block halves each data-parallel
// phase's serial length: QK^T 4x2 tiles/thread, apply 4 cols/thread,
// ab tail split aA (waves 0-3) / aB (waves 4-7) — wave-uniform, no
// divergence. Per-element FP expression order identical -> bit-identical.
// ---------------------------------------------------------------------------
__global__ __launch_bounds__(512) void prep_k(const float* __restrict__ Kc,
                                              const float* __restrict__ v_pre,
                                              const float* __restrict__ cv,
                                              const float* __restrict__ bcum,
                                              const float* __restrict__ bbuf,
                                              float* __restrict__ Wv,
                                              float* __restrict__ Wk,
                                              float* __restrict__ Ab,
                                              float* __restrict__ Bb) {
    __shared__ __align__(16) float k_s[CL * PAD];
    __shared__ __align__(16) float wv_s[CL * PAD];
    __shared__ __align__(16) float wk_s[CL * PAD];
    __shared__ __align__(16) float A_s[CL * PADA];
    __shared__ float T_s[4][16 * 17];
    __shared__ float b_s[CL], beta_s[CL], bk_s[CL], e_s[CL];

    const int blk = blockIdx.x;
    const int bh = blk >> 5;
    const int c = blk & 31;
    const int b = bh >> 4;
    const int h = bh & 15;
    const int tid = threadIdx.x;

    if (tid < 64) {
        float bv = bcum[(size_t)blk * 64 + tid];
        float bC = bcum[(size_t)blk * 64 + 63];
        float be = bbuf[((size_t)b * TT + c * CL + tid) * HH + h];
        b_s[tid] = bv;
        beta_s[tid] = be;
        bk_s[tid] = be * __expf(bv);
        e_s[tid] = __expf(bC - bv);
    }
    __syncthreads();

    {
        const float4* Kg = (const float4*)(Kc + (size_t)blk * 4096);
#pragma unroll
        for (int i = 0; i < 2; ++i) {
            int f = tid + i * 512;
            int t = f >> 4;
            int c4 = f & 15;
            int d = t * PAD + c4 * 4;                        // wk_s: plain
            int dsz = t * PAD + ((c4 ^ (t >> 2)) << 2);      // k_s: swizzled
            float4 kv = Kg[f];
            *(float4*)&k_s[dsz] = kv;
            float sk = bk_s[t];
            *(float4*)&wk_s[d] = make_float4(kv.x * sk, kv.y * sk, kv.z * sk, kv.w * sk);
        }
    }

    {
        const int lane = tid & 63;
        const int q8 = tid >> 6;          // 0..7 groups of 8 timesteps
        const int ch = h * DK + lane;
        const float4 wv4 = *(const float4*)&cv[ch * 4];
        const int T0 = c * CL + q8 * 8;
        float w0 = 0, w1 = 0, w2 = 0;
        if (T0 - 3 >= 0) w0 = v_pre[((size_t)b * TT + T0 - 3) * HD + ch];
        if (T0 - 2 >= 0) w1 = v_pre[((size_t)b * TT + T0 - 2) * HD + ch];
        if (T0 - 1 >= 0) w2 = v_pre[((size_t)b * TT + T0 - 1) * HD + ch];
#pragma unroll 1
        for (int i = 0; i < 8; ++i) {
            const int t = T0 + i;
            const float vc_ = v_pre[((size_t)b * TT + t) * HD + ch];
            float va = w0 * wv4.x + w1 * wv4.y + w2 * wv4.z + vc_ * wv4.w;
            w0 = w1; w1 = w2; w2 = vc_;
            va = siluf_(va);
            wv_s[(q8 * 8 + i) * PAD + lane] = va * beta_s[q8 * 8 + i];
        }
    }
    __syncthreads();

    // QK^T: 4x2 output tiles per thread (512 threads cover 64x64)
    {
        const int qrow = tid >> 5;          // 0..15 (row chunk)
        const int qc2 = tid & 31;           // 0..31 (2-col group)
        const int t0 = qrow * 4, s0 = qc2 * 2;
        const int scnk = qc2 >> 1;          // row-chunk of rows s0,s0+1
        float acc[4][2] = {};
        for (int kk = 0; kk < 64; kk += 4) {
            const int ka = ((kk >> 2) ^ qrow) << 2;
            const int kb = ((kk >> 2) ^ scnk) << 2;
            float4 ta0 = *(const float4*)&k_s[(t0 + 0) * PAD + ka];
            float4 ta1 = *(const float4*)&k_s[(t0 + 1) * PAD + ka];
            float4 ta2 = *(const float4*)&k_s[(t0 + 2) * PAD + ka];
            float4 ta3 = *(const float4*)&k_s[(t0 + 3) * PAD + ka];
            float4 sb0 = *(const float4*)&k_s[(s0 + 0) * PAD + kb];
            float4 sb1 = *(const float4*)&k_s[(s0 + 1) * PAD + kb];
            acc[0][0] += DOT4(ta0, sb0); acc[0][1] += DOT4(ta0, sb1);
            acc[1][0] += DOT4(ta1, sb0); acc[1][1] += DOT4(ta1, sb1);
            acc[2][0] += DOT4(ta2, sb0); acc[2][1] += DOT4(ta2, sb1);
            acc[3][0] += DOT4(ta3, sb0); acc[3][1] += DOT4(ta3, sb1);
        }
        __syncthreads();
#pragma unroll
        for (int i = 0; i < 4; ++i)
#pragma unroll
            for (int j = 0; j < 2; ++j) {
                const int t = t0 + i, s = s0 + j;
                A_s[t * PADA + s] = (s < t) ? acc[i][j] * beta_s[t] * __expf(b_s[t] - b_s[s]) : 0.0f;
            }
    }
    __syncthreads();

    if (tid < 64) {
        const int d = tid >> 4;
        const int col = tid & 15;
        const int base = d * 16;
        float tcol[16];
#pragma unroll
        for (int s = 0; s < 16; ++s) tcol[s] = (s == col) ? 1.0f : 0.0f;
#pragma unroll
        for (int t = 1; t < 16; ++t) {
            float a = 0.0f;
#pragma unroll
            for (int s = 0; s < 16; ++s)
                if (s < t) a += A_s[(base + t) * PADA + base + s] * tcol[s];
            tcol[t] -= a;
        }
#pragma unroll
        for (int t = 0; t < 16; ++t) T_s[d][t * 17 + col] = tcol[t];
    }
    __syncthreads();

    // blocked triangular apply: 4 columns per thread (32 col-groups)
    {
        const int r = tid >> 5;             // 0..15
        const int cg = tid & 31;            // 0..31
        float* Wc = (cg < 16) ? wv_s : wk_s;
        const int cc = (cg & 15) * 4;

        for (int tb = 0; tb < 4; ++tb) {
            const int t = tb * 16 + r;
            if (tb > 0) {
                float4 lo = *(const float4*)&Wc[t * PAD + cc];
#pragma unroll 4
                for (int s = 0; s < tb * 16; ++s) {
                    const float a = A_s[t * PADA + s];
                    float4 wlo = *(const float4*)&Wc[s * PAD + cc];
                    lo.x -= a * wlo.x; lo.y -= a * wlo.y; lo.z -= a * wlo.z; lo.w -= a * wlo.w;
                }
                *(float4*)&Wc[t * PAD + cc] = lo;
            }
            __syncthreads();
            float4 alo = make_float4(0, 0, 0, 0);
#pragma unroll 4
            for (int s = 0; s < 16; ++s) {
                const float tv = T_s[tb][r * 17 + s];
                float4 wlo = *(const float4*)&Wc[(tb * 16 + s) * PAD + cc];
                alo.x += tv * wlo.x; alo.y += tv * wlo.y; alo.z += tv * wlo.z; alo.w += tv * wlo.w;
            }
            __syncthreads();
            *(float4*)&Wc[t * PAD + cc] = alo;
            __syncthreads();
        }
    }

    // Wv/Wk writeback
    float4* Wvg = (float4*)(Wv + (size_t)blk * 4096);
    float4* Wkg = (float4*)(Wk + (size_t)blk * 4096);
#pragma unroll
    for (int i = 0; i < 2; ++i) {
        int f = tid + i * 512;
        int d = (f >> 4) * PAD + (f & 15) * 4;
        Wvg[f] = *(float4*)&wv_s[d];
        Wkg[f] = *(float4*)&wk_s[d];
    }

    // ---- fused ab (R18): waves 0-3 -> aA, waves 4-7 -> aB ----
    {
        const int t256 = tid & 255;
        const int isB = tid >> 8;            // wave-uniform half select
        const int k0q = t256 >> 4;           // col chunk 0..15
        const int k0 = k0q * 4;
        const int m0 = (t256 & 15) * 4;
        const int p = t256 & 15;             // panel index = m0>>2
        const float ebC = __expf(b_s[63]);
        const float* Wsrc = isB ? wv_s : wk_s;
        float a4[4][4] = {};
        for (int ss = 0; ss < 64; ss += 4) {
            float4 kf0 = *(const float4*)&k_s[(ss + 0) * PAD + ((((ss + 0) >> 2) ^ k0q) << 2)];
            float4 kf1 = *(const float4*)&k_s[(ss + 1) * PAD + ((((ss + 1) >> 2) ^ k0q) << 2)];
            float4 kf2 = *(const float4*)&k_s[(ss + 2) * PAD + ((((ss + 2) >> 2) ^ k0q) << 2)];
            float4 kf3 = *(const float4*)&k_s[(ss + 3) * PAD + ((((ss + 3) >> 2) ^ k0q) << 2)];
            const float e0 = e_s[ss + 0], e1 = e_s[ss + 1];
            const float e2 = e_s[ss + 2], e3 = e_s[ss + 3];
            kf0.x *= e0; kf0.y *= e0; kf0.z *= e0; kf0.w *= e0;
            kf1.x *= e1; kf1.y *= e1; kf1.z *= e1; kf1.w *= e1;
            kf2.x *= e2; kf2.y *= e2; kf2.z *= e2; kf2.w *= e2;
            kf3.x *= e3; kf3.y *= e3; kf3.z *= e3; kf3.w *= e3;
            float4 w0_ = *(const float4*)&Wsrc[(ss + 0) * PAD + m0];
            float4 w1_ = *(const float4*)&Wsrc[(ss + 1) * PAD + m0];
            float4 w2_ = *(const float4*)&Wsrc[(ss + 2) * PAD + m0];
            float4 w3_ = *(const float4*)&Wsrc[(ss + 3) * PAD + m0];
            OUT16(a4, kf0, w0_); OUT16(a4, kf1, w1_);
            OUT16(a4, kf2, w2_); OUT16(a4, kf3, w3_);
        }

        if (!isB) {
            float* Ag = Ab + (size_t)blk * 4096;
#pragma unroll
            for (int i = 0; i < 4; ++i) {
                const int kk = k0 + i;
                float4 av = make_float4(-a4[i][0], -a4[i][1], -a4[i][2], -a4[i][3]);
                if (kk - m0 == 0) av.x += ebC;
                if (kk - m0 == 1) av.y += ebC;
                if (kk - m0 == 2) av.z += ebC;
                if (kk - m0 == 3) av.w += ebC;
                *(float4*)&Ag[p * 256 + kk * 4] = av;   // panel-transposed
            }
        } else {
            float* Bg = Bb + (size_t)blk * 4096;
#pragma unroll
            for (int i = 0; i < 4; ++i) {
                const int kk = k0 + i;
                *(float4*)&Bg[kk * 64 + m0] =
                    make_float4(a4[i][0], a4[i][1], a4[i][2], a4[i][3]);
            }
        }
    }
}

// ---------------------------------------------------------------------------
// Phase B2 (R15): serial chunk recurrence h' = A_c h + B_c. (unchanged)
// ---------------------------------------------------------------------------
__global__ __launch_bounds__(64, 1) void hrec_k(const float* __restrict__ Ab,
                                                const float* __restrict__ Bb,
                                                float* __restrict__ Hst) {
    const int blk = blockIdx.x;
    const int bh = blk & 31;          // vs-major: same-bh blocks -> same XCD
    const int vs = blk >> 5;          // 0..VS-1
    const int k = threadIdx.x;

    __shared__ __align__(16) float A_lds[2][4096];
    __shared__ __align__(16) float h_s[4][64];

#pragma unroll
    for (int j = 0; j < 4; ++j) h_s[j][k] = 0.0f;
    float h0 = 0, h1 = 0, h2 = 0, h3 = 0;

    const float* Abase = Ab + (size_t)bh * NC * 4096;
    const float* Bbase = Bb + (size_t)bh * NC * 4096 + k * 64 + vs * 4;
    float* Hbase = Hst + (size_t)bh * NC * 4096 + k * 64 + vs * 4;

    // per-lane LDS read pointers (AS3, 32-bit)
    const LAS float* rd_cur = (const LAS float*)&A_lds[0][0] + k * 4;
    const LAS float* rd_nxt = (const LAS float*)&A_lds[1][0] + k * 4;
    const LAS float* hp = (const LAS float*)&h_s[0][0];   // uniform h base

    // prologue: stage A(0) into buf0, B(0) -> register
#pragma unroll
    for (int i = 0; i < 16; ++i)
        __builtin_amdgcn_global_load_lds((const GAS unsigned int*)(Abase + i * 256 + k * 4),
                                         (LAS unsigned int*)&A_lds[0][i * 256], 16, 0, 0);
    float4 bn = *(const float4*)&Bbase[0];

#define ARD(DST, OFF) asm volatile("ds_read_b128 %0, %1 offset:" OFF \
                                   : "=v"(DST) : "v"(rd_cur))
#define HRD(DST, OFF) asm volatile("ds_read_b128 %0, %1 offset:" OFF \
                                   : "=v"(DST) : "v"(hp) : "memory")
#define FMAG(AR, H0, H1, H2, H3) \
    a0 += AR[0]*H0[0] + AR[1]*H0[1] + AR[2]*H0[2] + AR[3]*H0[3]; \
    a1 += AR[0]*H1[0] + AR[1]*H1[1] + AR[2]*H1[2] + AR[3]*H1[3]; \
    a2 += AR[0]*H2[0] + AR[1]*H2[1] + AR[2]*H2[2] + AR[3]*H2[3]; \
    a3 += AR[0]*H3[0] + AR[1]*H3[1] + AR[2]*H3[2] + AR[3]*H3[3];
#define WAIT10 asm volatile("s_waitcnt lgkmcnt(10)" ::: "memory"); \
               __builtin_amdgcn_sched_barrier(0);

#pragma unroll 1
    for (int c = 0; c < NC; ++c) {
        float4 b0 = bn;

        // chunk-start state (pre-update); fire-and-forget store
        *(float4*)&Hbase[(size_t)c * 4096] = make_float4(h0, h1, h2, h3);

        if (c + 1 < NC) {
            const float* An = Abase + (size_t)(c + 1) * 4096;
#pragma unroll
            for (int i = 0; i < 16; ++i)
                __builtin_amdgcn_global_load_lds((const GAS unsigned int*)(An + i * 256 + k * 4),
                                                 (LAS unsigned int*)(rd_nxt - (size_t)k * 4 + i * 256),
                                                 16, 0, 0);
            bn = *(const float4*)&Bbase[(size_t)(c + 1) * 4096];
            // newest 18 (H-store + 16 A-lds + 1 B) stay in flight
            asm volatile("s_waitcnt vmcnt(18)" ::: "memory");
        } else {
            asm volatile("s_waitcnt vmcnt(1)" ::: "memory");
        }
        __builtin_amdgcn_sched_barrier(0);

        f32x4 ar0, ar1, ar2, ar3, ar4, ar5, ar6, ar7;
        f32x4 ar8, ar9, ar10, ar11, ar12, ar13, ar14, ar15;
        f32x4 ha0, ha1, ha2, ha3, ha4, ha5, ha6, ha7;   // bank A (even batch)
        f32x4 hb0, hb1, hb2, hb3, hb4, hb5, hb6, hb7;   // bank B (odd batch)

        // batch0 (m4 0,1) + ar0,ar1 ; batch1 (m4 2,3) + ar2,ar3  -> 20 out
        HRD(ha0, "0");   HRD(ha1, "256"); HRD(ha2, "512"); HRD(ha3, "768");
        HRD(ha4, "16");  HRD(ha5, "272"); HRD(ha6, "528"); HRD(ha7, "784");
        ARD(ar0, "0");   ARD(ar1, "1024");
        HRD(hb0, "32");  HRD(hb1, "288"); HRD(hb2, "544"); HRD(hb3, "800");
        HRD(hb4, "48");  HRD(hb5, "304"); HRD(hb6, "560"); HRD(hb7, "816");
        ARD(ar2, "2048"); ARD(ar3, "3072");
        WAIT10   // batch0 + ar0,ar1 done; batch1+ar2,ar3 in flight

        float a0 = b0.x, a1 = b0.y, a2 = b0.z, a3 = b0.w;
        // sub0: m4 0,1
        FMAG(ar0, ha0, ha1, ha2, ha3)
        FMAG(ar1, ha4, ha5, ha6, ha7)
        HRD(ha0, "64");  HRD(ha1, "320"); HRD(ha2, "576"); HRD(ha3, "832");
        HRD(ha4, "80");  HRD(ha5, "336"); HRD(ha6, "592"); HRD(ha7, "848");
        ARD(ar4, "4096"); ARD(ar5, "5120");
        WAIT10
        // sub1: m4 2,3
        FMAG(ar2, hb0, hb1, hb2, hb3)
        FMAG(ar3, hb4, hb5, hb6, hb7)
        HRD(hb0, "96");  HRD(hb1, "352"); HRD(hb2, "608"); HRD(hb3, "864");
        HRD(hb4, "112"); HRD(hb5, "368"); HRD(hb6, "624"); HRD(hb7, "880");
        ARD(ar6, "6144"); ARD(ar7, "7168");
        WAIT10
        // sub2: m4 4,5
        FMAG(ar4, ha0, ha1, ha2, ha3)
        FMAG(ar5, ha4, ha5, ha6, ha7)
        HRD(ha0, "128"); HRD(ha1, "384"); HRD(ha2, "640"); HRD(ha3, "896");
        HRD(ha4, "144"); HRD(ha5, "400"); HRD(ha6, "656"); HRD(ha7, "912");
        ARD(ar8, "8192"); ARD(ar9, "9216");
        WAIT10
        // sub3: m4 6,7
        FMAG(ar6, hb0, hb1, hb2, hb3)
        FMAG(ar7, hb4, hb5, hb6, hb7)
        HRD(hb0, "160"); HRD(hb1, "416"); HRD(hb2, "672"); HRD(hb3, "928");
        HRD(hb4, "176"); HRD(hb5, "432"); HRD(hb6, "688"); HRD(hb7, "944");
        ARD(ar10, "10240"); ARD(ar11, "11264");
        WAIT10
        // sub4: m4 8,9
        FMAG(ar8, ha0, ha1, ha2, ha3)
        FMAG(ar9, ha4, ha5, ha6, ha7)
        HRD(ha0, "192"); HRD(ha1, "448"); HRD(ha2, "704"); HRD(ha3, "960");
        HRD(ha4, "208"); HRD(ha5, "464"); HRD(ha6, "720"); HRD(ha7, "976");
        ARD(ar12, "12288"); ARD(ar13, "13312");
        WAIT10
        // sub5: m4 10,11
        FMAG(ar10, hb0, hb1, hb2, hb3)
        FMAG(ar11, hb4, hb5, hb6, hb7)
        HRD(hb0, "224"); HRD(hb1, "480"); HRD(hb2, "736"); HRD(hb3, "992");
        HRD(hb4, "240"); HRD(hb5, "496"); HRD(hb6, "752"); HRD(hb7, "1008");
        ARD(ar14, "14336"); ARD(ar15, "15360");
        WAIT10
        // sub6: m4 12,13
        FMAG(ar12, ha0, ha1, ha2, ha3)
        FMAG(ar13, ha4, ha5, ha6, ha7)
        asm volatile("s_waitcnt lgkmcnt(0)" ::: "memory");
        __builtin_amdgcn_sched_barrier(0);
        // sub7: m4 14,15
        FMAG(ar14, hb0, hb1, hb2, hb3)
        FMAG(ar15, hb4, hb5, hb6, hb7)

        h0 = a0; h1 = a1; h2 = a2; h3 = a3;
        h_s[0][k] = h0; h_s[1][k] = h1; h_s[2][k] = h2; h_s[3][k] = h3;
        // per-wave DS ops execute in order at the LDS unit: next iteration's
        // HRD reads (memory-clobbered asm) see these writes.

        const LAS float* t = rd_cur; rd_cur = rd_nxt; rd_nxt = (LAS float*)t;
    }
#undef ARD
#undef HRD
#undef FMAG
#undef WAIT10
}

// ---------------------------------------------------------------------------
// Phase B3: W_c = Wv_c - Wk_c h0_c (unchanged)
// ---------------------------------------------------------------------------
__global__ __launch_bounds__(256) void wfix_k(const float* __restrict__ Wk,
                                              const float* __restrict__ Hst,
                                              float* __restrict__ Wio) {
    __shared__ __align__(16) float wk_s[CL * PAD];
    __shared__ __align__(16) float h_s[CL * PAD];

    const int blk = blockIdx.x;
    const int tid = threadIdx.x;

    {
        const float4* Wkg = (const float4*)(Wk + (size_t)blk * 4096);
        const float4* Hg = (const float4*)(Hst + (size_t)blk * 4096);
#pragma unroll
        for (int i = 0; i < 4; ++i) {
            int f = tid + i * 256;
            int d = (f >> 4) * PAD + (f & 15) * 4;
            *(float4*)&wk_s[d] = Wkg[f];
            *(float4*)&h_s[d] = Hg[f];
        }
    }
    __syncthreads();

    const int t0 = (tid >> 4) * 4, v0 = (tid & 15) * 4;
    float* Wg = Wio + (size_t)blk * 4096;

    float acc[4][4];
#pragma unroll
    for (int i = 0; i < 4; ++i) {
        float4 wv = *(const float4*)&Wg[(t0 + i) * 64 + v0];
        acc[i][0] = wv.x; acc[i][1] = wv.y; acc[i][2] = wv.z; acc[i][3] = wv.w;
    }
    for (int kk = 0; kk < 64; kk += 4) {
        float4 wa0 = *(const float4*)&wk_s[(t0 + 0) * PAD + kk];
        float4 wa1 = *(const float4*)&wk_s[(t0 + 1) * PAD + kk];
        float4 wa2 = *(const float4*)&wk_s[(t0 + 2) * PAD + kk];
        float4 wa3 = *(const float4*)&wk_s[(t0 + 3) * PAD + kk];
        float4 hb0 = *(const float4*)&h_s[(kk + 0) * PAD + v0];
        float4 hb1 = *(const float4*)&h_s[(kk + 1) * PAD + v0];
        float4 hb2 = *(const float4*)&h_s[(kk + 2) * PAD + v0];
        float4 hb3 = *(const float4*)&h_s[(kk + 3) * PAD + v0];
        WSUB(x, hb0); WSUB(y, hb1); WSUB(z, hb2); WSUB(w, hb3);
    }
#pragma unroll
    for (int i = 0; i < 4; ++i)
        *(float4*)&Wg[(t0 + i) * 64 + v0] =
            make_float4(acc[i][0], acc[i][1], acc[i][2], acc[i][3]);
}

// ---------------------------------------------------------------------------
// Phase C (R16): XOR chunk-swizzle on s_s (unchanged)
// ---------------------------------------------------------------------------
__global__ __launch_bounds__(256) void out_k(const float* __restrict__ Qc,
                                             const float* __restrict__ Kc,
                                             const float* __restrict__ Wb_,
                                             const float* __restrict__ Hst,
                                             const float* __restrict__ bcum,
                                             float* __restrict__ o_scan) {
    __shared__ __align__(16) float q_s[CL * PAD];
    __shared__ __align__(16) float s_s[CL * PAD];   // K, then S (swizzled)
    __shared__ __align__(16) float h_s[CL * PAD];
    __shared__ __align__(16) float w_s[CL * PAD];
    __shared__ float b_s[64];

    const int blk = blockIdx.x;
    const int bh = blk >> 5;
    const int c = blk & 31;
    const int b = bh >> 4;
    const int h = bh & 15;
    const int tid = threadIdx.x;

    if (tid < 64) b_s[tid] = bcum[(size_t)blk * 64 + tid];
    {
        const float4* Qg = (const float4*)(Qc + (size_t)blk * 4096);
        const float4* Kg = (const float4*)(Kc + (size_t)blk * 4096);
        const float4* Hg = (const float4*)(Hst + (size_t)blk * 4096);
        const float4* Wg = (const float4*)(Wb_ + (size_t)blk * 4096);
#pragma unroll
        for (int i = 0; i < 4; ++i) {
            int f = tid + i * 256;
            int t = f >> 4;
            int c4 = f & 15;
            int d = t * PAD + c4 * 4;
            int dsz = t * PAD + ((c4 ^ (t >> 2)) << 2);     // s_s swizzled
            *(float4*)&q_s[d] = Qg[f];
            *(float4*)&s_s[dsz] = Kg[f];
            *(float4*)&h_s[d] = Hg[f];
            *(float4*)&w_s[d] = Wg[f];
        }
    }
    __syncthreads();

    // Phase 1: S = (Q K^T) ⊙ exp(b_t - b_s) [s<=t], overwrite s_s
    const int qrow = tid >> 4;          // = (t0+i)>>2
    const int qcol = tid & 15;          // = (s0+j)>>2
    {
        const int t0 = qrow * 4, s0 = qcol * 4;
        float acc[4][4] = {};
        for (int kk = 0; kk < 64; kk += 4) {
            const int kb = ((kk >> 2) ^ qcol) << 2;
            float4 ta0 = *(const float4*)&q_s[(t0 + 0) * PAD + kk];
            float4 ta1 = *(const float4*)&q_s[(t0 + 1) * PAD + kk];
            float4 ta2 = *(const float4*)&q_s[(t0 + 2) * PAD + kk];
            float4 ta3 = *(const float4*)&q_s[(t0 + 3) * PAD + kk];
            float4 sb0 = *(const float4*)&s_s[(s0 + 0) * PAD + kb];
            float4 sb1 = *(const float4*)&s_s[(s0 + 1) * PAD + kb];
            float4 sb2 = *(const float4*)&s_s[(s0 + 2) * PAD + kb];
            float4 sb3 = *(const float4*)&s_s[(s0 + 3) * PAD + kb];
            acc[0][0] += DOT4(ta0, sb0); acc[0][1] += DOT4(ta0, sb1);
            acc[0][2] += DOT4(ta0, sb2); acc[0][3] += DOT4(ta0, sb3);
            acc[1][0] += DOT4(ta1, sb0); acc[1][1] += DOT4(ta1, sb1);
            acc[1][2] += DOT4(ta1, sb2); acc[1][3] += DOT4(ta1, sb3);
            acc[2][0] += DOT4(ta2, sb0); acc[2][1] += DOT4(ta2, sb1);
            acc[2][2] += DOT4(ta2, sb2); acc[2][3] += DOT4(ta2, sb3);
            acc[3][0] += DOT4(ta3, sb0); acc[3][1] += DOT4(ta3, sb1);
            acc[3][2] += DOT4(ta3, sb2); acc[3][3] += DOT4(ta3, sb3);
        }
        __syncthreads();   // all Q,K reads done before overwrite
#pragma unroll
        for (int i = 0; i < 4; ++i)
#pragma unroll
            for (int j = 0; j < 4; ++j) {
                const int t = t0 + i, s = s0 + j;
                // swizzled scalar store: chunk (s>>2)=qcol XOR (t>>2)=qrow
                s_s[t * PAD + ((qcol ^ qrow) << 2) + (s & 3)] =
                    (s <= t) ? acc[i][j] * __expf(b_s[t] - b_s[s]) : 0.0f;
            }
    }
    // scale q rows by e^{b_t}  (q_s plain)
#pragma unroll
    for (int i = 0; i < 16; ++i) {
        const int e = tid + i * 256;
        const int t = e >> 6;
        q_s[t * PAD + (e & 63)] *= __expf(b_s[t]);
    }
    __syncthreads();

    // Phase 2: O = S @ W + Qs @ H
    {
        const int t0 = qrow * 4, v0 = qcol * 4;
        float acc[4][4] = {};
        for (int ss = 0; ss < 64; ss += 4) {
            const int ks = ((ss >> 2) ^ qrow) << 2;   // s_s swizzled read
            float4 sa0 = *(const float4*)&s_s[(t0 + 0) * PAD + ks];
            float4 sa1 = *(const float4*)&s_s[(t0 + 1) * PAD + ks];
            float4 sa2 = *(const float4*)&s_s[(t0 + 2) * PAD + ks];
            float4 sa3 = *(const float4*)&s_s[(t0 + 3) * PAD + ks];
            float4 wb0 = *(const float4*)&w_s[(ss + 0) * PAD + v0];
            float4 wb1 = *(const float4*)&w_s[(ss + 1) * PAD + v0];
            float4 wb2 = *(const float4*)&w_s[(ss + 2) * PAD + v0];
            float4 wb3 = *(const float4*)&w_s[(ss + 3) * PAD + v0];
            ACC16(x, wb0); ACC16(y, wb1); ACC16(z, wb2); ACC16(w, wb3);
        }
        for (int kk = 0; kk < 64; kk += 4) {
            float4 sa0 = *(const float4*)&q_s[(t0 + 0) * PAD + kk];
            float4 sa1 = *(const float4*)&q_s[(t0 + 1) * PAD + kk];
            float4 sa2 = *(const float4*)&q_s[(t0 + 2) * PAD + kk];
            float4 sa3 = *(const float4*)&q_s[(t0 + 3) * PAD + kk];
            float4 wb0 = *(const float4*)&h_s[(kk + 0) * PAD + v0];
            float4 wb1 = *(const float4*)&h_s[(kk + 1) * PAD + v0];
            float4 wb2 = *(const float4*)&h_s[(kk + 2) * PAD + v0];
            float4 wb3 = *(const float4*)&h_s[(kk + 3) * PAD + v0];
            ACC16(x, wb0); ACC16(y, wb1); ACC16(z, wb2); ACC16(w, wb3);
        }
#pragma unroll
        for (int i = 0; i < 4; ++i) {
            const int t = c * CL + t0 + i;
            *(float4*)&o_scan[(((size_t)b * TT + t) * HH + h) * DK + v0] =
                make_float4(acc[i][0], acc[i][1], acc[i][2], acc[i][3]);
        }
    }
}

// ---------------------------------------------------------------------------
// Gated RMSNorm -> bf16 output (unchanged)
// ---------------------------------------------------------------------------
__global__ __launch_bounds__(256) void gnorm_k(const float* __restrict__ o_scan,
                                               const float* __restrict__ gate,
                                               const float* __restrict__ rms_w,
                                               unsigned short* __restrict__ o2) {
    const int tid = threadIdx.x;
    const int grp = tid >> 6;
    const int lane = tid & 63;
    const int bth = blockIdx.x * 4 + grp;
    const int h = bth & 15;
    const int row = bth >> 4;

    float ov = o_scan[(size_t)bth * DK + lane];
    float s = ov * ov;
#pragma unroll
    for (int sh = 32; sh > 0; sh >>= 1) s += __shfl_xor(s, sh);
    float r = rsqrtf(s * (1.0f / 64.0f) + 1e-5f);

    float gt = gate[(size_t)row * HD + h * DK + lane];
    o2[(size_t)row * HD + h * DK + lane] = f2bf(ov * r * rms_w[lane] * siluf_(gt));
}

// ---------------------------------------------------------------------------
extern "C" void kernel_launch(void* const* d_in, const int* in_sizes, int n_in,
                              void* d_out, int out_size, void* d_ws, size_t ws_size,
                              hipStream_t stream) {
    (void)in_sizes; (void)n_in; (void)out_size; (void)ws_size;

    const float* x       = (const float*)d_in[0];
    const float* Wq      = (const float*)d_in[1];
    const float* Wk_     = (const float*)d_in[2];
    const float* Wv_     = (const float*)d_in[3];
    const float* Wa      = (const float*)d_in[4];
    const float* Wb      = (const float*)d_in[5];
    const float* Wg      = (const float*)d_in[6];
    const float* Wo      = (const float*)d_in[7];
    const float* conv_q  = (const float*)d_in[8];
    const float* conv_k  = (const float*)d_in[9];
    const float* conv_v  = (const float*)d_in[10];
    const float* A_log   = (const float*)d_in[11];
    const float* dt_bias = (const float*)d_in[12];
    const float* rms_w   = (const float*)d_in[13];
    float* out = (float*)d_out;

    float* ws = (float*)d_ws;
    const size_t NTOK = (size_t)BB * TT;     // 4096
    const size_t BIG = NTOK * HD;            // 4 Mi floats

    float* q_pre = ws + 0 * BIG;
    float* k_pre = ws + 1 * BIG;
    float* v_pre = ws + 2 * BIG;
    float* gatep = ws + 3 * BIG;
    float* Qc    = ws + 4 * BIG;
    float* Kc    = ws + 5 * BIG;
    float* gbuf  = ws + 6 * BIG;
    float* bbuf  = gbuf + NTOK * HH;
    float* bcumb = bbuf + NTOK * HH;

    // bf16 buffers after the fp32 region (wqt..wgt contiguous = fused B matrix)
    unsigned short* xb  = (unsigned short*)(bcumb + NTOK * HH);
    unsigned short* wqt = xb + (size_t)NTOK * DD;
    unsigned short* wkt = wqt + (size_t)DD * HD;
    unsigned short* wvt = wkt + (size_t)DD * HD;
    unsigned short* wgt = wvt + (size_t)DD * HD;
    unsigned short* wot = wgt + (size_t)DD * HD;

    // fp32 buffers after bf16 region: Bb + Hst (32 MB) + Wab_t (128 KB)
    float* Bbuf = (float*)(wot + (size_t)DD * HD);
    float* HstB = Bbuf + BIG;
    float* Wabt = HstB + BIG;

    // aliases (stream-ordered lifetimes):
    float* Wvb    = q_pre;   // prep_k out; wfix_k rewrites in place to W
    float* Wkb    = k_pre;
    // A buffer aliases the xb/wqt region (dead after gemm_qkvg_k).
    float* Abuf   = (float*)xb;
    float* o_scan = v_pre;   // out_k out (v_pre dead after prep_k)
    unsigned short* o2b = (unsigned short*)Qc;

    // casts
    castx_k<<<(int)(NTOK * DD / (256 * 8)), 256, 0, stream>>>(x, xb);
    dim3 tg(16, 16);
    castw_k<<<tg, 256, 0, stream>>>(Wq, wqt);
    castw_k<<<tg, 256, 0, stream>>>(Wk_, wkt);
    castw_k<<<tg, 256, 0, stream>>>(Wv_, wvt);
    castw_k<<<tg, 256, 0, stream>>>(Wg, wgt);
    castw_k<<<tg, 256, 0, stream>>>(Wo, wot);
    tw_k<<<32, 256, 0, stream>>>(Wa, Wb, Wabt);

    // fused QKVG projection: 256 blocks x 512 threads (256^2 8-phase, R13)
    gemm_qkvg_k<<<256, 512, 0, stream>>>(xb, wqt, q_pre, k_pre, v_pre, gatep);

    gbeta_k<<<(int)(NTOK / 8), 256, 0, stream>>>(x, Wabt, A_log, dt_bias, gbuf, bbuf);

    stage_k<<<BB * HH * NC, 64, 0, stream>>>(q_pre, k_pre, conv_q, conv_k, gbuf,
                                             Qc, Kc, bcumb);

    // prep_k (512 threads, R18) also emits A_c/B_c (fused ab_k, R17)
    prep_k<<<BB * HH * NC, 512, 0, stream>>>(Kc, v_pre, conv_v, bcumb, bbuf,
                                             Wvb, Wkb, Abuf, Bbuf);

    hrec_k<<<BB * HH * VS, 64, 0, stream>>>(Abuf, Bbuf, HstB);
    wfix_k<<<BB * HH * NC, 256, 0, stream>>>(Wkb, HstB, Wvb);

    out_k<<<BB * HH * NC, 256, 0, stream>>>(Qc, Kc, Wvb, HstB, bcumb, o_scan);

    gnorm_k<<<(int)(NTOK * HH / 4), 256, 0, stream>>>(o_scan, gatep, rms_w, o2b);

    gemm_bf16_k<<<dim3(HD / 128, NTOK / 128), 256, 0, stream>>>(o2b, wot, out,
                                                                (int)NTOK, HD, DD);
}

// Round 9
// 423.842 us; speedup vs baseline: 1.2344x; 1.2344x over previous
//
#include <hip/hip_runtime.h>
#include <hip/hip_bf16.h>
#include <math.h>
#include <stdint.h>

// Problem constants
#define BB 2
#define TT 2048
#define DD 1024
#define HH 16
#define DK 64
#define HD 1024   // H*DK
#define NC 32     // chunks per sequence (TT/64)
#define CL 64     // chunk length
#define PAD 68    // padded LDS row stride (floats)
#define PADA 67   // A_s row stride (R16)
#define VS 16     // v-splits in hrec_k

typedef short bf16x8 __attribute__((ext_vector_type(8)));     // 8 bf16 (4 VGPRs)
typedef float f32x4 __attribute__((ext_vector_type(4)));      // MFMA acc
typedef unsigned short u16x8 __attribute__((ext_vector_type(8)));
typedef unsigned short u16x4 __attribute__((ext_vector_type(4)));

#define GAS __attribute__((address_space(1)))
#define LAS __attribute__((address_space(3)))

#define DOT4(a, b) ((a).x*(b).x + (a).y*(b).y + (a).z*(b).z + (a).w*(b).w)

// acc[i][j] += kf[i-component] * wv[j-component]   (one contraction step)
#define OUT16(acc, kf, wv) \
    acc[0][0] += kf.x * wv.x; acc[0][1] += kf.x * wv.y; acc[0][2] += kf.x * wv.z; acc[0][3] += kf.x * wv.w; \
    acc[1][0] += kf.y * wv.x; acc[1][1] += kf.y * wv.y; acc[1][2] += kf.y * wv.z; acc[1][3] += kf.y * wv.w; \
    acc[2][0] += kf.z * wv.x; acc[2][1] += kf.z * wv.y; acc[2][2] += kf.z * wv.z; acc[2][3] += kf.z * wv.w; \
    acc[3][0] += kf.w * wv.x; acc[3][1] += kf.w * wv.y; acc[3][2] += kf.w * wv.z; acc[3][3] += kf.w * wv.w;

// acc[i][j] -= wa_i.c * hv[j]   (c = component selecting m)
#define WSUB(c, hv) \
    acc[0][0] -= wa0.c * hv.x; acc[0][1] -= wa0.c * hv.y; acc[0][2] -= wa0.c * hv.z; acc[0][3] -= wa0.c * hv.w; \
    acc[1][0] -= wa1.c * hv.x; acc[1][1] -= wa1.c * hv.y; acc[1][2] -= wa1.c * hv.z; acc[1][3] -= wa1.c * hv.w; \
    acc[2][0] -= wa2.c * hv.x; acc[2][1] -= wa2.c * hv.y; acc[2][2] -= wa2.c * hv.z; acc[2][3] -= wa2.c * hv.w; \
    acc[3][0] -= wa3.c * hv.x; acc[3][1] -= wa3.c * hv.y; acc[3][2] -= wa3.c * hv.z; acc[3][3] -= wa3.c * hv.w;

// acc[i][j] += sa_i.c * wv[j]   (c = component selecting the contraction idx)
#define ACC16(c, wv) \
    acc[0][0] += sa0.c * wv.x; acc[0][1] += sa0.c * wv.y; acc[0][2] += sa0.c * wv.z; acc[0][3] += sa0.c * wv.w; \
    acc[1][0] += sa1.c * wv.x; acc[1][1] += sa1.c * wv.y; acc[1][2] += sa1.c * wv.z; acc[1][3] += sa1.c * wv.w; \
    acc[2][0] += sa2.c * wv.x; acc[2][1] += sa2.c * wv.y; acc[2][2] += sa2.c * wv.z; acc[2][3] += sa2.c * wv.w; \
    acc[3][0] += sa3.c * wv.x; acc[3][1] += sa3.c * wv.y; acc[3][2] += sa3.c * wv.z; acc[3][3] += sa3.c * wv.w;

__device__ __forceinline__ float sigmoidf_(float x) { return 1.0f / (1.0f + expf(-x)); }
__device__ __forceinline__ float siluf_(float x) { return x * sigmoidf_(x); }

// round-to-nearest-even fp32 -> bf16
__device__ __forceinline__ unsigned short f2bf(float f) {
    unsigned int u = __builtin_bit_cast(unsigned int, f);
    u = (u + 0x7fffu + ((u >> 16) & 1u)) >> 16;
    return (unsigned short)u;
}

// ---------------------------------------------------------------------------
// Cast x (fp32) -> bf16, flat.
// ---------------------------------------------------------------------------
__global__ __launch_bounds__(256) void castx_k(const float* __restrict__ src,
                                               unsigned short* __restrict__ dst) {
    const size_t idx = (size_t)blockIdx.x * 256 + threadIdx.x;
    float4 a = *(const float4*)&src[idx * 8];
    float4 b = *(const float4*)&src[idx * 8 + 4];
    u16x8 o;
    o[0] = f2bf(a.x); o[1] = f2bf(a.y); o[2] = f2bf(a.z); o[3] = f2bf(a.w);
    o[4] = f2bf(b.x); o[5] = f2bf(b.y); o[6] = f2bf(b.z); o[7] = f2bf(b.w);
    *(u16x8*)&dst[idx * 8] = o;
}

// ---------------------------------------------------------------------------
// Transpose+cast weight: W[K=1024][N=1024] fp32 -> Wt[N][K] bf16.
// ---------------------------------------------------------------------------
__global__ __launch_bounds__(256) void castw_k(const float* __restrict__ W,
                                               unsigned short* __restrict__ Wt) {
    __shared__ float t_s[64][65];
    const int tid = threadIdx.x;
    const int rr = tid >> 4;
    const int cc = tid & 15;
    const int r0 = blockIdx.y * 64;
    const int c0 = blockIdx.x * 64;
#pragma unroll
    for (int i = 0; i < 4; ++i) {
        const int row = rr + i * 16;
        float4 v = *(const float4*)&W[(size_t)(r0 + row) * 1024 + c0 + cc * 4];
        t_s[row][cc * 4 + 0] = v.x;
        t_s[row][cc * 4 + 1] = v.y;
        t_s[row][cc * 4 + 2] = v.z;
        t_s[row][cc * 4 + 3] = v.w;
    }
    __syncthreads();
#pragma unroll
    for (int i = 0; i < 4; ++i) {
        const int nr = rr + i * 16;
        u16x4 o;
#pragma unroll
        for (int d = 0; d < 4; ++d) o[d] = f2bf(t_s[cc * 4 + d][nr]);
        *(u16x4*)&Wt[(size_t)(c0 + nr) * 1024 + r0 + cc * 4] = o;
    }
}

// ---------------------------------------------------------------------------
// transpose Wa|Wb [1024][16] -> Wab_t [32][1024] fp32 (R8)
// ---------------------------------------------------------------------------
__global__ __launch_bounds__(256) void tw_k(const float* __restrict__ Wa,
                                            const float* __restrict__ Wb,
                                            float* __restrict__ Wt) {
    const int o = blockIdx.x;          // 0..31
    const int h = o & 15;
    const float* W = (o < 16) ? Wa : Wb;
    const int tid = threadIdx.x;
    float4 v;
    v.x = W[(size_t)(tid * 4 + 0) * HH + h];
    v.y = W[(size_t)(tid * 4 + 1) * HH + h];
    v.z = W[(size_t)(tid * 4 + 2) * HH + h];
    v.w = W[(size_t)(tid * 4 + 3) * HH + h];
    *(float4*)&Wt[(size_t)o * DD + tid * 4] = v;
}

// ---------------------------------------------------------------------------
// bf16 MFMA GEMM (m97 structure) — generic single-output (used for Wo).
// ---------------------------------------------------------------------------
__global__ __launch_bounds__(256) void gemm_bf16_k(const unsigned short* __restrict__ A,
                                                   const unsigned short* __restrict__ Bt,
                                                   float* __restrict__ C,
                                                   int M, int N, int Kd) {
    __shared__ unsigned short a_s[128 * 32];
    __shared__ unsigned short b_s[128 * 32];

    const int tid = threadIdx.x;
    const int wave = tid >> 6;
    const int lane = tid & 63;
    const int m0 = blockIdx.y * 128;
    const int n0 = blockIdx.x * 128;

    const int quad = lane >> 4;
    const int l16 = lane & 15;
    const int wr = wave >> 1;
    const int wc = wave & 1;

    const int srow = lane >> 2;
    const int sseg = lane & 3;

    f32x4 acc[4][4];
#pragma unroll
    for (int i = 0; i < 4; ++i)
#pragma unroll
        for (int j = 0; j < 4; ++j) acc[i][j] = (f32x4){0.f, 0.f, 0.f, 0.f};

    for (int k0 = 0; k0 < Kd; k0 += 32) {
        __syncthreads();
#pragma unroll
        for (int c = 0; c < 2; ++c) {
            const int region = wave * 2 + c;
            const int r0t = region * 16;
            const int ra = r0t + srow;
            const unsigned short* ga = A + (size_t)(m0 + ra) * Kd + k0 + sseg * 8;
            const unsigned short* gb = Bt + (size_t)(n0 + ra) * Kd + k0 + sseg * 8;
            __builtin_amdgcn_global_load_lds((const GAS unsigned int*)ga,
                                             (LAS unsigned int*)&a_s[r0t * 32], 16, 0, 0);
            __builtin_amdgcn_global_load_lds((const GAS unsigned int*)gb,
                                             (LAS unsigned int*)&b_s[r0t * 32], 16, 0, 0);
        }
        __syncthreads();

        bf16x8 af[4], bfr[4];
#pragma unroll
        for (int i = 0; i < 4; ++i)
            af[i] = *(const bf16x8*)&a_s[(wr * 64 + i * 16 + l16) * 32 + quad * 8];
#pragma unroll
        for (int j = 0; j < 4; ++j)
            bfr[j] = *(const bf16x8*)&b_s[(wc * 64 + j * 16 + l16) * 32 + quad * 8];
#pragma unroll
        for (int i = 0; i < 4; ++i)
#pragma unroll
            for (int j = 0; j < 4; ++j)
                acc[i][j] = __builtin_amdgcn_mfma_f32_16x16x32_bf16(af[i], bfr[j], acc[i][j], 0, 0, 0);
    }

#pragma unroll
    for (int i = 0; i < 4; ++i)
#pragma unroll
        for (int j = 0; j < 4; ++j) {
            const int col = n0 + wc * 64 + j * 16 + l16;
#pragma unroll
            for (int r = 0; r < 4; ++r) {
                const int row = m0 + wr * 64 + i * 16 + quad * 4 + r;
                C[(size_t)row * N + col] = acc[i][j][r];
            }
        }
}

// ---------------------------------------------------------------------------
// Fused QKVG projection GEMM — R13 structure (unchanged): 256x256 tile,
// 8 waves, BK=64, swizzled LDS, counted vmcnt/lgkmcnt, setprio.
// ---------------------------------------------------------------------------
#define DSRQ(D, P, OFF) asm volatile("ds_read_b128 %0, %1 offset:" OFF \
                                     : "=v"(D) : "v"(P))

__global__ __launch_bounds__(512, 2) void gemm_qkvg_k(const unsigned short* __restrict__ A,
                                                      const unsigned short* __restrict__ Bt,
                                                      float* __restrict__ Oq,
                                                      float* __restrict__ Ok,
                                                      float* __restrict__ Ov,
                                                      float* __restrict__ Og) {
    __shared__ __align__(16) unsigned char lds_all[131072];   // 128 KiB

    const int tid = threadIdx.x;
    const int w = tid >> 6;           // wave 0..7
    const int lane = tid & 63;
    const int l16 = lane & 15;
    const int quad = lane >> 4;
    const int wr = w >> 2;            // 0..1 : 128-row half
    const int wc = w & 3;             // 0..3 : 64-col quarter

    // XCD-aware block swizzle (bijective: 256 % 8 == 0)
    const int bid = blockIdx.x;
    const int wg = (bid & 7) * 32 + (bid >> 3);
    const int m0 = (wg >> 4) * 256;
    const int n0 = (wg & 15) * 256;

    // staging: lane (lr,ls) sources the PRE-SWIZZLED slot ls^lr so the
    // swizzled read finds logical data (rule #21).
    const int lr = lane >> 3;
    const int ls = lane & 7;
    const int sslot = ls ^ lr;
    const unsigned short* srcA = A + (size_t)(m0 + lr) * DD + sslot * 8 + (size_t)w * 8 * DD;
    const unsigned short* srcB = Bt + (size_t)(n0 + lr) * DD + sslot * 8 + (size_t)w * 8 * DD;

    const LAS unsigned char* LB = (const LAS unsigned char*)&lds_all[0];

    // swizzled read base (buf0, ksub0); ^64 toggles ksub, +32768 toggles buf
    const unsigned int xq = (unsigned int)((quad ^ (l16 & 7)) << 4);
    const unsigned int uA0 = (unsigned int)((wr * 128 + l16) * 128) + xq;
    const unsigned int uB0 = 65536u + (unsigned int)((wc * 64 + l16) * 128) + xq;

    f32x4 acc[8][4];
#pragma unroll
    for (int i = 0; i < 8; ++i)
#pragma unroll
        for (int j = 0; j < 4; ++j) acc[i][j] = (f32x4){0.f, 0.f, 0.f, 0.f};

#define STG1Q(T, IA) \
    __builtin_amdgcn_global_load_lds( \
        (const GAS unsigned int*)(srcA + (size_t)(IA) * 65536 + (size_t)(T) * 64), \
        (LAS unsigned int*)(LB + (((unsigned)((T) & 1)) << 15) + ((IA) * 8 + w) * 1024), 16, 0, 0); \
    __builtin_amdgcn_global_load_lds( \
        (const GAS unsigned int*)(srcB + (size_t)(IA) * 65536 + (size_t)(T) * 64), \
        (LAS unsigned int*)(LB + 65536u + (((unsigned)((T) & 1)) << 15) + ((IA) * 8 + w) * 1024), 16, 0, 0);
#define STGQ(T) { STG1Q(T, 0) STG1Q(T, 1) STG1Q(T, 2) STG1Q(T, 3) }

    STGQ(0);                           // prologue: stage K-step 0 into buf0

    bf16x8 aG0[4], aG1[4], b0[4], b1[4];

#pragma unroll 1
    for (int t = 0; t < 16; ++t) {
        if (t + 1 < 16) {
            STGQ(t + 1);               // 8 loads for next K-step -> other buf
            asm volatile("s_waitcnt vmcnt(8)" ::: "memory");   // stage(t) done
        } else {
            asm volatile("s_waitcnt vmcnt(0)" ::: "memory");
        }
        __builtin_amdgcn_s_barrier();  // buf(t&1) staged by ALL waves

        const unsigned int boff = ((unsigned)(t & 1)) << 15;
        const LAS unsigned char* pA0 = LB + (uA0 + boff);
        const LAS unsigned char* pA1 = LB + ((uA0 ^ 64u) + boff);
        const LAS unsigned char* pB0 = LB + (uB0 + boff);
        const LAS unsigned char* pB1 = LB + ((uB0 ^ 64u) + boff);

        // issue 16 reads: b0, aG0(k0), aG1(k0), b1
        DSRQ(b0[0], pB0, "0");    DSRQ(b0[1], pB0, "2048");
        DSRQ(b0[2], pB0, "4096"); DSRQ(b0[3], pB0, "6144");
        DSRQ(aG0[0], pA0, "0");    DSRQ(aG0[1], pA0, "2048");
        DSRQ(aG0[2], pA0, "4096"); DSRQ(aG0[3], pA0, "6144");
        DSRQ(aG1[0], pA0, "8192");  DSRQ(aG1[1], pA0, "10240");
        DSRQ(aG1[2], pA0, "12288"); DSRQ(aG1[3], pA0, "14336");
        DSRQ(b1[0], pB1, "0");    DSRQ(b1[1], pB1, "2048");
        DSRQ(b1[2], pB1, "4096"); DSRQ(b1[3], pB1, "6144");

        asm volatile("s_waitcnt lgkmcnt(8)" ::: "memory");   // b0,aG0 ready
        __builtin_amdgcn_sched_barrier(0);
        __builtin_amdgcn_s_setprio(1);
#pragma unroll
        for (int ia = 0; ia < 4; ++ia)
#pragma unroll
            for (int j = 0; j < 4; ++j)
                acc[ia][j] = __builtin_amdgcn_mfma_f32_16x16x32_bf16(aG0[ia], b0[j], acc[ia][j], 0, 0, 0);
        __builtin_amdgcn_s_setprio(0);

        DSRQ(aG0[0], pA1, "0");    DSRQ(aG0[1], pA1, "2048");   // aG0 <- ksub1
        DSRQ(aG0[2], pA1, "4096"); DSRQ(aG0[3], pA1, "6144");
        asm volatile("s_waitcnt lgkmcnt(4)" ::: "memory");   // aG1(k0),b1 ready
        __builtin_amdgcn_sched_barrier(0);
        __builtin_amdgcn_s_setprio(1);
#pragma unroll
        for (int ia = 0; ia < 4; ++ia)
#pragma unroll
            for (int j = 0; j < 4; ++j)
                acc[4 + ia][j] = __builtin_amdgcn_mfma_f32_16x16x32_bf16(aG1[ia], b0[j], acc[4 + ia][j], 0, 0, 0);
        __builtin_amdgcn_s_setprio(0);

        DSRQ(aG1[0], pA1, "8192");  DSRQ(aG1[1], pA1, "10240"); // aG1 <- ksub1
        DSRQ(aG1[2], pA1, "12288"); DSRQ(aG1[3], pA1, "14336");
        asm volatile("s_waitcnt lgkmcnt(4)" ::: "memory");   // aG0(k1) ready
        __builtin_amdgcn_sched_barrier(0);
        __builtin_amdgcn_s_setprio(1);
#pragma unroll
        for (int ia = 0; ia < 4; ++ia)
#pragma unroll
            for (int j = 0; j < 4; ++j)
                acc[ia][j] = __builtin_amdgcn_mfma_f32_16x16x32_bf16(aG0[ia], b1[j], acc[ia][j], 0, 0, 0);
        __builtin_amdgcn_s_setprio(0);

        asm volatile("s_waitcnt lgkmcnt(0)" ::: "memory");   // aG1(k1) ready
        __builtin_amdgcn_sched_barrier(0);
        __builtin_amdgcn_s_setprio(1);
#pragma unroll
        for (int ia = 0; ia < 4; ++ia)
#pragma unroll
            for (int j = 0; j < 4; ++j)
                acc[4 + ia][j] = __builtin_amdgcn_mfma_f32_16x16x32_bf16(aG1[ia], b1[j], acc[4 + ia][j], 0, 0, 0);
        __builtin_amdgcn_s_setprio(0);

        __builtin_amdgcn_s_barrier();  // all reads of buf(t&1) done before
                                       // next iteration overwrites it
    }
#undef STGQ
#undef STG1Q

    float* Cd = (n0 < 1024) ? Oq : (n0 < 2048) ? Ok : (n0 < 3072) ? Ov : Og;
    const int nl = n0 & 1023;
    const int rbase = m0 + wr * 128 + quad * 4;
    const int cbase = nl + wc * 64 + l16;
#pragma unroll
    for (int ia = 0; ia < 8; ++ia)
#pragma unroll
        for (int j = 0; j < 4; ++j) {
            const int col = cbase + j * 16;
#pragma unroll
            for (int r = 0; r < 4; ++r)
                Cd[(size_t)(rbase + ia * 16 + r) * HD + col] = acc[ia][j][r];
        }
}

// ---------------------------------------------------------------------------
// g / beta kernel (R8, unchanged)
// ---------------------------------------------------------------------------
__global__ __launch_bounds__(256) void gbeta_k(const float* __restrict__ x,
                                               const float* __restrict__ Wt,
                                               const float* __restrict__ A_log,
                                               const float* __restrict__ dt_bias,
                                               float* __restrict__ g,
                                               float* __restrict__ beta) {
    __shared__ __align__(16) float xs[8][DD];
    const int r0 = blockIdx.x * 8;
    const int tid = threadIdx.x;

#pragma unroll
    for (int i = 0; i < 8; ++i) {
        const int f = tid + i * 256;
        const int r = f >> 8;
        const int col = (f & 255) * 4;
        *(float4*)&xs[r][col] = *(const float4*)&x[((size_t)r0 + r) * DD + col];
    }
    __syncthreads();

    const int out = tid >> 3;
    const int part = tid & 7;
    const int h = out & 15;
    const float* Wrow = Wt + (size_t)out * DD;

    float a0 = 0, a1 = 0, a2 = 0, a3 = 0, a4 = 0, a5 = 0, a6 = 0, a7 = 0;
#pragma unroll 4
    for (int i = 0; i < 32; ++i) {
        const int d = i * 32 + part * 4;
        const float4 wv = *(const float4*)&Wrow[d];
        float4 x0 = *(const float4*)&xs[0][d];
        float4 x1 = *(const float4*)&xs[1][d];
        float4 x2 = *(const float4*)&xs[2][d];
        float4 x3 = *(const float4*)&xs[3][d];
        float4 x4 = *(const float4*)&xs[4][d];
        float4 x5 = *(const float4*)&xs[5][d];
        float4 x6 = *(const float4*)&xs[6][d];
        float4 x7 = *(const float4*)&xs[7][d];
        a0 += DOT4(x0, wv); a1 += DOT4(x1, wv);
        a2 += DOT4(x2, wv); a3 += DOT4(x3, wv);
        a4 += DOT4(x4, wv); a5 += DOT4(x5, wv);
        a6 += DOT4(x6, wv); a7 += DOT4(x7, wv);
    }
#pragma unroll
    for (int s = 1; s <= 4; s <<= 1) {
        a0 += __shfl_xor(a0, s); a1 += __shfl_xor(a1, s);
        a2 += __shfl_xor(a2, s); a3 += __shfl_xor(a3, s);
        a4 += __shfl_xor(a4, s); a5 += __shfl_xor(a5, s);
        a6 += __shfl_xor(a6, s); a7 += __shfl_xor(a7, s);
    }

    if (part == 0) {
        float sv[8] = {a0, a1, a2, a3, a4, a5, a6, a7};
        if (out < 16) {
            const float ae = -expf(A_log[h]);
            const float db = dt_bias[h];
#pragma unroll
            for (int r = 0; r < 8; ++r) {
                float v = sv[r] + db;
                float sp = (v > 20.0f) ? v : log1pf(expf(v));
                g[((size_t)r0 + r) * HH + h] = ae * sp;
            }
        } else {
#pragma unroll
            for (int r = 0; r < 8; ++r)
                beta[((size_t)r0 + r) * HH + h] = sigmoidf_(sv[r]);
        }
    }
}

// ---------------------------------------------------------------------------
// Phase A1: stage normalized q,k (conv+silu+l2norm) and cumsum(g). (unchanged)
// ---------------------------------------------------------------------------
__global__ __launch_bounds__(64) void stage_k(const float* __restrict__ q_pre,
                                              const float* __restrict__ k_pre,
                                              const float* __restrict__ cq,
                                              const float* __restrict__ ck,
                                              const float* __restrict__ g,
                                              float* __restrict__ Qc,
                                              float* __restrict__ Kc,
                                              float* __restrict__ bcum) {
    const int blk = blockIdx.x;
    const int bh = blk >> 5;
    const int c = blk & 31;
    const int b = bh >> 4;
    const int h = bh & 15;
    const int lane = threadIdx.x;
    const int ch = h * DK + lane;

    const float4 wq4 = *(const float4*)&cq[ch * 4];
    const float4 wk4 = *(const float4*)&ck[ch * 4];

    float qw0 = 0, qw1 = 0, qw2 = 0, kw0 = 0, kw1 = 0, kw2 = 0;
    {
        const int t0 = c * CL;
        if (t0 - 3 >= 0) { size_t bi = ((size_t)b * TT + t0 - 3) * HD + ch; qw0 = q_pre[bi]; kw0 = k_pre[bi]; }
        if (t0 - 2 >= 0) { size_t bi = ((size_t)b * TT + t0 - 2) * HD + ch; qw1 = q_pre[bi]; kw1 = k_pre[bi]; }
        if (t0 - 1 >= 0) { size_t bi = ((size_t)b * TT + t0 - 1) * HD + ch; qw2 = q_pre[bi]; kw2 = k_pre[bi]; }
    }
    float* Qo = Qc + (size_t)blk * 4096;
    float* Ko = Kc + (size_t)blk * 4096;

    for (int tt = 0; tt < CL; ++tt) {
        const int t = c * CL + tt;
        const size_t bi = ((size_t)b * TT + t) * HD + ch;
        const float qc_ = q_pre[bi];
        const float kc_ = k_pre[bi];
        float qa = qw0 * wq4.x + qw1 * wq4.y + qw2 * wq4.z + qc_ * wq4.w;
        float ka = kw0 * wk4.x + kw1 * wk4.y + kw2 * wk4.z + kc_ * wk4.w;
        qw0 = qw1; qw1 = qw2; qw2 = qc_;
        kw0 = kw1; kw1 = kw2; kw2 = kc_;
        qa = siluf_(qa);
        ka = siluf_(ka);
        float qs2 = qa * qa, ks2 = ka * ka;
#pragma unroll
        for (int s = 32; s > 0; s >>= 1) {
            qs2 += __shfl_xor(qs2, s);
            ks2 += __shfl_xor(ks2, s);
        }
        Qo[tt * 64 + lane] = qa * rsqrtf(qs2 + 1e-6f) * 0.125f;
        Ko[tt * 64 + lane] = ka * rsqrtf(ks2 + 1e-6f);
    }

    float cum = g[((size_t)b * TT + c * CL + lane) * HH + h];
#pragma unroll
    for (int s = 1; s < 64; s <<= 1) {
        float u = __shfl_up(cum, s);
        if (lane >= s) cum += u;
    }
    bcum[(size_t)blk * 64 + lane] = cum;
}

// ---------------------------------------------------------------------------
// Phase A2 (R19 = R17 verbatim): 256-thread triangular solve + fused ab.
// R18 post-mortem: 512 threads under the same 74.7KB LDS halved the VGPR
// budget -> compiler capped at 128 VGPR and SPILLED (FETCH 17->118MB,
// WRITE 64->262MB, dur 74->160us). Reverted to the known-good 88-VGPR
// 256-thread version.
// ---------------------------------------------------------------------------
__global__ __launch_bounds__(256) void prep_k(const float* __restrict__ Kc,
                                              const float* __restrict__ v_pre,
                                              const float* __restrict__ cv,
                                              const float* __restrict__ bcum,
                                              const float* __restrict__ bbuf,
                                              float* __restrict__ Wv,
                                              float* __restrict__ Wk,
                                              float* __restrict__ Ab,
                                              float* __restrict__ Bb) {
    __shared__ __align__(16) float k_s[CL * PAD];
    __shared__ __align__(16) float wv_s[CL * PAD];
    __shared__ __align__(16) float wk_s[CL * PAD];
    __shared__ __align__(16) float A_s[CL * PADA];
    __shared__ float T_s[4][16 * 17];
    __shared__ float b_s[CL], beta_s[CL], bk_s[CL], e_s[CL];

    const int blk = blockIdx.x;
    const int bh = blk >> 5;
    const int c = blk & 31;
    const int b = bh >> 4;
    const int h = bh & 15;
    const int tid = threadIdx.x;

    if (tid < 64) {
        float bv = bcum[(size_t)blk * 64 + tid];
        float bC = bcum[(size_t)blk * 64 + 63];
        float be = bbuf[((size_t)b * TT + c * CL + tid) * HH + h];
        b_s[tid] = bv;
        beta_s[tid] = be;
        bk_s[tid] = be * __expf(bv);
        e_s[tid] = __expf(bC - bv);          // == ab_k's e_s (R17)
    }
    __syncthreads();

    {
        const float4* Kg = (const float4*)(Kc + (size_t)blk * 4096);
#pragma unroll
        for (int i = 0; i < 4; ++i) {
            int f = tid + i * 256;
            int t = f >> 4;
            int c4 = f & 15;
            int d = t * PAD + c4 * 4;                        // wk_s: plain
            int dsz = t * PAD + ((c4 ^ (t >> 2)) << 2);      // k_s: swizzled
            float4 kv = Kg[f];
            *(float4*)&k_s[dsz] = kv;
            float sk = bk_s[t];
            *(float4*)&wk_s[d] = make_float4(kv.x * sk, kv.y * sk, kv.z * sk, kv.w * sk);
        }
    }

    {
        const int lane = tid & 63;
        const int q4 = tid >> 6;
        const int ch = h * DK + lane;
        const float4 wv4 = *(const float4*)&cv[ch * 4];
        const int T0 = c * CL + q4 * 16;
        float w0 = 0, w1 = 0, w2 = 0;
        if (T0 - 3 >= 0) w0 = v_pre[((size_t)b * TT + T0 - 3) * HD + ch];
        if (T0 - 2 >= 0) w1 = v_pre[((size_t)b * TT + T0 - 2) * HD + ch];
        if (T0 - 1 >= 0) w2 = v_pre[((size_t)b * TT + T0 - 1) * HD + ch];
#pragma unroll 1
        for (int i = 0; i < 16; ++i) {
            const int t = T0 + i;
            const float vc_ = v_pre[((size_t)b * TT + t) * HD + ch];
            float va = w0 * wv4.x + w1 * wv4.y + w2 * wv4.z + vc_ * wv4.w;
            w0 = w1; w1 = w2; w2 = vc_;
            va = siluf_(va);
            wv_s[(q4 * 16 + i) * PAD + lane] = va * beta_s[q4 * 16 + i];
        }
    }
    __syncthreads();

    {
        const int qrow = tid >> 4;          // = (t0+i)>>2 for i in 0..3
        const int qcol = tid & 15;          // = (s0+j)>>2 for j in 0..3
        const int t0 = qrow * 4, s0 = qcol * 4;
        float acc[4][4] = {};
        for (int kk = 0; kk < 64; kk += 4) {
            const int ka = ((kk >> 2) ^ qrow) << 2;
            const int kb = ((kk >> 2) ^ qcol) << 2;
            float4 ta0 = *(const float4*)&k_s[(t0 + 0) * PAD + ka];
            float4 ta1 = *(const float4*)&k_s[(t0 + 1) * PAD + ka];
            float4 ta2 = *(const float4*)&k_s[(t0 + 2) * PAD + ka];
            float4 ta3 = *(const float4*)&k_s[(t0 + 3) * PAD + ka];
            float4 sb0 = *(const float4*)&k_s[(s0 + 0) * PAD + kb];
            float4 sb1 = *(const float4*)&k_s[(s0 + 1) * PAD + kb];
            float4 sb2 = *(const float4*)&k_s[(s0 + 2) * PAD + kb];
            float4 sb3 = *(const float4*)&k_s[(s0 + 3) * PAD + kb];
            acc[0][0] += DOT4(ta0, sb0); acc[0][1] += DOT4(ta0, sb1);
            acc[0][2] += DOT4(ta0, sb2); acc[0][3] += DOT4(ta0, sb3);
            acc[1][0] += DOT4(ta1, sb0); acc[1][1] += DOT4(ta1, sb1);
            acc[1][2] += DOT4(ta1, sb2); acc[1][3] += DOT4(ta1, sb3);
            acc[2][0] += DOT4(ta2, sb0); acc[2][1] += DOT4(ta2, sb1);
            acc[2][2] += DOT4(ta2, sb2); acc[2][3] += DOT4(ta2, sb3);
            acc[3][0] += DOT4(ta3, sb0); acc[3][1] += DOT4(ta3, sb1);
            acc[3][2] += DOT4(ta3, sb2); acc[3][3] += DOT4(ta3, sb3);
        }
        __syncthreads();
#pragma unroll
        for (int i = 0; i < 4; ++i)
#pragma unroll
            for (int j = 0; j < 4; ++j) {
                const int t = t0 + i, s = s0 + j;
                A_s[t * PADA + s] = (s < t) ? acc[i][j] * beta_s[t] * __expf(b_s[t] - b_s[s]) : 0.0f;
            }
    }
    __syncthreads();

    if (tid < 64) {
        const int d = tid >> 4;
        const int col = tid & 15;
        const int base = d * 16;
        float tcol[16];
#pragma unroll
        for (int s = 0; s < 16; ++s) tcol[s] = (s == col) ? 1.0f : 0.0f;
#pragma unroll
        for (int t = 1; t < 16; ++t) {
            float a = 0.0f;
#pragma unroll
            for (int s = 0; s < 16; ++s)
                if (s < t) a += A_s[(base + t) * PADA + base + s] * tcol[s];
            tcol[t] -= a;
        }
#pragma unroll
        for (int t = 0; t < 16; ++t) T_s[d][t * 17 + col] = tcol[t];
    }
    __syncthreads();

    {
        const int r = tid >> 4;
        const int cg = tid & 15;
        float* Wc = (cg < 8) ? wv_s : wk_s;
        const int cc = (cg & 7) * 8;

        for (int tb = 0; tb < 4; ++tb) {
            const int t = tb * 16 + r;
            if (tb > 0) {
                float4 lo = *(const float4*)&Wc[t * PAD + cc];
                float4 hi = *(const float4*)&Wc[t * PAD + cc + 4];
#pragma unroll 4
                for (int s = 0; s < tb * 16; ++s) {
                    const float a = A_s[t * PADA + s];
                    float4 wlo = *(const float4*)&Wc[s * PAD + cc];
                    float4 whi = *(const float4*)&Wc[s * PAD + cc + 4];
                    lo.x -= a * wlo.x; lo.y -= a * wlo.y; lo.z -= a * wlo.z; lo.w -= a * wlo.w;
                    hi.x -= a * whi.x; hi.y -= a * whi.y; hi.z -= a * whi.z; hi.w -= a * whi.w;
                }
                *(float4*)&Wc[t * PAD + cc] = lo;
                *(float4*)&Wc[t * PAD + cc + 4] = hi;
            }
            __syncthreads();
            float4 alo = make_float4(0, 0, 0, 0);
            float4 ahi = make_float4(0, 0, 0, 0);
#pragma unroll 4
            for (int s = 0; s < 16; ++s) {
                const float tv = T_s[tb][r * 17 + s];
                float4 wlo = *(const float4*)&Wc[(tb * 16 + s) * PAD + cc];
                float4 whi = *(const float4*)&Wc[(tb * 16 + s) * PAD + cc + 4];
                alo.x += tv * wlo.x; alo.y += tv * wlo.y; alo.z += tv * wlo.z; alo.w += tv * wlo.w;
                ahi.x += tv * whi.x; ahi.y += tv * whi.y; ahi.z += tv * whi.z; ahi.w += tv * whi.w;
            }
            __syncthreads();
            *(float4*)&Wc[t * PAD + cc] = alo;
            *(float4*)&Wc[t * PAD + cc + 4] = ahi;
            __syncthreads();
        }
    }

    // Wv/Wk writeback
    float4* Wvg = (float4*)(Wv + (size_t)blk * 4096);
    float4* Wkg = (float4*)(Wk + (size_t)blk * 4096);
#pragma unroll
    for (int i = 0; i < 4; ++i) {
        int f = tid + i * 256;
        int d = (f >> 4) * PAD + (f & 15) * 4;
        Wvg[f] = *(float4*)&wv_s[d];
        Wkg[f] = *(float4*)&wk_s[d];
    }

    // ---- fused ab (R17): A_c, B_c from LDS-resident k_s/wk_s/wv_s ----
    {
        const int k0q = tid >> 4;            // col chunk 0..15
        const int k0 = k0q * 4;
        const int m0 = (tid & 15) * 4;
        const int p = tid & 15;              // panel index = m0>>2
        const float ebC = __expf(b_s[63]);
        float aA[4][4] = {};
        float aB[4][4] = {};
        for (int ss = 0; ss < 64; ss += 4) {
            float4 kf0 = *(const float4*)&k_s[(ss + 0) * PAD + ((((ss + 0) >> 2) ^ k0q) << 2)];
            float4 kf1 = *(const float4*)&k_s[(ss + 1) * PAD + ((((ss + 1) >> 2) ^ k0q) << 2)];
            float4 kf2 = *(const float4*)&k_s[(ss + 2) * PAD + ((((ss + 2) >> 2) ^ k0q) << 2)];
            float4 kf3 = *(const float4*)&k_s[(ss + 3) * PAD + ((((ss + 3) >> 2) ^ k0q) << 2)];
            const float e0 = e_s[ss + 0], e1 = e_s[ss + 1];
            const float e2 = e_s[ss + 2], e3 = e_s[ss + 3];
            kf0.x *= e0; kf0.y *= e0; kf0.z *= e0; kf0.w *= e0;
            kf1.x *= e1; kf1.y *= e1; kf1.z *= e1; kf1.w *= e1;
            kf2.x *= e2; kf2.y *= e2; kf2.z *= e2; kf2.w *= e2;
            kf3.x *= e3; kf3.y *= e3; kf3.z *= e3; kf3.w *= e3;
            float4 wa0 = *(const float4*)&wk_s[(ss + 0) * PAD + m0];
            float4 wa1 = *(const float4*)&wk_s[(ss + 1) * PAD + m0];
            float4 wa2 = *(const float4*)&wk_s[(ss + 2) * PAD + m0];
            float4 wa3 = *(const float4*)&wk_s[(ss + 3) * PAD + m0];
            float4 wb0 = *(const float4*)&wv_s[(ss + 0) * PAD + m0];
            float4 wb1 = *(const float4*)&wv_s[(ss + 1) * PAD + m0];
            float4 wb2 = *(const float4*)&wv_s[(ss + 2) * PAD + m0];
            float4 wb3 = *(const float4*)&wv_s[(ss + 3) * PAD + m0];
            OUT16(aA, kf0, wa0); OUT16(aA, kf1, wa1); OUT16(aA, kf2, wa2); OUT16(aA, kf3, wa3);
            OUT16(aB, kf0, wb0); OUT16(aB, kf1, wb1); OUT16(aB, kf2, wb2); OUT16(aB, kf3, wb3);
        }

        float* Ag = Ab + (size_t)blk * 4096;
        float* Bg = Bb + (size_t)blk * 4096;
#pragma unroll
        for (int i = 0; i < 4; ++i) {
            const int kk = k0 + i;
            float4 av = make_float4(-aA[i][0], -aA[i][1], -aA[i][2], -aA[i][3]);
            if (kk - m0 == 0) av.x += ebC;
            if (kk - m0 == 1) av.y += ebC;
            if (kk - m0 == 2) av.z += ebC;
            if (kk - m0 == 3) av.w += ebC;
            *(float4*)&Ag[p * 256 + kk * 4] = av;   // panel-transposed (R11)
            *(float4*)&Bg[kk * 64 + m0] = make_float4(aB[i][0], aB[i][1], aB[i][2], aB[i][3]);
        }
    }
}

// ---------------------------------------------------------------------------
// Phase B2 (R15): serial chunk recurrence h' = A_c h + B_c. (unchanged)
// ---------------------------------------------------------------------------
__global__ __launch_bounds__(64, 1) void hrec_k(const float* __restrict__ Ab,
                                                const float* __restrict__ Bb,
                                                float* __restrict__ Hst) {
    const int blk = blockIdx.x;
    const int bh = blk & 31;          // vs-major: same-bh blocks -> same XCD
    const int vs = blk >> 5;          // 0..VS-1
    const int k = threadIdx.x;

    __shared__ __align__(16) float A_lds[2][4096];
    __shared__ __align__(16) float h_s[4][64];

#pragma unroll
    for (int j = 0; j < 4; ++j) h_s[j][k] = 0.0f;
    float h0 = 0, h1 = 0, h2 = 0, h3 = 0;

    const float* Abase = Ab + (size_t)bh * NC * 4096;
    const float* Bbase = Bb + (size_t)bh * NC * 4096 + k * 64 + vs * 4;
    float* Hbase = Hst + (size_t)bh * NC * 4096 + k * 64 + vs * 4;

    // per-lane LDS read pointers (AS3, 32-bit)
    const LAS float* rd_cur = (const LAS float*)&A_lds[0][0] + k * 4;
    const LAS float* rd_nxt = (const LAS float*)&A_lds[1][0] + k * 4;
    const LAS float* hp = (const LAS float*)&h_s[0][0];   // uniform h base

    // prologue: stage A(0) into buf0, B(0) -> register
#pragma unroll
    for (int i = 0; i < 16; ++i)
        __builtin_amdgcn_global_load_lds((const GAS unsigned int*)(Abase + i * 256 + k * 4),
                                         (LAS unsigned int*)&A_lds[0][i * 256], 16, 0, 0);
    float4 bn = *(const float4*)&Bbase[0];

#define ARD(DST, OFF) asm volatile("ds_read_b128 %0, %1 offset:" OFF \
                                   : "=v"(DST) : "v"(rd_cur))
#define HRD(DST, OFF) asm volatile("ds_read_b128 %0, %1 offset:" OFF \
                                   : "=v"(DST) : "v"(hp) : "memory")
#define FMAG(AR, H0, H1, H2, H3) \
    a0 += AR[0]*H0[0] + AR[1]*H0[1] + AR[2]*H0[2] + AR[3]*H0[3]; \
    a1 += AR[0]*H1[0] + AR[1]*H1[1] + AR[2]*H1[2] + AR[3]*H1[3]; \
    a2 += AR[0]*H2[0] + AR[1]*H2[1] + AR[2]*H2[2] + AR[3]*H2[3]; \
    a3 += AR[0]*H3[0] + AR[1]*H3[1] + AR[2]*H3[2] + AR[3]*H3[3];
#define WAIT10 asm volatile("s_waitcnt lgkmcnt(10)" ::: "memory"); \
               __builtin_amdgcn_sched_barrier(0);

#pragma unroll 1
    for (int c = 0; c < NC; ++c) {
        float4 b0 = bn;

        // chunk-start state (pre-update); fire-and-forget store
        *(float4*)&Hbase[(size_t)c * 4096] = make_float4(h0, h1, h2, h3);

        if (c + 1 < NC) {
            const float* An = Abase + (size_t)(c + 1) * 4096;
#pragma unroll
            for (int i = 0; i < 16; ++i)
                __builtin_amdgcn_global_load_lds((const GAS unsigned int*)(An + i * 256 + k * 4),
                                                 (LAS unsigned int*)(rd_nxt - (size_t)k * 4 + i * 256),
                                                 16, 0, 0);
            bn = *(const float4*)&Bbase[(size_t)(c + 1) * 4096];
            // newest 18 (H-store + 16 A-lds + 1 B) stay in flight
            asm volatile("s_waitcnt vmcnt(18)" ::: "memory");
        } else {
            asm volatile("s_waitcnt vmcnt(1)" ::: "memory");
        }
        __builtin_amdgcn_sched_barrier(0);

        f32x4 ar0, ar1, ar2, ar3, ar4, ar5, ar6, ar7;
        f32x4 ar8, ar9, ar10, ar11, ar12, ar13, ar14, ar15;
        f32x4 ha0, ha1, ha2, ha3, ha4, ha5, ha6, ha7;   // bank A (even batch)
        f32x4 hb0, hb1, hb2, hb3, hb4, hb5, hb6, hb7;   // bank B (odd batch)

        // batch0 (m4 0,1) + ar0,ar1 ; batch1 (m4 2,3) + ar2,ar3  -> 20 out
        HRD(ha0, "0");   HRD(ha1, "256"); HRD(ha2, "512"); HRD(ha3, "768");
        HRD(ha4, "16");  HRD(ha5, "272"); HRD(ha6, "528"); HRD(ha7, "784");
        ARD(ar0, "0");   ARD(ar1, "1024");
        HRD(hb0, "32");  HRD(hb1, "288"); HRD(hb2, "544"); HRD(hb3, "800");
        HRD(hb4, "48");  HRD(hb5, "304"); HRD(hb6, "560"); HRD(hb7, "816");
        ARD(ar2, "2048"); ARD(ar3, "3072");
        WAIT10   // batch0 + ar0,ar1 done; batch1+ar2,ar3 in flight

        float a0 = b0.x, a1 = b0.y, a2 = b0.z, a3 = b0.w;
        // sub0: m4 0,1
        FMAG(ar0, ha0, ha1, ha2, ha3)
        FMAG(ar1, ha4, ha5, ha6, ha7)
        HRD(ha0, "64");  HRD(ha1, "320"); HRD(ha2, "576"); HRD(ha3, "832");
        HRD(ha4, "80");  HRD(ha5, "336"); HRD(ha6, "592"); HRD(ha7, "848");
        ARD(ar4, "4096"); ARD(ar5, "5120");
        WAIT10
        // sub1: m4 2,3
        FMAG(ar2, hb0, hb1, hb2, hb3)
        FMAG(ar3, hb4, hb5, hb6, hb7)
        HRD(hb0, "96");  HRD(hb1, "352"); HRD(hb2, "608"); HRD(hb3, "864");
        HRD(hb4, "112"); HRD(hb5, "368"); HRD(hb6, "624"); HRD(hb7, "880");
        ARD(ar6, "6144"); ARD(ar7, "7168");
        WAIT10
        // sub2: m4 4,5
        FMAG(ar4, ha0, ha1, ha2, ha3)
        FMAG(ar5, ha4, ha5, ha6, ha7)
        HRD(ha0, "128"); HRD(ha1, "384"); HRD(ha2, "640"); HRD(ha3, "896");
        HRD(ha4, "144"); HRD(ha5, "400"); HRD(ha6, "656"); HRD(ha7, "912");
        ARD(ar8, "8192"); ARD(ar9, "9216");
        WAIT10
        // sub3: m4 6,7
        FMAG(ar6, hb0, hb1, hb2, hb3)
        FMAG(ar7, hb4, hb5, hb6, hb7)
        HRD(hb0, "160"); HRD(hb1, "416"); HRD(hb2, "672"); HRD(hb3, "928");
        HRD(hb4, "176"); HRD(hb5, "432"); HRD(hb6, "688"); HRD(hb7, "944");
        ARD(ar10, "10240"); ARD(ar11, "11264");
        WAIT10
        // sub4: m4 8,9
        FMAG(ar8, ha0, ha1, ha2, ha3)
        FMAG(ar9, ha4, ha5, ha6, ha7)
        HRD(ha0, "192"); HRD(ha1, "448"); HRD(ha2, "704"); HRD(ha3, "960");
        HRD(ha4, "208"); HRD(ha5, "464"); HRD(ha6, "720"); HRD(ha7, "976");
        ARD(ar12, "12288"); ARD(ar13, "13312");
        WAIT10
        // sub5: m4 10,11
        FMAG(ar10, hb0, hb1, hb2, hb3)
        FMAG(ar11, hb4, hb5, hb6, hb7)
        HRD(hb0, "224"); HRD(hb1, "480"); HRD(hb2, "736"); HRD(hb3, "992");
        HRD(hb4, "240"); HRD(hb5, "496"); HRD(hb6, "752"); HRD(hb7, "1008");
        ARD(ar14, "14336"); ARD(ar15, "15360");
        WAIT10
        // sub6: m4 12,13
        FMAG(ar12, ha0, ha1, ha2, ha3)
        FMAG(ar13, ha4, ha5, ha6, ha7)
        asm volatile("s_waitcnt lgkmcnt(0)" ::: "memory");
        __builtin_amdgcn_sched_barrier(0);
        // sub7: m4 14,15
        FMAG(ar14, hb0, hb1, hb2, hb3)
        FMAG(ar15, hb4, hb5, hb6, hb7)

        h0 = a0; h1 = a1; h2 = a2; h3 = a3;
        h_s[0][k] = h0; h_s[1][k] = h1; h_s[2][k] = h2; h_s[3][k] = h3;
        // per-wave DS ops execute in order at the LDS unit: next iteration's
        // HRD reads (memory-clobbered asm) see these writes.

        const LAS float* t = rd_cur; rd_cur = rd_nxt; rd_nxt = (LAS float*)t;
    }
#undef ARD
#undef HRD
#undef FMAG
#undef WAIT10
}

// ---------------------------------------------------------------------------
// Phase B3: W_c = Wv_c - Wk_c h0_c (unchanged)
// ---------------------------------------------------------------------------
__global__ __launch_bounds__(256) void wfix_k(const float* __restrict__ Wk,
                                              const float* __restrict__ Hst,
                                              float* __restrict__ Wio) {
    __shared__ __align__(16) float wk_s[CL * PAD];
    __shared__ __align__(16) float h_s[CL * PAD];

    const int blk = blockIdx.x;
    const int tid = threadIdx.x;

    {
        const float4* Wkg = (const float4*)(Wk + (size_t)blk * 4096);
        const float4* Hg = (const float4*)(Hst + (size_t)blk * 4096);
#pragma unroll
        for (int i = 0; i < 4; ++i) {
            int f = tid + i * 256;
            int d = (f >> 4) * PAD + (f & 15) * 4;
            *(float4*)&wk_s[d] = Wkg[f];
            *(float4*)&h_s[d] = Hg[f];
        }
    }
    __syncthreads();

    const int t0 = (tid >> 4) * 4, v0 = (tid & 15) * 4;
    float* Wg = Wio + (size_t)blk * 4096;

    float acc[4][4];
#pragma unroll
    for (int i = 0; i < 4; ++i) {
        float4 wv = *(const float4*)&Wg[(t0 + i) * 64 + v0];
        acc[i][0] = wv.x; acc[i][1] = wv.y; acc[i][2] = wv.z; acc[i][3] = wv.w;
    }
    for (int kk = 0; kk < 64; kk += 4) {
        float4 wa0 = *(const float4*)&wk_s[(t0 + 0) * PAD + kk];
        float4 wa1 = *(const float4*)&wk_s[(t0 + 1) * PAD + kk];
        float4 wa2 = *(const float4*)&wk_s[(t0 + 2) * PAD + kk];
        float4 wa3 = *(const float4*)&wk_s[(t0 + 3) * PAD + kk];
        float4 hb0 = *(const float4*)&h_s[(kk + 0) * PAD + v0];
        float4 hb1 = *(const float4*)&h_s[(kk + 1) * PAD + v0];
        float4 hb2 = *(const float4*)&h_s[(kk + 2) * PAD + v0];
        float4 hb3 = *(const float4*)&h_s[(kk + 3) * PAD + v0];
        WSUB(x, hb0); WSUB(y, hb1); WSUB(z, hb2); WSUB(w, hb3);
    }
#pragma unroll
    for (int i = 0; i < 4; ++i)
        *(float4*)&Wg[(t0 + i) * 64 + v0] =
            make_float4(acc[i][0], acc[i][1], acc[i][2], acc[i][3]);
}

// ---------------------------------------------------------------------------
// Phase C (R19): XOR chunk-swizzle on s_s (R16) + FUSED gated RMSNorm
// epilogue (was gnorm_k). Each thread holds rows t0..t0+3 x cols v0..v0+3;
// the row sum-of-squares is a 16-lane shfl_xor tree over qcol (lane bits
// 0-3, within one wave). Writes bf16 o2 directly — o_scan round-trip and
// the gnorm dispatch are eliminated. RMS sum reassociates (4-wide partial
// + 16-lane tree vs 64-lane tree): ~1e-7 relative, invisible at bf16.
// ---------------------------------------------------------------------------
__global__ __launch_bounds__(256) void out_k(const float* __restrict__ Qc,
                                             const float* __restrict__ Kc,
                                             const float* __restrict__ Wb_,
                                             const float* __restrict__ Hst,
                                             const float* __restrict__ bcum,
                                             const float* __restrict__ gate,
                                             const float* __restrict__ rms_w,
                                             unsigned short* __restrict__ o2) {
    __shared__ __align__(16) float q_s[CL * PAD];
    __shared__ __align__(16) float s_s[CL * PAD];   // K, then S (swizzled)
    __shared__ __align__(16) float h_s[CL * PAD];
    __shared__ __align__(16) float w_s[CL * PAD];
    __shared__ float b_s[64];

    const int blk = blockIdx.x;
    const int bh = blk >> 5;
    const int c = blk & 31;
    const int b = bh >> 4;
    const int h = bh & 15;
    const int tid = threadIdx.x;

    if (tid < 64) b_s[tid] = bcum[(size_t)blk * 64 + tid];
    {
        const float4* Qg = (const float4*)(Qc + (size_t)blk * 4096);
        const float4* Kg = (const float4*)(Kc + (size_t)blk * 4096);
        const float4* Hg = (const float4*)(Hst + (size_t)blk * 4096);
        const float4* Wg = (const float4*)(Wb_ + (size_t)blk * 4096);
#pragma unroll
        for (int i = 0; i < 4; ++i) {
            int f = tid + i * 256;
            int t = f >> 4;
            int c4 = f & 15;
            int d = t * PAD + c4 * 4;
            int dsz = t * PAD + ((c4 ^ (t >> 2)) << 2);     // s_s swizzled
            *(float4*)&q_s[d] = Qg[f];
            *(float4*)&s_s[dsz] = Kg[f];
            *(float4*)&h_s[d] = Hg[f];
            *(float4*)&w_s[d] = Wg[f];
        }
    }
    __syncthreads();

    // Phase 1: S = (Q K^T) ⊙ exp(b_t - b_s) [s<=t], overwrite s_s
    const int qrow = tid >> 4;          // = (t0+i)>>2
    const int qcol = tid & 15;          // = (s0+j)>>2
    {
        const int t0 = qrow * 4, s0 = qcol * 4;
        float acc[4][4] = {};
        for (int kk = 0; kk < 64; kk += 4) {
            const int kb = ((kk >> 2) ^ qcol) << 2;
            float4 ta0 = *(const float4*)&q_s[(t0 + 0) * PAD + kk];
            float4 ta1 = *(const float4*)&q_s[(t0 + 1) * PAD + kk];
            float4 ta2 = *(const float4*)&q_s[(t0 + 2) * PAD + kk];
            float4 ta3 = *(const float4*)&q_s[(t0 + 3) * PAD + kk];
            float4 sb0 = *(const float4*)&s_s[(s0 + 0) * PAD + kb];
            float4 sb1 = *(const float4*)&s_s[(s0 + 1) * PAD + kb];
            float4 sb2 = *(const float4*)&s_s[(s0 + 2) * PAD + kb];
            float4 sb3 = *(const float4*)&s_s[(s0 + 3) * PAD + kb];
            acc[0][0] += DOT4(ta0, sb0); acc[0][1] += DOT4(ta0, sb1);
            acc[0][2] += DOT4(ta0, sb2); acc[0][3] += DOT4(ta0, sb3);
            acc[1][0] += DOT4(ta1, sb0); acc[1][1] += DOT4(ta1, sb1);
            acc[1][2] += DOT4(ta1, sb2); acc[1][3] += DOT4(ta1, sb3);
            acc[2][0] += DOT4(ta2, sb0); acc[2][1] += DOT4(ta2, sb1);
            acc[2][2] += DOT4(ta2, sb2); acc[2][3] += DOT4(ta2, sb3);
            acc[3][0] += DOT4(ta3, sb0); acc[3][1] += DOT4(ta3, sb1);
            acc[3][2] += DOT4(ta3, sb2); acc[3][3] += DOT4(ta3, sb3);
        }
        __syncthreads();   // all Q,K reads done before overwrite
#pragma unroll
        for (int i = 0; i < 4; ++i)
#pragma unroll
            for (int j = 0; j < 4; ++j) {
                const int t = t0 + i, s = s0 + j;
                // swizzled scalar store: chunk (s>>2)=qcol XOR (t>>2)=qrow
                s_s[t * PAD + ((qcol ^ qrow) << 2) + (s & 3)] =
                    (s <= t) ? acc[i][j] * __expf(b_s[t] - b_s[s]) : 0.0f;
            }
    }
    // scale q rows by e^{b_t}  (q_s plain)
#pragma unroll
    for (int i = 0; i < 16; ++i) {
        const int e = tid + i * 256;
        const int t = e >> 6;
        q_s[t * PAD + (e & 63)] *= __expf(b_s[t]);
    }
    __syncthreads();

    // Phase 2: O = S @ W + Qs @ H, then fused gated RMSNorm -> bf16
    {
        const int t0 = qrow * 4, v0 = qcol * 4;
        float acc[4][4] = {};
        for (int ss = 0; ss < 64; ss += 4) {
            const int ks = ((ss >> 2) ^ qrow) << 2;   // s_s swizzled read
            float4 sa0 = *(const float4*)&s_s[(t0 + 0) * PAD + ks];
            float4 sa1 = *(const float4*)&s_s[(t0 + 1) * PAD + ks];
            float4 sa2 = *(const float4*)&s_s[(t0 + 2) * PAD + ks];
            float4 sa3 = *(const float4*)&s_s[(t0 + 3) * PAD + ks];
            float4 wb0 = *(const float4*)&w_s[(ss + 0) * PAD + v0];
            float4 wb1 = *(const float4*)&w_s[(ss + 1) * PAD + v0];
            float4 wb2 = *(const float4*)&w_s[(ss + 2) * PAD + v0];
            float4 wb3 = *(const float4*)&w_s[(ss + 3) * PAD + v0];
            ACC16(x, wb0); ACC16(y, wb1); ACC16(z, wb2); ACC16(w, wb3);
        }
        for (int kk = 0; kk < 64; kk += 4) {
            float4 sa0 = *(const float4*)&q_s[(t0 + 0) * PAD + kk];
            float4 sa1 = *(const float4*)&q_s[(t0 + 1) * PAD + kk];
            float4 sa2 = *(const float4*)&q_s[(t0 + 2) * PAD + kk];
            float4 sa3 = *(const float4*)&q_s[(t0 + 3) * PAD + kk];
            float4 wb0 = *(const float4*)&h_s[(kk + 0) * PAD + v0];
            float4 wb1 = *(const float4*)&h_s[(kk + 1) * PAD + v0];
            float4 wb2 = *(const float4*)&h_s[(kk + 2) * PAD + v0];
            float4 wb3 = *(const float4*)&h_s[(kk + 3) * PAD + v0];
            ACC16(x, wb0); ACC16(y, wb1); ACC16(z, wb2); ACC16(w, wb3);
        }

        // fused gated RMSNorm epilogue (R19)
        const float4 rw = *(const float4*)&rms_w[v0];
#pragma unroll
        for (int i = 0; i < 4; ++i) {
            float ss2 = acc[i][0] * acc[i][0] + acc[i][1] * acc[i][1]
                      + acc[i][2] * acc[i][2] + acc[i][3] * acc[i][3];
            ss2 += __shfl_xor(ss2, 1);
            ss2 += __shfl_xor(ss2, 2);
            ss2 += __shfl_xor(ss2, 4);
            ss2 += __shfl_xor(ss2, 8);
            const float r = rsqrtf(ss2 * (1.0f / 64.0f) + 1e-5f);
            const int t = c * CL + t0 + i;
            const size_t row = (size_t)b * TT + t;
            const float4 gt = *(const float4*)&gate[row * HD + h * DK + v0];
            u16x4 o;
            o[0] = f2bf(acc[i][0] * r * rw.x * siluf_(gt.x));
            o[1] = f2bf(acc[i][1] * r * rw.y * siluf_(gt.y));
            o[2] = f2bf(acc[i][2] * r * rw.z * siluf_(gt.z));
            o[3] = f2bf(acc[i][3] * r * rw.w * siluf_(gt.w));
            *(u16x4*)&o2[row * HD + h * DK + v0] = o;
        }
    }
}

// ---------------------------------------------------------------------------
extern "C" void kernel_launch(void* const* d_in, const int* in_sizes, int n_in,
                              void* d_out, int out_size, void* d_ws, size_t ws_size,
                              hipStream_t stream) {
    (void)in_sizes; (void)n_in; (void)out_size; (void)ws_size;

    const float* x       = (const float*)d_in[0];
    const float* Wq      = (const float*)d_in[1];
    const float* Wk_     = (const float*)d_in[2];
    const float* Wv_     = (const float*)d_in[3];
    const float* Wa      = (const float*)d_in[4];
    const float* Wb      = (const float*)d_in[5];
    const float* Wg      = (const float*)d_in[6];
    const float* Wo      = (const float*)d_in[7];
    const float* conv_q  = (const float*)d_in[8];
    const float* conv_k  = (const float*)d_in[9];
    const float* conv_v  = (const float*)d_in[10];
    const float* A_log   = (const float*)d_in[11];
    const float* dt_bias = (const float*)d_in[12];
    const float* rms_w   = (const float*)d_in[13];
    float* out = (float*)d_out;

    float* ws = (float*)d_ws;
    const size_t NTOK = (size_t)BB * TT;     // 4096
    const size_t BIG = NTOK * HD;            // 4 Mi floats

    float* q_pre = ws + 0 * BIG;
    float* k_pre = ws + 1 * BIG;
    float* v_pre = ws + 2 * BIG;
    float* gatep = ws + 3 * BIG;
    float* Qc    = ws + 4 * BIG;
    float* Kc    = ws + 5 * BIG;
    float* gbuf  = ws + 6 * BIG;
    float* bbuf  = gbuf + NTOK * HH;
    float* bcumb = bbuf + NTOK * HH;

    // bf16 buffers after the fp32 region (wqt..wgt contiguous = fused B matrix)
    unsigned short* xb  = (unsigned short*)(bcumb + NTOK * HH);
    unsigned short* wqt = xb + (size_t)NTOK * DD;
    unsigned short* wkt = wqt + (size_t)DD * HD;
    unsigned short* wvt = wkt + (size_t)DD * HD;
    unsigned short* wgt = wvt + (size_t)DD * HD;
    unsigned short* wot = wgt + (size_t)DD * HD;

    // fp32 buffers after bf16 region: Bb + Hst (32 MB) + Wab_t (128 KB)
    float* Bbuf = (float*)(wot + (size_t)DD * HD);
    float* HstB = Bbuf + BIG;
    float* Wabt = HstB + BIG;

    // aliases (stream-ordered lifetimes):
    float* Wvb    = q_pre;   // prep_k out; wfix_k rewrites in place to W
    float* Wkb    = k_pre;
    // A buffer aliases the xb/wqt region (dead after gemm_qkvg_k).
    float* Abuf   = (float*)xb;
    // R19: o2 (bf16 output of fused out_k) aliases Abuf (dead after hrec_k);
    // disjoint from wot (starts after wgt) and from Qc/Kc (still read).
    unsigned short* o2b = (unsigned short*)Abuf;

    // casts
    castx_k<<<(int)(NTOK * DD / (256 * 8)), 256, 0, stream>>>(x, xb);
    dim3 tg(16, 16);
    castw_k<<<tg, 256, 0, stream>>>(Wq, wqt);
    castw_k<<<tg, 256, 0, stream>>>(Wk_, wkt);
    castw_k<<<tg, 256, 0, stream>>>(Wv_, wvt);
    castw_k<<<tg, 256, 0, stream>>>(Wg, wgt);
    castw_k<<<tg, 256, 0, stream>>>(Wo, wot);
    tw_k<<<32, 256, 0, stream>>>(Wa, Wb, Wabt);

    // fused QKVG projection: 256 blocks x 512 threads (256^2 8-phase, R13)
    gemm_qkvg_k<<<256, 512, 0, stream>>>(xb, wqt, q_pre, k_pre, v_pre, gatep);

    gbeta_k<<<(int)(NTOK / 8), 256, 0, stream>>>(x, Wabt, A_log, dt_bias, gbuf, bbuf);

    stage_k<<<BB * HH * NC, 64, 0, stream>>>(q_pre, k_pre, conv_q, conv_k, gbuf,
                                             Qc, Kc, bcumb);

    // prep_k (256 threads, R17-verbatim) also emits A_c/B_c
    prep_k<<<BB * HH * NC, 256, 0, stream>>>(Kc, v_pre, conv_v, bcumb, bbuf,
                                             Wvb, Wkb, Abuf, Bbuf);

    hrec_k<<<BB * HH * VS, 64, 0, stream>>>(Abuf, Bbuf, HstB);
    wfix_k<<<BB * HH * NC, 256, 0, stream>>>(Wkb, HstB, Wvb);

    // out_k now fuses the gated RMSNorm and writes bf16 o2 directly (R19)
    out_k<<<BB * HH * NC, 256, 0, stream>>>(Qc, Kc, Wvb, HstB, bcumb,
                                            gatep, rms_w, o2b);

    gemm_bf16_k<<<dim3(HD / 128, NTOK / 128), 256, 0, stream>>>(o2b, wot, out,
                                                                (int)NTOK, HD, DD);
}

// Round 10
// 415.913 us; speedup vs baseline: 1.2579x; 1.0191x over previous
//
#include <hip/hip_runtime.h>
#include <hip/hip_bf16.h>
#include <math.h>
#include <stdint.h>

// Problem constants
#define BB 2
#define TT 2048
#define DD 1024
#define HH 16
#define DK 64
#define HD 1024   // H*DK
#define NC 32     // chunks per sequence (TT/64)
#define CL 64     // chunk length
#define PAD 68    // padded LDS row stride (floats)
#define PADA 67   // A_s row stride (R16)
#define VS 16     // v-splits in hrec_k

typedef short bf16x8 __attribute__((ext_vector_type(8)));     // 8 bf16 (4 VGPRs)
typedef float f32x4 __attribute__((ext_vector_type(4)));      // MFMA acc
typedef unsigned short u16x8 __attribute__((ext_vector_type(8)));
typedef unsigned short u16x4 __attribute__((ext_vector_type(4)));

#define GAS __attribute__((address_space(1)))
#define LAS __attribute__((address_space(3)))

#define DOT4(a, b) ((a).x*(b).x + (a).y*(b).y + (a).z*(b).z + (a).w*(b).w)

// acc[i][j] += kf[i-component] * wv[j-component]   (one contraction step)
#define OUT16(acc, kf, wv) \
    acc[0][0] += kf.x * wv.x; acc[0][1] += kf.x * wv.y; acc[0][2] += kf.x * wv.z; acc[0][3] += kf.x * wv.w; \
    acc[1][0] += kf.y * wv.x; acc[1][1] += kf.y * wv.y; acc[1][2] += kf.y * wv.z; acc[1][3] += kf.y * wv.w; \
    acc[2][0] += kf.z * wv.x; acc[2][1] += kf.z * wv.y; acc[2][2] += kf.z * wv.z; acc[2][3] += kf.z * wv.w; \
    acc[3][0] += kf.w * wv.x; acc[3][1] += kf.w * wv.y; acc[3][2] += kf.w * wv.z; acc[3][3] += kf.w * wv.w;

// acc[i][j] -= wa_i.c * hv[j]   (c = component selecting m)
#define WSUB(c, hv) \
    acc[0][0] -= wa0.c * hv.x; acc[0][1] -= wa0.c * hv.y; acc[0][2] -= wa0.c * hv.z; acc[0][3] -= wa0.c * hv.w; \
    acc[1][0] -= wa1.c * hv.x; acc[1][1] -= wa1.c * hv.y; acc[1][2] -= wa1.c * hv.z; acc[1][3] -= wa1.c * hv.w; \
    acc[2][0] -= wa2.c * hv.x; acc[2][1] -= wa2.c * hv.y; acc[2][2] -= wa2.c * hv.z; acc[2][3] -= wa2.c * hv.w; \
    acc[3][0] -= wa3.c * hv.x; acc[3][1] -= wa3.c * hv.y; acc[3][2] -= wa3.c * hv.z; acc[3][3] -= wa3.c * hv.w;

// acc[i][j] += sa_i.c * wv[j]   (c = component selecting the contraction idx)
#define ACC16(c, wv) \
    acc[0][0] += sa0.c * wv.x; acc[0][1] += sa0.c * wv.y; acc[0][2] += sa0.c * wv.z; acc[0][3] += sa0.c * wv.w; \
    acc[1][0] += sa1.c * wv.x; acc[1][1] += sa1.c * wv.y; acc[1][2] += sa1.c * wv.z; acc[1][3] += sa1.c * wv.w; \
    acc[2][0] += sa2.c * wv.x; acc[2][1] += sa2.c * wv.y; acc[2][2] += sa2.c * wv.z; acc[2][3] += sa2.c * wv.w; \
    acc[3][0] += sa3.c * wv.x; acc[3][1] += sa3.c * wv.y; acc[3][2] += sa3.c * wv.z; acc[3][3] += sa3.c * wv.w;

__device__ __forceinline__ float sigmoidf_(float x) { return 1.0f / (1.0f + expf(-x)); }
__device__ __forceinline__ float siluf_(float x) { return x * sigmoidf_(x); }

// round-to-nearest-even fp32 -> bf16
__device__ __forceinline__ unsigned short f2bf(float f) {
    unsigned int u = __builtin_bit_cast(unsigned int, f);
    u = (u + 0x7fffu + ((u >> 16) & 1u)) >> 16;
    return (unsigned short)u;
}

// ---------------------------------------------------------------------------
// Cast x (fp32) -> bf16, flat.
// ---------------------------------------------------------------------------
__global__ __launch_bounds__(256) void castx_k(const float* __restrict__ src,
                                               unsigned short* __restrict__ dst) {
    const size_t idx = (size_t)blockIdx.x * 256 + threadIdx.x;
    float4 a = *(const float4*)&src[idx * 8];
    float4 b = *(const float4*)&src[idx * 8 + 4];
    u16x8 o;
    o[0] = f2bf(a.x); o[1] = f2bf(a.y); o[2] = f2bf(a.z); o[3] = f2bf(a.w);
    o[4] = f2bf(b.x); o[5] = f2bf(b.y); o[6] = f2bf(b.z); o[7] = f2bf(b.w);
    *(u16x8*)&dst[idx * 8] = o;
}

// ---------------------------------------------------------------------------
// Transpose+cast weight: W[K=1024][N=1024] fp32 -> Wt[N][K] bf16.
// ---------------------------------------------------------------------------
__global__ __launch_bounds__(256) void castw_k(const float* __restrict__ W,
                                               unsigned short* __restrict__ Wt) {
    __shared__ float t_s[64][65];
    const int tid = threadIdx.x;
    const int rr = tid >> 4;
    const int cc = tid & 15;
    const int r0 = blockIdx.y * 64;
    const int c0 = blockIdx.x * 64;
#pragma unroll
    for (int i = 0; i < 4; ++i) {
        const int row = rr + i * 16;
        float4 v = *(const float4*)&W[(size_t)(r0 + row) * 1024 + c0 + cc * 4];
        t_s[row][cc * 4 + 0] = v.x;
        t_s[row][cc * 4 + 1] = v.y;
        t_s[row][cc * 4 + 2] = v.z;
        t_s[row][cc * 4 + 3] = v.w;
    }
    __syncthreads();
#pragma unroll
    for (int i = 0; i < 4; ++i) {
        const int nr = rr + i * 16;
        u16x4 o;
#pragma unroll
        for (int d = 0; d < 4; ++d) o[d] = f2bf(t_s[cc * 4 + d][nr]);
        *(u16x4*)&Wt[(size_t)(c0 + nr) * 1024 + r0 + cc * 4] = o;
    }
}

// ---------------------------------------------------------------------------
// transpose Wa|Wb [1024][16] -> Wab_t [32][1024] fp32 (R8)
// ---------------------------------------------------------------------------
__global__ __launch_bounds__(256) void tw_k(const float* __restrict__ Wa,
                                            const float* __restrict__ Wb,
                                            float* __restrict__ Wt) {
    const int o = blockIdx.x;          // 0..31
    const int h = o & 15;
    const float* W = (o < 16) ? Wa : Wb;
    const int tid = threadIdx.x;
    float4 v;
    v.x = W[(size_t)(tid * 4 + 0) * HH + h];
    v.y = W[(size_t)(tid * 4 + 1) * HH + h];
    v.z = W[(size_t)(tid * 4 + 2) * HH + h];
    v.w = W[(size_t)(tid * 4 + 3) * HH + h];
    *(float4*)&Wt[(size_t)o * DD + tid * 4] = v;
}

// ---------------------------------------------------------------------------
// bf16 MFMA GEMM (m97 structure) — generic single-output (used for Wo).
// ---------------------------------------------------------------------------
__global__ __launch_bounds__(256) void gemm_bf16_k(const unsigned short* __restrict__ A,
                                                   const unsigned short* __restrict__ Bt,
                                                   float* __restrict__ C,
                                                   int M, int N, int Kd) {
    __shared__ unsigned short a_s[128 * 32];
    __shared__ unsigned short b_s[128 * 32];

    const int tid = threadIdx.x;
    const int wave = tid >> 6;
    const int lane = tid & 63;
    const int m0 = blockIdx.y * 128;
    const int n0 = blockIdx.x * 128;

    const int quad = lane >> 4;
    const int l16 = lane & 15;
    const int wr = wave >> 1;
    const int wc = wave & 1;

    const int srow = lane >> 2;
    const int sseg = lane & 3;

    f32x4 acc[4][4];
#pragma unroll
    for (int i = 0; i < 4; ++i)
#pragma unroll
        for (int j = 0; j < 4; ++j) acc[i][j] = (f32x4){0.f, 0.f, 0.f, 0.f};

    for (int k0 = 0; k0 < Kd; k0 += 32) {
        __syncthreads();
#pragma unroll
        for (int c = 0; c < 2; ++c) {
            const int region = wave * 2 + c;
            const int r0t = region * 16;
            const int ra = r0t + srow;
            const unsigned short* ga = A + (size_t)(m0 + ra) * Kd + k0 + sseg * 8;
            const unsigned short* gb = Bt + (size_t)(n0 + ra) * Kd + k0 + sseg * 8;
            __builtin_amdgcn_global_load_lds((const GAS unsigned int*)ga,
                                             (LAS unsigned int*)&a_s[r0t * 32], 16, 0, 0);
            __builtin_amdgcn_global_load_lds((const GAS unsigned int*)gb,
                                             (LAS unsigned int*)&b_s[r0t * 32], 16, 0, 0);
        }
        __syncthreads();

        bf16x8 af[4], bfr[4];
#pragma unroll
        for (int i = 0; i < 4; ++i)
            af[i] = *(const bf16x8*)&a_s[(wr * 64 + i * 16 + l16) * 32 + quad * 8];
#pragma unroll
        for (int j = 0; j < 4; ++j)
            bfr[j] = *(const bf16x8*)&b_s[(wc * 64 + j * 16 + l16) * 32 + quad * 8];
#pragma unroll
        for (int i = 0; i < 4; ++i)
#pragma unroll
            for (int j = 0; j < 4; ++j)
                acc[i][j] = __builtin_amdgcn_mfma_f32_16x16x32_bf16(af[i], bfr[j], acc[i][j], 0, 0, 0);
    }

#pragma unroll
    for (int i = 0; i < 4; ++i)
#pragma unroll
        for (int j = 0; j < 4; ++j) {
            const int col = n0 + wc * 64 + j * 16 + l16;
#pragma unroll
            for (int r = 0; r < 4; ++r) {
                const int row = m0 + wr * 64 + i * 16 + quad * 4 + r;
                C[(size_t)row * N + col] = acc[i][j][r];
            }
        }
}

// ---------------------------------------------------------------------------
// Fused QKVG projection GEMM — R13 structure (unchanged): 256x256 tile,
// 8 waves, BK=64, swizzled LDS, counted vmcnt/lgkmcnt, setprio.
// ---------------------------------------------------------------------------
#define DSRQ(D, P, OFF) asm volatile("ds_read_b128 %0, %1 offset:" OFF \
                                     : "=v"(D) : "v"(P))

__global__ __launch_bounds__(512, 2) void gemm_qkvg_k(const unsigned short* __restrict__ A,
                                                      const unsigned short* __restrict__ Bt,
                                                      float* __restrict__ Oq,
                                                      float* __restrict__ Ok,
                                                      float* __restrict__ Ov,
                                                      float* __restrict__ Og) {
    __shared__ __align__(16) unsigned char lds_all[131072];   // 128 KiB

    const int tid = threadIdx.x;
    const int w = tid >> 6;           // wave 0..7
    const int lane = tid & 63;
    const int l16 = lane & 15;
    const int quad = lane >> 4;
    const int wr = w >> 2;            // 0..1 : 128-row half
    const int wc = w & 3;             // 0..3 : 64-col quarter

    // XCD-aware block swizzle (bijective: 256 % 8 == 0)
    const int bid = blockIdx.x;
    const int wg = (bid & 7) * 32 + (bid >> 3);
    const int m0 = (wg >> 4) * 256;
    const int n0 = (wg & 15) * 256;

    // staging: lane (lr,ls) sources the PRE-SWIZZLED slot ls^lr so the
    // swizzled read finds logical data (rule #21).
    const int lr = lane >> 3;
    const int ls = lane & 7;
    const int sslot = ls ^ lr;
    const unsigned short* srcA = A + (size_t)(m0 + lr) * DD + sslot * 8 + (size_t)w * 8 * DD;
    const unsigned short* srcB = Bt + (size_t)(n0 + lr) * DD + sslot * 8 + (size_t)w * 8 * DD;

    const LAS unsigned char* LB = (const LAS unsigned char*)&lds_all[0];

    // swizzled read base (buf0, ksub0); ^64 toggles ksub, +32768 toggles buf
    const unsigned int xq = (unsigned int)((quad ^ (l16 & 7)) << 4);
    const unsigned int uA0 = (unsigned int)((wr * 128 + l16) * 128) + xq;
    const unsigned int uB0 = 65536u + (unsigned int)((wc * 64 + l16) * 128) + xq;

    f32x4 acc[8][4];
#pragma unroll
    for (int i = 0; i < 8; ++i)
#pragma unroll
        for (int j = 0; j < 4; ++j) acc[i][j] = (f32x4){0.f, 0.f, 0.f, 0.f};

#define STG1Q(T, IA) \
    __builtin_amdgcn_global_load_lds( \
        (const GAS unsigned int*)(srcA + (size_t)(IA) * 65536 + (size_t)(T) * 64), \
        (LAS unsigned int*)(LB + (((unsigned)((T) & 1)) << 15) + ((IA) * 8 + w) * 1024), 16, 0, 0); \
    __builtin_amdgcn_global_load_lds( \
        (const GAS unsigned int*)(srcB + (size_t)(IA) * 65536 + (size_t)(T) * 64), \
        (LAS unsigned int*)(LB + 65536u + (((unsigned)((T) & 1)) << 15) + ((IA) * 8 + w) * 1024), 16, 0, 0);
#define STGQ(T) { STG1Q(T, 0) STG1Q(T, 1) STG1Q(T, 2) STG1Q(T, 3) }

    STGQ(0);                           // prologue: stage K-step 0 into buf0

    bf16x8 aG0[4], aG1[4], b0[4], b1[4];

#pragma unroll 1
    for (int t = 0; t < 16; ++t) {
        if (t + 1 < 16) {
            STGQ(t + 1);               // 8 loads for next K-step -> other buf
            asm volatile("s_waitcnt vmcnt(8)" ::: "memory");   // stage(t) done
        } else {
            asm volatile("s_waitcnt vmcnt(0)" ::: "memory");
        }
        __builtin_amdgcn_s_barrier();  // buf(t&1) staged by ALL waves

        const unsigned int boff = ((unsigned)(t & 1)) << 15;
        const LAS unsigned char* pA0 = LB + (uA0 + boff);
        const LAS unsigned char* pA1 = LB + ((uA0 ^ 64u) + boff);
        const LAS unsigned char* pB0 = LB + (uB0 + boff);
        const LAS unsigned char* pB1 = LB + ((uB0 ^ 64u) + boff);

        // issue 16 reads: b0, aG0(k0), aG1(k0), b1
        DSRQ(b0[0], pB0, "0");    DSRQ(b0[1], pB0, "2048");
        DSRQ(b0[2], pB0, "4096"); DSRQ(b0[3], pB0, "6144");
        DSRQ(aG0[0], pA0, "0");    DSRQ(aG0[1], pA0, "2048");
        DSRQ(aG0[2], pA0, "4096"); DSRQ(aG0[3], pA0, "6144");
        DSRQ(aG1[0], pA0, "8192");  DSRQ(aG1[1], pA0, "10240");
        DSRQ(aG1[2], pA0, "12288"); DSRQ(aG1[3], pA0, "14336");
        DSRQ(b1[0], pB1, "0");    DSRQ(b1[1], pB1, "2048");
        DSRQ(b1[2], pB1, "4096"); DSRQ(b1[3], pB1, "6144");

        asm volatile("s_waitcnt lgkmcnt(8)" ::: "memory");   // b0,aG0 ready
        __builtin_amdgcn_sched_barrier(0);
        __builtin_amdgcn_s_setprio(1);
#pragma unroll
        for (int ia = 0; ia < 4; ++ia)
#pragma unroll
            for (int j = 0; j < 4; ++j)
                acc[ia][j] = __builtin_amdgcn_mfma_f32_16x16x32_bf16(aG0[ia], b0[j], acc[ia][j], 0, 0, 0);
        __builtin_amdgcn_s_setprio(0);

        DSRQ(aG0[0], pA1, "0");    DSRQ(aG0[1], pA1, "2048");   // aG0 <- ksub1
        DSRQ(aG0[2], pA1, "4096"); DSRQ(aG0[3], pA1, "6144");
        asm volatile("s_waitcnt lgkmcnt(4)" ::: "memory");   // aG1(k0),b1 ready
        __builtin_amdgcn_sched_barrier(0);
        __builtin_amdgcn_s_setprio(1);
#pragma unroll
        for (int ia = 0; ia < 4; ++ia)
#pragma unroll
            for (int j = 0; j < 4; ++j)
                acc[4 + ia][j] = __builtin_amdgcn_mfma_f32_16x16x32_bf16(aG1[ia], b0[j], acc[4 + ia][j], 0, 0, 0);
        __builtin_amdgcn_s_setprio(0);

        DSRQ(aG1[0], pA1, "8192");  DSRQ(aG1[1], pA1, "10240"); // aG1 <- ksub1
        DSRQ(aG1[2], pA1, "12288"); DSRQ(aG1[3], pA1, "14336");
        asm volatile("s_waitcnt lgkmcnt(4)" ::: "memory");   // aG0(k1) ready
        __builtin_amdgcn_sched_barrier(0);
        __builtin_amdgcn_s_setprio(1);
#pragma unroll
        for (int ia = 0; ia < 4; ++ia)
#pragma unroll
            for (int j = 0; j < 4; ++j)
                acc[ia][j] = __builtin_amdgcn_mfma_f32_16x16x32_bf16(aG0[ia], b1[j], acc[ia][j], 0, 0, 0);
        __builtin_amdgcn_s_setprio(0);

        asm volatile("s_waitcnt lgkmcnt(0)" ::: "memory");   // aG1(k1) ready
        __builtin_amdgcn_sched_barrier(0);
        __builtin_amdgcn_s_setprio(1);
#pragma unroll
        for (int ia = 0; ia < 4; ++ia)
#pragma unroll
            for (int j = 0; j < 4; ++j)
                acc[4 + ia][j] = __builtin_amdgcn_mfma_f32_16x16x32_bf16(aG1[ia], b1[j], acc[4 + ia][j], 0, 0, 0);
        __builtin_amdgcn_s_setprio(0);

        __builtin_amdgcn_s_barrier();  // all reads of buf(t&1) done before
                                       // next iteration overwrites it
    }
#undef STGQ
#undef STG1Q

    float* Cd = (n0 < 1024) ? Oq : (n0 < 2048) ? Ok : (n0 < 3072) ? Ov : Og;
    const int nl = n0 & 1023;
    const int rbase = m0 + wr * 128 + quad * 4;
    const int cbase = nl + wc * 64 + l16;
#pragma unroll
    for (int ia = 0; ia < 8; ++ia)
#pragma unroll
        for (int j = 0; j < 4; ++j) {
            const int col = cbase + j * 16;
#pragma unroll
            for (int r = 0; r < 4; ++r)
                Cd[(size_t)(rbase + ia * 16 + r) * HD + col] = acc[ia][j][r];
        }
}

// ---------------------------------------------------------------------------
// g / beta kernel (R8, unchanged)
// ---------------------------------------------------------------------------
__global__ __launch_bounds__(256) void gbeta_k(const float* __restrict__ x,
                                               const float* __restrict__ Wt,
                                               const float* __restrict__ A_log,
                                               const float* __restrict__ dt_bias,
                                               float* __restrict__ g,
                                               float* __restrict__ beta) {
    __shared__ __align__(16) float xs[8][DD];
    const int r0 = blockIdx.x * 8;
    const int tid = threadIdx.x;

#pragma unroll
    for (int i = 0; i < 8; ++i) {
        const int f = tid + i * 256;
        const int r = f >> 8;
        const int col = (f & 255) * 4;
        *(float4*)&xs[r][col] = *(const float4*)&x[((size_t)r0 + r) * DD + col];
    }
    __syncthreads();

    const int out = tid >> 3;
    const int part = tid & 7;
    const int h = out & 15;
    const float* Wrow = Wt + (size_t)out * DD;

    float a0 = 0, a1 = 0, a2 = 0, a3 = 0, a4 = 0, a5 = 0, a6 = 0, a7 = 0;
#pragma unroll 4
    for (int i = 0; i < 32; ++i) {
        const int d = i * 32 + part * 4;
        const float4 wv = *(const float4*)&Wrow[d];
        float4 x0 = *(const float4*)&xs[0][d];
        float4 x1 = *(const float4*)&xs[1][d];
        float4 x2 = *(const float4*)&xs[2][d];
        float4 x3 = *(const float4*)&xs[3][d];
        float4 x4 = *(const float4*)&xs[4][d];
        float4 x5 = *(const float4*)&xs[5][d];
        float4 x6 = *(const float4*)&xs[6][d];
        float4 x7 = *(const float4*)&xs[7][d];
        a0 += DOT4(x0, wv); a1 += DOT4(x1, wv);
        a2 += DOT4(x2, wv); a3 += DOT4(x3, wv);
        a4 += DOT4(x4, wv); a5 += DOT4(x5, wv);
        a6 += DOT4(x6, wv); a7 += DOT4(x7, wv);
    }
#pragma unroll
    for (int s = 1; s <= 4; s <<= 1) {
        a0 += __shfl_xor(a0, s); a1 += __shfl_xor(a1, s);
        a2 += __shfl_xor(a2, s); a3 += __shfl_xor(a3, s);
        a4 += __shfl_xor(a4, s); a5 += __shfl_xor(a5, s);
        a6 += __shfl_xor(a6, s); a7 += __shfl_xor(a7, s);
    }

    if (part == 0) {
        float sv[8] = {a0, a1, a2, a3, a4, a5, a6, a7};
        if (out < 16) {
            const float ae = -expf(A_log[h]);
            const float db = dt_bias[h];
#pragma unroll
            for (int r = 0; r < 8; ++r) {
                float v = sv[r] + db;
                float sp = (v > 20.0f) ? v : log1pf(expf(v));
                g[((size_t)r0 + r) * HH + h] = ae * sp;
            }
        } else {
#pragma unroll
            for (int r = 0; r < 8; ++r)
                beta[((size_t)r0 + r) * HH + h] = sigmoidf_(sv[r]);
        }
    }
}

// ---------------------------------------------------------------------------
// Phase A1: stage normalized q,k (conv+silu+l2norm) and cumsum(g). (unchanged)
// ---------------------------------------------------------------------------
__global__ __launch_bounds__(64) void stage_k(const float* __restrict__ q_pre,
                                              const float* __restrict__ k_pre,
                                              const float* __restrict__ cq,
                                              const float* __restrict__ ck,
                                              const float* __restrict__ g,
                                              float* __restrict__ Qc,
                                              float* __restrict__ Kc,
                                              float* __restrict__ bcum) {
    const int blk = blockIdx.x;
    const int bh = blk >> 5;
    const int c = blk & 31;
    const int b = bh >> 4;
    const int h = bh & 15;
    const int lane = threadIdx.x;
    const int ch = h * DK + lane;

    const float4 wq4 = *(const float4*)&cq[ch * 4];
    const float4 wk4 = *(const float4*)&ck[ch * 4];

    float qw0 = 0, qw1 = 0, qw2 = 0, kw0 = 0, kw1 = 0, kw2 = 0;
    {
        const int t0 = c * CL;
        if (t0 - 3 >= 0) { size_t bi = ((size_t)b * TT + t0 - 3) * HD + ch; qw0 = q_pre[bi]; kw0 = k_pre[bi]; }
        if (t0 - 2 >= 0) { size_t bi = ((size_t)b * TT + t0 - 2) * HD + ch; qw1 = q_pre[bi]; kw1 = k_pre[bi]; }
        if (t0 - 1 >= 0) { size_t bi = ((size_t)b * TT + t0 - 1) * HD + ch; qw2 = q_pre[bi]; kw2 = k_pre[bi]; }
    }
    float* Qo = Qc + (size_t)blk * 4096;
    float* Ko = Kc + (size_t)blk * 4096;

    for (int tt = 0; tt < CL; ++tt) {
        const int t = c * CL + tt;
        const size_t bi = ((size_t)b * TT + t) * HD + ch;
        const float qc_ = q_pre[bi];
        const float kc_ = k_pre[bi];
        float qa = qw0 * wq4.x + qw1 * wq4.y + qw2 * wq4.z + qc_ * wq4.w;
        float ka = kw0 * wk4.x + kw1 * wk4.y + kw2 * wk4.z + kc_ * wk4.w;
        qw0 = qw1; qw1 = qw2; qw2 = qc_;
        kw0 = kw1; kw1 = kw2; kw2 = kc_;
        qa = siluf_(qa);
        ka = siluf_(ka);
        float qs2 = qa * qa, ks2 = ka * ka;
#pragma unroll
        for (int s = 32; s > 0; s >>= 1) {
            qs2 += __shfl_xor(qs2, s);
            ks2 += __shfl_xor(ks2, s);
        }
        Qo[tt * 64 + lane] = qa * rsqrtf(qs2 + 1e-6f) * 0.125f;
        Ko[tt * 64 + lane] = ka * rsqrtf(ks2 + 1e-6f);
    }

    float cum = g[((size_t)b * TT + c * CL + lane) * HH + h];
#pragma unroll
    for (int s = 1; s < 64; s <<= 1) {
        float u = __shfl_up(cum, s);
        if (lane >= s) cum += u;
    }
    bcum[(size_t)blk * 64 + lane] = cum;
}

// ---------------------------------------------------------------------------
// Phase A2 (R17-verbatim): 256-thread triangular solve + fused ab.
// ---------------------------------------------------------------------------
__global__ __launch_bounds__(256) void prep_k(const float* __restrict__ Kc,
                                              const float* __restrict__ v_pre,
                                              const float* __restrict__ cv,
                                              const float* __restrict__ bcum,
                                              const float* __restrict__ bbuf,
                                              float* __restrict__ Wv,
                                              float* __restrict__ Wk,
                                              float* __restrict__ Ab,
                                              float* __restrict__ Bb) {
    __shared__ __align__(16) float k_s[CL * PAD];
    __shared__ __align__(16) float wv_s[CL * PAD];
    __shared__ __align__(16) float wk_s[CL * PAD];
    __shared__ __align__(16) float A_s[CL * PADA];
    __shared__ float T_s[4][16 * 17];
    __shared__ float b_s[CL], beta_s[CL], bk_s[CL], e_s[CL];

    const int blk = blockIdx.x;
    const int bh = blk >> 5;
    const int c = blk & 31;
    const int b = bh >> 4;
    const int h = bh & 15;
    const int tid = threadIdx.x;

    if (tid < 64) {
        float bv = bcum[(size_t)blk * 64 + tid];
        float bC = bcum[(size_t)blk * 64 + 63];
        float be = bbuf[((size_t)b * TT + c * CL + tid) * HH + h];
        b_s[tid] = bv;
        beta_s[tid] = be;
        bk_s[tid] = be * __expf(bv);
        e_s[tid] = __expf(bC - bv);          // == ab_k's e_s (R17)
    }
    __syncthreads();

    {
        const float4* Kg = (const float4*)(Kc + (size_t)blk * 4096);
#pragma unroll
        for (int i = 0; i < 4; ++i) {
            int f = tid + i * 256;
            int t = f >> 4;
            int c4 = f & 15;
            int d = t * PAD + c4 * 4;                        // wk_s: plain
            int dsz = t * PAD + ((c4 ^ (t >> 2)) << 2);      // k_s: swizzled
            float4 kv = Kg[f];
            *(float4*)&k_s[dsz] = kv;
            float sk = bk_s[t];
            *(float4*)&wk_s[d] = make_float4(kv.x * sk, kv.y * sk, kv.z * sk, kv.w * sk);
        }
    }

    {
        const int lane = tid & 63;
        const int q4 = tid >> 6;
        const int ch = h * DK + lane;
        const float4 wv4 = *(const float4*)&cv[ch * 4];
        const int T0 = c * CL + q4 * 16;
        float w0 = 0, w1 = 0, w2 = 0;
        if (T0 - 3 >= 0) w0 = v_pre[((size_t)b * TT + T0 - 3) * HD + ch];
        if (T0 - 2 >= 0) w1 = v_pre[((size_t)b * TT + T0 - 2) * HD + ch];
        if (T0 - 1 >= 0) w2 = v_pre[((size_t)b * TT + T0 - 1) * HD + ch];
#pragma unroll 1
        for (int i = 0; i < 16; ++i) {
            const int t = T0 + i;
            const float vc_ = v_pre[((size_t)b * TT + t) * HD + ch];
            float va = w0 * wv4.x + w1 * wv4.y + w2 * wv4.z + vc_ * wv4.w;
            w0 = w1; w1 = w2; w2 = vc_;
            va = siluf_(va);
            wv_s[(q4 * 16 + i) * PAD + lane] = va * beta_s[q4 * 16 + i];
        }
    }
    __syncthreads();

    {
        const int qrow = tid >> 4;          // = (t0+i)>>2 for i in 0..3
        const int qcol = tid & 15;          // = (s0+j)>>2 for j in 0..3
        const int t0 = qrow * 4, s0 = qcol * 4;
        float acc[4][4] = {};
        for (int kk = 0; kk < 64; kk += 4) {
            const int ka = ((kk >> 2) ^ qrow) << 2;
            const int kb = ((kk >> 2) ^ qcol) << 2;
            float4 ta0 = *(const float4*)&k_s[(t0 + 0) * PAD + ka];
            float4 ta1 = *(const float4*)&k_s[(t0 + 1) * PAD + ka];
            float4 ta2 = *(const float4*)&k_s[(t0 + 2) * PAD + ka];
            float4 ta3 = *(const float4*)&k_s[(t0 + 3) * PAD + ka];
            float4 sb0 = *(const float4*)&k_s[(s0 + 0) * PAD + kb];
            float4 sb1 = *(const float4*)&k_s[(s0 + 1) * PAD + kb];
            float4 sb2 = *(const float4*)&k_s[(s0 + 2) * PAD + kb];
            float4 sb3 = *(const float4*)&k_s[(s0 + 3) * PAD + kb];
            acc[0][0] += DOT4(ta0, sb0); acc[0][1] += DOT4(ta0, sb1);
            acc[0][2] += DOT4(ta0, sb2); acc[0][3] += DOT4(ta0, sb3);
            acc[1][0] += DOT4(ta1, sb0); acc[1][1] += DOT4(ta1, sb1);
            acc[1][2] += DOT4(ta1, sb2); acc[1][3] += DOT4(ta1, sb3);
            acc[2][0] += DOT4(ta2, sb0); acc[2][1] += DOT4(ta2, sb1);
            acc[2][2] += DOT4(ta2, sb2); acc[2][3] += DOT4(ta2, sb3);
            acc[3][0] += DOT4(ta3, sb0); acc[3][1] += DOT4(ta3, sb1);
            acc[3][2] += DOT4(ta3, sb2); acc[3][3] += DOT4(ta3, sb3);
        }
        __syncthreads();
#pragma unroll
        for (int i = 0; i < 4; ++i)
#pragma unroll
            for (int j = 0; j < 4; ++j) {
                const int t = t0 + i, s = s0 + j;
                A_s[t * PADA + s] = (s < t) ? acc[i][j] * beta_s[t] * __expf(b_s[t] - b_s[s]) : 0.0f;
            }
    }
    __syncthreads();

    if (tid < 64) {
        const int d = tid >> 4;
        const int col = tid & 15;
        const int base = d * 16;
        float tcol[16];
#pragma unroll
        for (int s = 0; s < 16; ++s) tcol[s] = (s == col) ? 1.0f : 0.0f;
#pragma unroll
        for (int t = 1; t < 16; ++t) {
            float a = 0.0f;
#pragma unroll
            for (int s = 0; s < 16; ++s)
                if (s < t) a += A_s[(base + t) * PADA + base + s] * tcol[s];
            tcol[t] -= a;
        }
#pragma unroll
        for (int t = 0; t < 16; ++t) T_s[d][t * 17 + col] = tcol[t];
    }
    __syncthreads();

    {
        const int r = tid >> 4;
        const int cg = tid & 15;
        float* Wc = (cg < 8) ? wv_s : wk_s;
        const int cc = (cg & 7) * 8;

        for (int tb = 0; tb < 4; ++tb) {
            const int t = tb * 16 + r;
            if (tb > 0) {
                float4 lo = *(const float4*)&Wc[t * PAD + cc];
                float4 hi = *(const float4*)&Wc[t * PAD + cc + 4];
#pragma unroll 4
                for (int s = 0; s < tb * 16; ++s) {
                    const float a = A_s[t * PADA + s];
                    float4 wlo = *(const float4*)&Wc[s * PAD + cc];
                    float4 whi = *(const float4*)&Wc[s * PAD + cc + 4];
                    lo.x -= a * wlo.x; lo.y -= a * wlo.y; lo.z -= a * wlo.z; lo.w -= a * wlo.w;
                    hi.x -= a * whi.x; hi.y -= a * whi.y; hi.z -= a * whi.z; hi.w -= a * whi.w;
                }
                *(float4*)&Wc[t * PAD + cc] = lo;
                *(float4*)&Wc[t * PAD + cc + 4] = hi;
            }
            __syncthreads();
            float4 alo = make_float4(0, 0, 0, 0);
            float4 ahi = make_float4(0, 0, 0, 0);
#pragma unroll 4
            for (int s = 0; s < 16; ++s) {
                const float tv = T_s[tb][r * 17 + s];
                float4 wlo = *(const float4*)&Wc[(tb * 16 + s) * PAD + cc];
                float4 whi = *(const float4*)&Wc[(tb * 16 + s) * PAD + cc + 4];
                alo.x += tv * wlo.x; alo.y += tv * wlo.y; alo.z += tv * wlo.z; alo.w += tv * wlo.w;
                ahi.x += tv * whi.x; ahi.y += tv * whi.y; ahi.z += tv * whi.z; ahi.w += tv * whi.w;
            }
            __syncthreads();
            *(float4*)&Wc[t * PAD + cc] = alo;
            *(float4*)&Wc[t * PAD + cc + 4] = ahi;
            __syncthreads();
        }
    }

    // Wv/Wk writeback
    float4* Wvg = (float4*)(Wv + (size_t)blk * 4096);
    float4* Wkg = (float4*)(Wk + (size_t)blk * 4096);
#pragma unroll
    for (int i = 0; i < 4; ++i) {
        int f = tid + i * 256;
        int d = (f >> 4) * PAD + (f & 15) * 4;
        Wvg[f] = *(float4*)&wv_s[d];
        Wkg[f] = *(float4*)&wk_s[d];
    }

    // ---- fused ab (R17): A_c, B_c from LDS-resident k_s/wk_s/wv_s ----
    {
        const int k0q = tid >> 4;            // col chunk 0..15
        const int k0 = k0q * 4;
        const int m0 = (tid & 15) * 4;
        const int p = tid & 15;              // panel index = m0>>2
        const float ebC = __expf(b_s[63]);
        float aA[4][4] = {};
        float aB[4][4] = {};
        for (int ss = 0; ss < 64; ss += 4) {
            float4 kf0 = *(const float4*)&k_s[(ss + 0) * PAD + ((((ss + 0) >> 2) ^ k0q) << 2)];
            float4 kf1 = *(const float4*)&k_s[(ss + 1) * PAD + ((((ss + 1) >> 2) ^ k0q) << 2)];
            float4 kf2 = *(const float4*)&k_s[(ss + 2) * PAD + ((((ss + 2) >> 2) ^ k0q) << 2)];
            float4 kf3 = *(const float4*)&k_s[(ss + 3) * PAD + ((((ss + 3) >> 2) ^ k0q) << 2)];
            const float e0 = e_s[ss + 0], e1 = e_s[ss + 1];
            const float e2 = e_s[ss + 2], e3 = e_s[ss + 3];
            kf0.x *= e0; kf0.y *= e0; kf0.z *= e0; kf0.w *= e0;
            kf1.x *= e1; kf1.y *= e1; kf1.z *= e1; kf1.w *= e1;
            kf2.x *= e2; kf2.y *= e2; kf2.z *= e2; kf2.w *= e2;
            kf3.x *= e3; kf3.y *= e3; kf3.z *= e3; kf3.w *= e3;
            float4 wa0 = *(const float4*)&wk_s[(ss + 0) * PAD + m0];
            float4 wa1 = *(const float4*)&wk_s[(ss + 1) * PAD + m0];
            float4 wa2 = *(const float4*)&wk_s[(ss + 2) * PAD + m0];
            float4 wa3 = *(const float4*)&wk_s[(ss + 3) * PAD + m0];
            float4 wb0 = *(const float4*)&wv_s[(ss + 0) * PAD + m0];
            float4 wb1 = *(const float4*)&wv_s[(ss + 1) * PAD + m0];
            float4 wb2 = *(const float4*)&wv_s[(ss + 2) * PAD + m0];
            float4 wb3 = *(const float4*)&wv_s[(ss + 3) * PAD + m0];
            OUT16(aA, kf0, wa0); OUT16(aA, kf1, wa1); OUT16(aA, kf2, wa2); OUT16(aA, kf3, wa3);
            OUT16(aB, kf0, wb0); OUT16(aB, kf1, wb1); OUT16(aB, kf2, wb2); OUT16(aB, kf3, wb3);
        }

        float* Ag = Ab + (size_t)blk * 4096;
        float* Bg = Bb + (size_t)blk * 4096;
#pragma unroll
        for (int i = 0; i < 4; ++i) {
            const int kk = k0 + i;
            float4 av = make_float4(-aA[i][0], -aA[i][1], -aA[i][2], -aA[i][3]);
            if (kk - m0 == 0) av.x += ebC;
            if (kk - m0 == 1) av.y += ebC;
            if (kk - m0 == 2) av.z += ebC;
            if (kk - m0 == 3) av.w += ebC;
            *(float4*)&Ag[p * 256 + kk * 4] = av;   // panel-transposed (R11)
            *(float4*)&Bg[kk * 64 + m0] = make_float4(aB[i][0], aB[i][1], aB[i][2], aB[i][3]);
        }
    }
}

// ---------------------------------------------------------------------------
// Phase B2 (R15): serial chunk recurrence h' = A_c h + B_c. (unchanged)
// ---------------------------------------------------------------------------
__global__ __launch_bounds__(64, 1) void hrec_k(const float* __restrict__ Ab,
                                                const float* __restrict__ Bb,
                                                float* __restrict__ Hst) {
    const int blk = blockIdx.x;
    const int bh = blk & 31;          // vs-major: same-bh blocks -> same XCD
    const int vs = blk >> 5;          // 0..VS-1
    const int k = threadIdx.x;

    __shared__ __align__(16) float A_lds[2][4096];
    __shared__ __align__(16) float h_s[4][64];

#pragma unroll
    for (int j = 0; j < 4; ++j) h_s[j][k] = 0.0f;
    float h0 = 0, h1 = 0, h2 = 0, h3 = 0;

    const float* Abase = Ab + (size_t)bh * NC * 4096;
    const float* Bbase = Bb + (size_t)bh * NC * 4096 + k * 64 + vs * 4;
    float* Hbase = Hst + (size_t)bh * NC * 4096 + k * 64 + vs * 4;

    // per-lane LDS read pointers (AS3, 32-bit)
    const LAS float* rd_cur = (const LAS float*)&A_lds[0][0] + k * 4;
    const LAS float* rd_nxt = (const LAS float*)&A_lds[1][0] + k * 4;
    const LAS float* hp = (const LAS float*)&h_s[0][0];   // uniform h base

    // prologue: stage A(0) into buf0, B(0) -> register
#pragma unroll
    for (int i = 0; i < 16; ++i)
        __builtin_amdgcn_global_load_lds((const GAS unsigned int*)(Abase + i * 256 + k * 4),
                                         (LAS unsigned int*)&A_lds[0][i * 256], 16, 0, 0);
    float4 bn = *(const float4*)&Bbase[0];

#define ARD(DST, OFF) asm volatile("ds_read_b128 %0, %1 offset:" OFF \
                                   : "=v"(DST) : "v"(rd_cur))
#define HRD(DST, OFF) asm volatile("ds_read_b128 %0, %1 offset:" OFF \
                                   : "=v"(DST) : "v"(hp) : "memory")
#define FMAG(AR, H0, H1, H2, H3) \
    a0 += AR[0]*H0[0] + AR[1]*H0[1] + AR[2]*H0[2] + AR[3]*H0[3]; \
    a1 += AR[0]*H1[0] + AR[1]*H1[1] + AR[2]*H1[2] + AR[3]*H1[3]; \
    a2 += AR[0]*H2[0] + AR[1]*H2[1] + AR[2]*H2[2] + AR[3]*H2[3]; \
    a3 += AR[0]*H3[0] + AR[1]*H3[1] + AR[2]*H3[2] + AR[3]*H3[3];
#define WAIT10 asm volatile("s_waitcnt lgkmcnt(10)" ::: "memory"); \
               __builtin_amdgcn_sched_barrier(0);

#pragma unroll 1
    for (int c = 0; c < NC; ++c) {
        float4 b0 = bn;

        // chunk-start state (pre-update); fire-and-forget store
        *(float4*)&Hbase[(size_t)c * 4096] = make_float4(h0, h1, h2, h3);

        if (c + 1 < NC) {
            const float* An = Abase + (size_t)(c + 1) * 4096;
#pragma unroll
            for (int i = 0; i < 16; ++i)
                __builtin_amdgcn_global_load_lds((const GAS unsigned int*)(An + i * 256 + k * 4),
                                                 (LAS unsigned int*)(rd_nxt - (size_t)k * 4 + i * 256),
                                                 16, 0, 0);
            bn = *(const float4*)&Bbase[(size_t)(c + 1) * 4096];
            // newest 18 (H-store + 16 A-lds + 1 B) stay in flight
            asm volatile("s_waitcnt vmcnt(18)" ::: "memory");
        } else {
            asm volatile("s_waitcnt vmcnt(1)" ::: "memory");
        }
        __builtin_amdgcn_sched_barrier(0);

        f32x4 ar0, ar1, ar2, ar3, ar4, ar5, ar6, ar7;
        f32x4 ar8, ar9, ar10, ar11, ar12, ar13, ar14, ar15;
        f32x4 ha0, ha1, ha2, ha3, ha4, ha5, ha6, ha7;   // bank A (even batch)
        f32x4 hb0, hb1, hb2, hb3, hb4, hb5, hb6, hb7;   // bank B (odd batch)

        // batch0 (m4 0,1) + ar0,ar1 ; batch1 (m4 2,3) + ar2,ar3  -> 20 out
        HRD(ha0, "0");   HRD(ha1, "256"); HRD(ha2, "512"); HRD(ha3, "768");
        HRD(ha4, "16");  HRD(ha5, "272"); HRD(ha6, "528"); HRD(ha7, "784");
        ARD(ar0, "0");   ARD(ar1, "1024");
        HRD(hb0, "32");  HRD(hb1, "288"); HRD(hb2, "544"); HRD(hb3, "800");
        HRD(hb4, "48");  HRD(hb5, "304"); HRD(hb6, "560"); HRD(hb7, "816");
        ARD(ar2, "2048"); ARD(ar3, "3072");
        WAIT10   // batch0 + ar0,ar1 done; batch1+ar2,ar3 in flight

        float a0 = b0.x, a1 = b0.y, a2 = b0.z, a3 = b0.w;
        // sub0: m4 0,1
        FMAG(ar0, ha0, ha1, ha2, ha3)
        FMAG(ar1, ha4, ha5, ha6, ha7)
        HRD(ha0, "64");  HRD(ha1, "320"); HRD(ha2, "576"); HRD(ha3, "832");
        HRD(ha4, "80");  HRD(ha5, "336"); HRD(ha6, "592"); HRD(ha7, "848");
        ARD(ar4, "4096"); ARD(ar5, "5120");
        WAIT10
        // sub1: m4 2,3
        FMAG(ar2, hb0, hb1, hb2, hb3)
        FMAG(ar3, hb4, hb5, hb6, hb7)
        HRD(hb0, "96");  HRD(hb1, "352"); HRD(hb2, "608"); HRD(hb3, "864");
        HRD(hb4, "112"); HRD(hb5, "368"); HRD(hb6, "624"); HRD(hb7, "880");
        ARD(ar6, "6144"); ARD(ar7, "7168");
        WAIT10
        // sub2: m4 4,5
        FMAG(ar4, ha0, ha1, ha2, ha3)
        FMAG(ar5, ha4, ha5, ha6, ha7)
        HRD(ha0, "128"); HRD(ha1, "384"); HRD(ha2, "640"); HRD(ha3, "896");
        HRD(ha4, "144"); HRD(ha5, "400"); HRD(ha6, "656"); HRD(ha7, "912");
        ARD(ar8, "8192"); ARD(ar9, "9216");
        WAIT10
        // sub3: m4 6,7
        FMAG(ar6, hb0, hb1, hb2, hb3)
        FMAG(ar7, hb4, hb5, hb6, hb7)
        HRD(hb0, "160"); HRD(hb1, "416"); HRD(hb2, "672"); HRD(hb3, "928");
        HRD(hb4, "176"); HRD(hb5, "432"); HRD(hb6, "688"); HRD(hb7, "944");
        ARD(ar10, "10240"); ARD(ar11, "11264");
        WAIT10
        // sub4: m4 8,9
        FMAG(ar8, ha0, ha1, ha2, ha3)
        FMAG(ar9, ha4, ha5, ha6, ha7)
        HRD(ha0, "192"); HRD(ha1, "448"); HRD(ha2, "704"); HRD(ha3, "960");
        HRD(ha4, "208"); HRD(ha5, "464"); HRD(ha6, "720"); HRD(ha7, "976");
        ARD(ar12, "12288"); ARD(ar13, "13312");
        WAIT10
        // sub5: m4 10,11
        FMAG(ar10, hb0, hb1, hb2, hb3)
        FMAG(ar11, hb4, hb5, hb6, hb7)
        HRD(hb0, "224"); HRD(hb1, "480"); HRD(hb2, "736"); HRD(hb3, "992");
        HRD(hb4, "240"); HRD(hb5, "496"); HRD(hb6, "752"); HRD(hb7, "1008");
        ARD(ar14, "14336"); ARD(ar15, "15360");
        WAIT10
        // sub6: m4 12,13
        FMAG(ar12, ha0, ha1, ha2, ha3)
        FMAG(ar13, ha4, ha5, ha6, ha7)
        asm volatile("s_waitcnt lgkmcnt(0)" ::: "memory");
        __builtin_amdgcn_sched_barrier(0);
        // sub7: m4 14,15
        FMAG(ar14, hb0, hb1, hb2, hb3)
        FMAG(ar15, hb4, hb5, hb6, hb7)

        h0 = a0; h1 = a1; h2 = a2; h3 = a3;
        h_s[0][k] = h0; h_s[1][k] = h1; h_s[2][k] = h2; h_s[3][k] = h3;
        // per-wave DS ops execute in order at the LDS unit: next iteration's
        // HRD reads (memory-clobbered asm) see these writes.

        const LAS float* t = rd_cur; rd_cur = rd_nxt; rd_nxt = (LAS float*)t;
    }
#undef ARD
#undef HRD
#undef FMAG
#undef WAIT10
}

// ---------------------------------------------------------------------------
// Phase C (R20): fused wfix + QK^T/S + output + gated RMSNorm.
// wfix_k (W = Wv − Wk·h0) existed only to feed this kernel through HBM.
// Now: stage Wk into s_s (XOR-swizzled — the fix contraction reads Wk
// row-varying per lane, T2 pattern), Wv into w_s, H into h_s, Q into q_s;
// compute W in-LDS with the IDENTICAL per-thread tile map + WSUB kk-order
// as wfix_k (bit-identical); then overwrite s_s with K (second staging
// round) and proceed as R19. Each W cell is read+written by one thread.
// ---------------------------------------------------------------------------
__global__ __launch_bounds__(256) void out_k(const float* __restrict__ Qc,
                                             const float* __restrict__ Kc,
                                             const float* __restrict__ Wv,
                                             const float* __restrict__ Wk,
                                             const float* __restrict__ Hst,
                                             const float* __restrict__ bcum,
                                             const float* __restrict__ gate,
                                             const float* __restrict__ rms_w,
                                             unsigned short* __restrict__ o2) {
    __shared__ __align__(16) float q_s[CL * PAD];
    __shared__ __align__(16) float s_s[CL * PAD];   // Wk, then K, then S (swizzled)
    __shared__ __align__(16) float h_s[CL * PAD];
    __shared__ __align__(16) float w_s[CL * PAD];   // Wv -> W
    __shared__ float b_s[64];

    const int blk = blockIdx.x;
    const int bh = blk >> 5;
    const int c = blk & 31;
    const int b = bh >> 4;
    const int h = bh & 15;
    const int tid = threadIdx.x;

    const int qrow = tid >> 4;          // row chunk 0..15
    const int qcol = tid & 15;          // col chunk 0..15

    if (tid < 64) b_s[tid] = bcum[(size_t)blk * 64 + tid];
    {
        const float4* Qg = (const float4*)(Qc + (size_t)blk * 4096);
        const float4* Wkg = (const float4*)(Wk + (size_t)blk * 4096);
        const float4* Hg = (const float4*)(Hst + (size_t)blk * 4096);
        const float4* Wvg = (const float4*)(Wv + (size_t)blk * 4096);
#pragma unroll
        for (int i = 0; i < 4; ++i) {
            int f = tid + i * 256;
            int t = f >> 4;
            int c4 = f & 15;
            int d = t * PAD + c4 * 4;
            int dsz = t * PAD + ((c4 ^ (t >> 2)) << 2);     // s_s swizzled
            *(float4*)&q_s[d] = Qg[f];
            *(float4*)&s_s[dsz] = Wkg[f];                   // Wk (swizzled)
            *(float4*)&h_s[d] = Hg[f];
            *(float4*)&w_s[d] = Wvg[f];                     // Wv (plain)
        }
    }
    __syncthreads();

    // Phase 0 (fused wfix): W[t][v] = Wv[t][v] − Σ_kk Wk[t][kk]·H[kk][v].
    // Thread map + WSUB kk-order identical to old wfix_k -> bit-identical.
    {
        const int t0 = qrow * 4, v0 = qcol * 4;
        float acc[4][4];
#pragma unroll
        for (int i = 0; i < 4; ++i) {
            float4 wv = *(const float4*)&w_s[(t0 + i) * PAD + v0];
            acc[i][0] = wv.x; acc[i][1] = wv.y; acc[i][2] = wv.z; acc[i][3] = wv.w;
        }
        for (int kk = 0; kk < 64; kk += 4) {
            const int ka = ((kk >> 2) ^ qrow) << 2;         // swizzled Wk read
            float4 wa0 = *(const float4*)&s_s[(t0 + 0) * PAD + ka];
            float4 wa1 = *(const float4*)&s_s[(t0 + 1) * PAD + ka];
            float4 wa2 = *(const float4*)&s_s[(t0 + 2) * PAD + ka];
            float4 wa3 = *(const float4*)&s_s[(t0 + 3) * PAD + ka];
            float4 hb0 = *(const float4*)&h_s[(kk + 0) * PAD + v0];
            float4 hb1 = *(const float4*)&h_s[(kk + 1) * PAD + v0];
            float4 hb2 = *(const float4*)&h_s[(kk + 2) * PAD + v0];
            float4 hb3 = *(const float4*)&h_s[(kk + 3) * PAD + v0];
            WSUB(x, hb0); WSUB(y, hb1); WSUB(z, hb2); WSUB(w, hb3);
        }
#pragma unroll
        for (int i = 0; i < 4; ++i)
            *(float4*)&w_s[(t0 + i) * PAD + v0] =
                make_float4(acc[i][0], acc[i][1], acc[i][2], acc[i][3]);
    }
    __syncthreads();   // all Wk reads done before s_s is overwritten with K

    // stage K into s_s (swizzled)
    {
        const float4* Kg = (const float4*)(Kc + (size_t)blk * 4096);
#pragma unroll
        for (int i = 0; i < 4; ++i) {
            int f = tid + i * 256;
            int t = f >> 4;
            int c4 = f & 15;
            int dsz = t * PAD + ((c4 ^ (t >> 2)) << 2);
            *(float4*)&s_s[dsz] = Kg[f];
        }
    }
    __syncthreads();

    // Phase 1: S = (Q K^T) ⊙ exp(b_t - b_s) [s<=t], overwrite s_s
    {
        const int t0 = qrow * 4, s0 = qcol * 4;
        float acc[4][4] = {};
        for (int kk = 0; kk < 64; kk += 4) {
            const int kb = ((kk >> 2) ^ qcol) << 2;
            float4 ta0 = *(const float4*)&q_s[(t0 + 0) * PAD + kk];
            float4 ta1 = *(const float4*)&q_s[(t0 + 1) * PAD + kk];
            float4 ta2 = *(const float4*)&q_s[(t0 + 2) * PAD + kk];
            float4 ta3 = *(const float4*)&q_s[(t0 + 3) * PAD + kk];
            float4 sb0 = *(const float4*)&s_s[(s0 + 0) * PAD + kb];
            float4 sb1 = *(const float4*)&s_s[(s0 + 1) * PAD + kb];
            float4 sb2 = *(const float4*)&s_s[(s0 + 2) * PAD + kb];
            float4 sb3 = *(const float4*)&s_s[(s0 + 3) * PAD + kb];
            acc[0][0] += DOT4(ta0, sb0); acc[0][1] += DOT4(ta0, sb1);
            acc[0][2] += DOT4(ta0, sb2); acc[0][3] += DOT4(ta0, sb3);
            acc[1][0] += DOT4(ta1, sb0); acc[1][1] += DOT4(ta1, sb1);
            acc[1][2] += DOT4(ta1, sb2); acc[1][3] += DOT4(ta1, sb3);
            acc[2][0] += DOT4(ta2, sb0); acc[2][1] += DOT4(ta2, sb1);
            acc[2][2] += DOT4(ta2, sb2); acc[2][3] += DOT4(ta2, sb3);
            acc[3][0] += DOT4(ta3, sb0); acc[3][1] += DOT4(ta3, sb1);
            acc[3][2] += DOT4(ta3, sb2); acc[3][3] += DOT4(ta3, sb3);
        }
        __syncthreads();   // all Q,K reads done before overwrite
#pragma unroll
        for (int i = 0; i < 4; ++i)
#pragma unroll
            for (int j = 0; j < 4; ++j) {
                const int t = t0 + i, s = s0 + j;
                // swizzled scalar store: chunk (s>>2)=qcol XOR (t>>2)=qrow
                s_s[t * PAD + ((qcol ^ qrow) << 2) + (s & 3)] =
                    (s <= t) ? acc[i][j] * __expf(b_s[t] - b_s[s]) : 0.0f;
            }
    }
    // scale q rows by e^{b_t}  (q_s plain)
#pragma unroll
    for (int i = 0; i < 16; ++i) {
        const int e = tid + i * 256;
        const int t = e >> 6;
        q_s[t * PAD + (e & 63)] *= __expf(b_s[t]);
    }
    __syncthreads();

    // Phase 2: O = S @ W + Qs @ H, then fused gated RMSNorm -> bf16
    {
        const int t0 = qrow * 4, v0 = qcol * 4;
        float acc[4][4] = {};
        for (int ss = 0; ss < 64; ss += 4) {
            const int ks = ((ss >> 2) ^ qrow) << 2;   // s_s swizzled read
            float4 sa0 = *(const float4*)&s_s[(t0 + 0) * PAD + ks];
            float4 sa1 = *(const float4*)&s_s[(t0 + 1) * PAD + ks];
            float4 sa2 = *(const float4*)&s_s[(t0 + 2) * PAD + ks];
            float4 sa3 = *(const float4*)&s_s[(t0 + 3) * PAD + ks];
            float4 wb0 = *(const float4*)&w_s[(ss + 0) * PAD + v0];
            float4 wb1 = *(const float4*)&w_s[(ss + 1) * PAD + v0];
            float4 wb2 = *(const float4*)&w_s[(ss + 2) * PAD + v0];
            float4 wb3 = *(const float4*)&w_s[(ss + 3) * PAD + v0];
            ACC16(x, wb0); ACC16(y, wb1); ACC16(z, wb2); ACC16(w, wb3);
        }
        for (int kk = 0; kk < 64; kk += 4) {
            float4 sa0 = *(const float4*)&q_s[(t0 + 0) * PAD + kk];
            float4 sa1 = *(const float4*)&q_s[(t0 + 1) * PAD + kk];
            float4 sa2 = *(const float4*)&q_s[(t0 + 2) * PAD + kk];
            float4 sa3 = *(const float4*)&q_s[(t0 + 3) * PAD + kk];
            float4 wb0 = *(const float4*)&h_s[(kk + 0) * PAD + v0];
            float4 wb1 = *(const float4*)&h_s[(kk + 1) * PAD + v0];
            float4 wb2 = *(const float4*)&h_s[(kk + 2) * PAD + v0];
            float4 wb3 = *(const float4*)&h_s[(kk + 3) * PAD + v0];
            ACC16(x, wb0); ACC16(y, wb1); ACC16(z, wb2); ACC16(w, wb3);
        }

        // fused gated RMSNorm epilogue (R19)
        const float4 rw = *(const float4*)&rms_w[v0];
#pragma unroll
        for (int i = 0; i < 4; ++i) {
            float ss2 = acc[i][0] * acc[i][0] + acc[i][1] * acc[i][1]
                      + acc[i][2] * acc[i][2] + acc[i][3] * acc[i][3];
            ss2 += __shfl_xor(ss2, 1);
            ss2 += __shfl_xor(ss2, 2);
            ss2 += __shfl_xor(ss2, 4);
            ss2 += __shfl_xor(ss2, 8);
            const float r = rsqrtf(ss2 * (1.0f / 64.0f) + 1e-5f);
            const int t = c * CL + t0 + i;
            const size_t row = (size_t)b * TT + t;
            const float4 gt = *(const float4*)&gate[row * HD + h * DK + v0];
            u16x4 o;
            o[0] = f2bf(acc[i][0] * r * rw.x * siluf_(gt.x));
            o[1] = f2bf(acc[i][1] * r * rw.y * siluf_(gt.y));
            o[2] = f2bf(acc[i][2] * r * rw.z * siluf_(gt.z));
            o[3] = f2bf(acc[i][3] * r * rw.w * siluf_(gt.w));
            *(u16x4*)&o2[row * HD + h * DK + v0] = o;
        }
    }
}

// ---------------------------------------------------------------------------
extern "C" void kernel_launch(void* const* d_in, const int* in_sizes, int n_in,
                              void* d_out, int out_size, void* d_ws, size_t ws_size,
                              hipStream_t stream) {
    (void)in_sizes; (void)n_in; (void)out_size; (void)ws_size;

    const float* x       = (const float*)d_in[0];
    const float* Wq      = (const float*)d_in[1];
    const float* Wk_     = (const float*)d_in[2];
    const float* Wv_     = (const float*)d_in[3];
    const float* Wa      = (const float*)d_in[4];
    const float* Wb      = (const float*)d_in[5];
    const float* Wg      = (const float*)d_in[6];
    const float* Wo      = (const float*)d_in[7];
    const float* conv_q  = (const float*)d_in[8];
    const float* conv_k  = (const float*)d_in[9];
    const float* conv_v  = (const float*)d_in[10];
    const float* A_log   = (const float*)d_in[11];
    const float* dt_bias = (const float*)d_in[12];
    const float* rms_w   = (const float*)d_in[13];
    float* out = (float*)d_out;

    float* ws = (float*)d_ws;
    const size_t NTOK = (size_t)BB * TT;     // 4096
    const size_t BIG = NTOK * HD;            // 4 Mi floats

    float* q_pre = ws + 0 * BIG;
    float* k_pre = ws + 1 * BIG;
    float* v_pre = ws + 2 * BIG;
    float* gatep = ws + 3 * BIG;
    float* Qc    = ws + 4 * BIG;
    float* Kc    = ws + 5 * BIG;
    float* gbuf  = ws + 6 * BIG;
    float* bbuf  = gbuf + NTOK * HH;
    float* bcumb = bbuf + NTOK * HH;

    // bf16 buffers after the fp32 region (wqt..wgt contiguous = fused B matrix)
    unsigned short* xb  = (unsigned short*)(bcumb + NTOK * HH);
    unsigned short* wqt = xb + (size_t)NTOK * DD;
    unsigned short* wkt = wqt + (size_t)DD * HD;
    unsigned short* wvt = wkt + (size_t)DD * HD;
    unsigned short* wgt = wvt + (size_t)DD * HD;
    unsigned short* wot = wgt + (size_t)DD * HD;

    // fp32 buffers after bf16 region: Bb + Hst (32 MB) + Wab_t (128 KB)
    float* Bbuf = (float*)(wot + (size_t)DD * HD);
    float* HstB = Bbuf + BIG;
    float* Wabt = HstB + BIG;

    // aliases (stream-ordered lifetimes):
    float* Wvb    = q_pre;   // prep_k out (Wv half, pre-fix)
    float* Wkb    = k_pre;   // prep_k out (Wk half)
    // A buffer aliases the xb/wqt region (dead after gemm_qkvg_k).
    float* Abuf   = (float*)xb;
    // o2 (bf16 output of fused out_k) aliases Abuf (dead after hrec_k);
    // disjoint from wot and from Qc/Kc (still read).
    unsigned short* o2b = (unsigned short*)Abuf;

    // casts
    castx_k<<<(int)(NTOK * DD / (256 * 8)), 256, 0, stream>>>(x, xb);
    dim3 tg(16, 16);
    castw_k<<<tg, 256, 0, stream>>>(Wq, wqt);
    castw_k<<<tg, 256, 0, stream>>>(Wk_, wkt);
    castw_k<<<tg, 256, 0, stream>>>(Wv_, wvt);
    castw_k<<<tg, 256, 0, stream>>>(Wg, wgt);
    castw_k<<<tg, 256, 0, stream>>>(Wo, wot);
    tw_k<<<32, 256, 0, stream>>>(Wa, Wb, Wabt);

    // fused QKVG projection: 256 blocks x 512 threads (256^2 8-phase, R13)
    gemm_qkvg_k<<<256, 512, 0, stream>>>(xb, wqt, q_pre, k_pre, v_pre, gatep);

    gbeta_k<<<(int)(NTOK / 8), 256, 0, stream>>>(x, Wabt, A_log, dt_bias, gbuf, bbuf);

    stage_k<<<BB * HH * NC, 64, 0, stream>>>(q_pre, k_pre, conv_q, conv_k, gbuf,
                                             Qc, Kc, bcumb);

    // prep_k (256 threads) also emits A_c/B_c
    prep_k<<<BB * HH * NC, 256, 0, stream>>>(Kc, v_pre, conv_v, bcumb, bbuf,
                                             Wvb, Wkb, Abuf, Bbuf);

    hrec_k<<<BB * HH * VS, 64, 0, stream>>>(Abuf, Bbuf, HstB);

    // out_k now fuses wfix (W = Wv − Wk·h0), QK^T/S, output, and gated
    // RMSNorm, writing bf16 o2 directly (R20)
    out_k<<<BB * HH * NC, 256, 0, stream>>>(Qc, Kc, Wvb, Wkb, HstB, bcumb,
                                            gatep, rms_w, o2b);

    gemm_bf16_k<<<dim3(HD / 128, NTOK / 128), 256, 0, stream>>>(o2b, wot, out,
                                                                (int)NTOK, HD, DD);
}

// Round 11
// 410.997 us; speedup vs baseline: 1.2730x; 1.0120x over previous
//
#include <hip/hip_runtime.h>
#include <hip/hip_bf16.h>
#include <math.h>
#include <stdint.h>

// Problem constants
#define BB 2
#define TT 2048
#define DD 1024
#define HH 16
#define DK 64
#define HD 1024   // H*DK
#define NC 32     // chunks per sequence (TT/64)
#define CL 64     // chunk length
#define PAD 68    // padded LDS row stride (floats)
#define PADA 67   // A_s row stride (R16)
#define VS 16     // v-splits in hrec_k

typedef short bf16x8 __attribute__((ext_vector_type(8)));     // 8 bf16 (4 VGPRs)
typedef float f32x4 __attribute__((ext_vector_type(4)));      // MFMA acc
typedef unsigned short u16x8 __attribute__((ext_vector_type(8)));
typedef unsigned short u16x4 __attribute__((ext_vector_type(4)));

#define GAS __attribute__((address_space(1)))
#define LAS __attribute__((address_space(3)))

#define DOT4(a, b) ((a).x*(b).x + (a).y*(b).y + (a).z*(b).z + (a).w*(b).w)

// acc[i][j] += kf[i-component] * wv[j-component]   (one contraction step)
#define OUT16(acc, kf, wv) \
    acc[0][0] += kf.x * wv.x; acc[0][1] += kf.x * wv.y; acc[0][2] += kf.x * wv.z; acc[0][3] += kf.x * wv.w; \
    acc[1][0] += kf.y * wv.x; acc[1][1] += kf.y * wv.y; acc[1][2] += kf.y * wv.z; acc[1][3] += kf.y * wv.w; \
    acc[2][0] += kf.z * wv.x; acc[2][1] += kf.z * wv.y; acc[2][2] += kf.z * wv.z; acc[2][3] += kf.z * wv.w; \
    acc[3][0] += kf.w * wv.x; acc[3][1] += kf.w * wv.y; acc[3][2] += kf.w * wv.z; acc[3][3] += kf.w * wv.w;

// acc[i][j] -= wa_i.c * hv[j]   (c = component selecting m)
#define WSUB(c, hv) \
    acc[0][0] -= wa0.c * hv.x; acc[0][1] -= wa0.c * hv.y; acc[0][2] -= wa0.c * hv.z; acc[0][3] -= wa0.c * hv.w; \
    acc[1][0] -= wa1.c * hv.x; acc[1][1] -= wa1.c * hv.y; acc[1][2] -= wa1.c * hv.z; acc[1][3] -= wa1.c * hv.w; \
    acc[2][0] -= wa2.c * hv.x; acc[2][1] -= wa2.c * hv.y; acc[2][2] -= wa2.c * hv.z; acc[2][3] -= wa2.c * hv.w; \
    acc[3][0] -= wa3.c * hv.x; acc[3][1] -= wa3.c * hv.y; acc[3][2] -= wa3.c * hv.z; acc[3][3] -= wa3.c * hv.w;

// acc[i][j] += sa_i.c * wv[j]   (c = component selecting the contraction idx)
#define ACC16(c, wv) \
    acc[0][0] += sa0.c * wv.x; acc[0][1] += sa0.c * wv.y; acc[0][2] += sa0.c * wv.z; acc[0][3] += sa0.c * wv.w; \
    acc[1][0] += sa1.c * wv.x; acc[1][1] += sa1.c * wv.y; acc[1][2] += sa1.c * wv.z; acc[1][3] += sa1.c * wv.w; \
    acc[2][0] += sa2.c * wv.x; acc[2][1] += sa2.c * wv.y; acc[2][2] += sa2.c * wv.z; acc[2][3] += sa2.c * wv.w; \
    acc[3][0] += sa3.c * wv.x; acc[3][1] += sa3.c * wv.y; acc[3][2] += sa3.c * wv.z; acc[3][3] += sa3.c * wv.w;

__device__ __forceinline__ float sigmoidf_(float x) { return 1.0f / (1.0f + expf(-x)); }
__device__ __forceinline__ float siluf_(float x) { return x * sigmoidf_(x); }

// round-to-nearest-even fp32 -> bf16
__device__ __forceinline__ unsigned short f2bf(float f) {
    unsigned int u = __builtin_bit_cast(unsigned int, f);
    u = (u + 0x7fffu + ((u >> 16) & 1u)) >> 16;
    return (unsigned short)u;
}

// ---------------------------------------------------------------------------
// Cast x (fp32) -> bf16, flat.
// ---------------------------------------------------------------------------
__global__ __launch_bounds__(256) void castx_k(const float* __restrict__ src,
                                               unsigned short* __restrict__ dst) {
    const size_t idx = (size_t)blockIdx.x * 256 + threadIdx.x;
    float4 a = *(const float4*)&src[idx * 8];
    float4 b = *(const float4*)&src[idx * 8 + 4];
    u16x8 o;
    o[0] = f2bf(a.x); o[1] = f2bf(a.y); o[2] = f2bf(a.z); o[3] = f2bf(a.w);
    o[4] = f2bf(b.x); o[5] = f2bf(b.y); o[6] = f2bf(b.z); o[7] = f2bf(b.w);
    *(u16x8*)&dst[idx * 8] = o;
}

// ---------------------------------------------------------------------------
// Transpose+cast weight: W[K=1024][N=1024] fp32 -> Wt[N][K] bf16.
// ---------------------------------------------------------------------------
__global__ __launch_bounds__(256) void castw_k(const float* __restrict__ W,
                                               unsigned short* __restrict__ Wt) {
    __shared__ float t_s[64][65];
    const int tid = threadIdx.x;
    const int rr = tid >> 4;
    const int cc = tid & 15;
    const int r0 = blockIdx.y * 64;
    const int c0 = blockIdx.x * 64;
#pragma unroll
    for (int i = 0; i < 4; ++i) {
        const int row = rr + i * 16;
        float4 v = *(const float4*)&W[(size_t)(r0 + row) * 1024 + c0 + cc * 4];
        t_s[row][cc * 4 + 0] = v.x;
        t_s[row][cc * 4 + 1] = v.y;
        t_s[row][cc * 4 + 2] = v.z;
        t_s[row][cc * 4 + 3] = v.w;
    }
    __syncthreads();
#pragma unroll
    for (int i = 0; i < 4; ++i) {
        const int nr = rr + i * 16;
        u16x4 o;
#pragma unroll
        for (int d = 0; d < 4; ++d) o[d] = f2bf(t_s[cc * 4 + d][nr]);
        *(u16x4*)&Wt[(size_t)(c0 + nr) * 1024 + r0 + cc * 4] = o;
    }
}

// ---------------------------------------------------------------------------
// transpose Wa|Wb [1024][16] -> Wab_t [32][1024] fp32 (R8)
// ---------------------------------------------------------------------------
__global__ __launch_bounds__(256) void tw_k(const float* __restrict__ Wa,
                                            const float* __restrict__ Wb,
                                            float* __restrict__ Wt) {
    const int o = blockIdx.x;          // 0..31
    const int h = o & 15;
    const float* W = (o < 16) ? Wa : Wb;
    const int tid = threadIdx.x;
    float4 v;
    v.x = W[(size_t)(tid * 4 + 0) * HH + h];
    v.y = W[(size_t)(tid * 4 + 1) * HH + h];
    v.z = W[(size_t)(tid * 4 + 2) * HH + h];
    v.w = W[(size_t)(tid * 4 + 3) * HH + h];
    *(float4*)&Wt[(size_t)o * DD + tid * 4] = v;
}

// ---------------------------------------------------------------------------
// bf16 MFMA GEMM (m97 structure) — generic single-output (used for Wo).
// ---------------------------------------------------------------------------
__global__ __launch_bounds__(256) void gemm_bf16_k(const unsigned short* __restrict__ A,
                                                   const unsigned short* __restrict__ Bt,
                                                   float* __restrict__ C,
                                                   int M, int N, int Kd) {
    __shared__ unsigned short a_s[128 * 32];
    __shared__ unsigned short b_s[128 * 32];

    const int tid = threadIdx.x;
    const int wave = tid >> 6;
    const int lane = tid & 63;
    const int m0 = blockIdx.y * 128;
    const int n0 = blockIdx.x * 128;

    const int quad = lane >> 4;
    const int l16 = lane & 15;
    const int wr = wave >> 1;
    const int wc = wave & 1;

    const int srow = lane >> 2;
    const int sseg = lane & 3;

    f32x4 acc[4][4];
#pragma unroll
    for (int i = 0; i < 4; ++i)
#pragma unroll
        for (int j = 0; j < 4; ++j) acc[i][j] = (f32x4){0.f, 0.f, 0.f, 0.f};

    for (int k0 = 0; k0 < Kd; k0 += 32) {
        __syncthreads();
#pragma unroll
        for (int c = 0; c < 2; ++c) {
            const int region = wave * 2 + c;
            const int r0t = region * 16;
            const int ra = r0t + srow;
            const unsigned short* ga = A + (size_t)(m0 + ra) * Kd + k0 + sseg * 8;
            const unsigned short* gb = Bt + (size_t)(n0 + ra) * Kd + k0 + sseg * 8;
            __builtin_amdgcn_global_load_lds((const GAS unsigned int*)ga,
                                             (LAS unsigned int*)&a_s[r0t * 32], 16, 0, 0);
            __builtin_amdgcn_global_load_lds((const GAS unsigned int*)gb,
                                             (LAS unsigned int*)&b_s[r0t * 32], 16, 0, 0);
        }
        __syncthreads();

        bf16x8 af[4], bfr[4];
#pragma unroll
        for (int i = 0; i < 4; ++i)
            af[i] = *(const bf16x8*)&a_s[(wr * 64 + i * 16 + l16) * 32 + quad * 8];
#pragma unroll
        for (int j = 0; j < 4; ++j)
            bfr[j] = *(const bf16x8*)&b_s[(wc * 64 + j * 16 + l16) * 32 + quad * 8];
#pragma unroll
        for (int i = 0; i < 4; ++i)
#pragma unroll
            for (int j = 0; j < 4; ++j)
                acc[i][j] = __builtin_amdgcn_mfma_f32_16x16x32_bf16(af[i], bfr[j], acc[i][j], 0, 0, 0);
    }

#pragma unroll
    for (int i = 0; i < 4; ++i)
#pragma unroll
        for (int j = 0; j < 4; ++j) {
            const int col = n0 + wc * 64 + j * 16 + l16;
#pragma unroll
            for (int r = 0; r < 4; ++r) {
                const int row = m0 + wr * 64 + i * 16 + quad * 4 + r;
                C[(size_t)row * N + col] = acc[i][j][r];
            }
        }
}

// ---------------------------------------------------------------------------
// Fused QKVG projection GEMM — R13 structure (unchanged): 256x256 tile,
// 8 waves, BK=64, swizzled LDS, counted vmcnt/lgkmcnt, setprio.
// ---------------------------------------------------------------------------
#define DSRQ(D, P, OFF) asm volatile("ds_read_b128 %0, %1 offset:" OFF \
                                     : "=v"(D) : "v"(P))

__global__ __launch_bounds__(512, 2) void gemm_qkvg_k(const unsigned short* __restrict__ A,
                                                      const unsigned short* __restrict__ Bt,
                                                      float* __restrict__ Oq,
                                                      float* __restrict__ Ok,
                                                      float* __restrict__ Ov,
                                                      float* __restrict__ Og) {
    __shared__ __align__(16) unsigned char lds_all[131072];   // 128 KiB

    const int tid = threadIdx.x;
    const int w = tid >> 6;           // wave 0..7
    const int lane = tid & 63;
    const int l16 = lane & 15;
    const int quad = lane >> 4;
    const int wr = w >> 2;            // 0..1 : 128-row half
    const int wc = w & 3;             // 0..3 : 64-col quarter

    // XCD-aware block swizzle (bijective: 256 % 8 == 0)
    const int bid = blockIdx.x;
    const int wg = (bid & 7) * 32 + (bid >> 3);
    const int m0 = (wg >> 4) * 256;
    const int n0 = (wg & 15) * 256;

    // staging: lane (lr,ls) sources the PRE-SWIZZLED slot ls^lr so the
    // swizzled read finds logical data (rule #21).
    const int lr = lane >> 3;
    const int ls = lane & 7;
    const int sslot = ls ^ lr;
    const unsigned short* srcA = A + (size_t)(m0 + lr) * DD + sslot * 8 + (size_t)w * 8 * DD;
    const unsigned short* srcB = Bt + (size_t)(n0 + lr) * DD + sslot * 8 + (size_t)w * 8 * DD;

    const LAS unsigned char* LB = (const LAS unsigned char*)&lds_all[0];

    // swizzled read base (buf0, ksub0); ^64 toggles ksub, +32768 toggles buf
    const unsigned int xq = (unsigned int)((quad ^ (l16 & 7)) << 4);
    const unsigned int uA0 = (unsigned int)((wr * 128 + l16) * 128) + xq;
    const unsigned int uB0 = 65536u + (unsigned int)((wc * 64 + l16) * 128) + xq;

    f32x4 acc[8][4];
#pragma unroll
    for (int i = 0; i < 8; ++i)
#pragma unroll
        for (int j = 0; j < 4; ++j) acc[i][j] = (f32x4){0.f, 0.f, 0.f, 0.f};

#define STG1Q(T, IA) \
    __builtin_amdgcn_global_load_lds( \
        (const GAS unsigned int*)(srcA + (size_t)(IA) * 65536 + (size_t)(T) * 64), \
        (LAS unsigned int*)(LB + (((unsigned)((T) & 1)) << 15) + ((IA) * 8 + w) * 1024), 16, 0, 0); \
    __builtin_amdgcn_global_load_lds( \
        (const GAS unsigned int*)(srcB + (size_t)(IA) * 65536 + (size_t)(T) * 64), \
        (LAS unsigned int*)(LB + 65536u + (((unsigned)((T) & 1)) << 15) + ((IA) * 8 + w) * 1024), 16, 0, 0);
#define STGQ(T) { STG1Q(T, 0) STG1Q(T, 1) STG1Q(T, 2) STG1Q(T, 3) }

    STGQ(0);                           // prologue: stage K-step 0 into buf0

    bf16x8 aG0[4], aG1[4], b0[4], b1[4];

#pragma unroll 1
    for (int t = 0; t < 16; ++t) {
        if (t + 1 < 16) {
            STGQ(t + 1);               // 8 loads for next K-step -> other buf
            asm volatile("s_waitcnt vmcnt(8)" ::: "memory");   // stage(t) done
        } else {
            asm volatile("s_waitcnt vmcnt(0)" ::: "memory");
        }
        __builtin_amdgcn_s_barrier();  // buf(t&1) staged by ALL waves

        const unsigned int boff = ((unsigned)(t & 1)) << 15;
        const LAS unsigned char* pA0 = LB + (uA0 + boff);
        const LAS unsigned char* pA1 = LB + ((uA0 ^ 64u) + boff);
        const LAS unsigned char* pB0 = LB + (uB0 + boff);
        const LAS unsigned char* pB1 = LB + ((uB0 ^ 64u) + boff);

        // issue 16 reads: b0, aG0(k0), aG1(k0), b1
        DSRQ(b0[0], pB0, "0");    DSRQ(b0[1], pB0, "2048");
        DSRQ(b0[2], pB0, "4096"); DSRQ(b0[3], pB0, "6144");
        DSRQ(aG0[0], pA0, "0");    DSRQ(aG0[1], pA0, "2048");
        DSRQ(aG0[2], pA0, "4096"); DSRQ(aG0[3], pA0, "6144");
        DSRQ(aG1[0], pA0, "8192");  DSRQ(aG1[1], pA0, "10240");
        DSRQ(aG1[2], pA0, "12288"); DSRQ(aG1[3], pA0, "14336");
        DSRQ(b1[0], pB1, "0");    DSRQ(b1[1], pB1, "2048");
        DSRQ(b1[2], pB1, "4096"); DSRQ(b1[3], pB1, "6144");

        asm volatile("s_waitcnt lgkmcnt(8)" ::: "memory");   // b0,aG0 ready
        __builtin_amdgcn_sched_barrier(0);
        __builtin_amdgcn_s_setprio(1);
#pragma unroll
        for (int ia = 0; ia < 4; ++ia)
#pragma unroll
            for (int j = 0; j < 4; ++j)
                acc[ia][j] = __builtin_amdgcn_mfma_f32_16x16x32_bf16(aG0[ia], b0[j], acc[ia][j], 0, 0, 0);
        __builtin_amdgcn_s_setprio(0);

        DSRQ(aG0[0], pA1, "0");    DSRQ(aG0[1], pA1, "2048");   // aG0 <- ksub1
        DSRQ(aG0[2], pA1, "4096"); DSRQ(aG0[3], pA1, "6144");
        asm volatile("s_waitcnt lgkmcnt(4)" ::: "memory");   // aG1(k0),b1 ready
        __builtin_amdgcn_sched_barrier(0);
        __builtin_amdgcn_s_setprio(1);
#pragma unroll
        for (int ia = 0; ia < 4; ++ia)
#pragma unroll
            for (int j = 0; j < 4; ++j)
                acc[4 + ia][j] = __builtin_amdgcn_mfma_f32_16x16x32_bf16(aG1[ia], b0[j], acc[4 + ia][j], 0, 0, 0);
        __builtin_amdgcn_s_setprio(0);

        DSRQ(aG1[0], pA1, "8192");  DSRQ(aG1[1], pA1, "10240"); // aG1 <- ksub1
        DSRQ(aG1[2], pA1, "12288"); DSRQ(aG1[3], pA1, "14336");
        asm volatile("s_waitcnt lgkmcnt(4)" ::: "memory");   // aG0(k1) ready
        __builtin_amdgcn_sched_barrier(0);
        __builtin_amdgcn_s_setprio(1);
#pragma unroll
        for (int ia = 0; ia < 4; ++ia)
#pragma unroll
            for (int j = 0; j < 4; ++j)
                acc[ia][j] = __builtin_amdgcn_mfma_f32_16x16x32_bf16(aG0[ia], b1[j], acc[ia][j], 0, 0, 0);
        __builtin_amdgcn_s_setprio(0);

        asm volatile("s_waitcnt lgkmcnt(0)" ::: "memory");   // aG1(k1) ready
        __builtin_amdgcn_sched_barrier(0);
        __builtin_amdgcn_s_setprio(1);
#pragma unroll
        for (int ia = 0; ia < 4; ++ia)
#pragma unroll
            for (int j = 0; j < 4; ++j)
                acc[4 + ia][j] = __builtin_amdgcn_mfma_f32_16x16x32_bf16(aG1[ia], b1[j], acc[4 + ia][j], 0, 0, 0);
        __builtin_amdgcn_s_setprio(0);

        __builtin_amdgcn_s_barrier();  // all reads of buf(t&1) done before
                                       // next iteration overwrites it
    }
#undef STGQ
#undef STG1Q

    float* Cd = (n0 < 1024) ? Oq : (n0 < 2048) ? Ok : (n0 < 3072) ? Ov : Og;
    const int nl = n0 & 1023;
    const int rbase = m0 + wr * 128 + quad * 4;
    const int cbase = nl + wc * 64 + l16;
#pragma unroll
    for (int ia = 0; ia < 8; ++ia)
#pragma unroll
        for (int j = 0; j < 4; ++j) {
            const int col = cbase + j * 16;
#pragma unroll
            for (int r = 0; r < 4; ++r)
                Cd[(size_t)(rbase + ia * 16 + r) * HD + col] = acc[ia][j][r];
        }
}

// ---------------------------------------------------------------------------
// g / beta kernel (R8, unchanged)
// ---------------------------------------------------------------------------
__global__ __launch_bounds__(256) void gbeta_k(const float* __restrict__ x,
                                               const float* __restrict__ Wt,
                                               const float* __restrict__ A_log,
                                               const float* __restrict__ dt_bias,
                                               float* __restrict__ g,
                                               float* __restrict__ beta) {
    __shared__ __align__(16) float xs[8][DD];
    const int r0 = blockIdx.x * 8;
    const int tid = threadIdx.x;

#pragma unroll
    for (int i = 0; i < 8; ++i) {
        const int f = tid + i * 256;
        const int r = f >> 8;
        const int col = (f & 255) * 4;
        *(float4*)&xs[r][col] = *(const float4*)&x[((size_t)r0 + r) * DD + col];
    }
    __syncthreads();

    const int out = tid >> 3;
    const int part = tid & 7;
    const int h = out & 15;
    const float* Wrow = Wt + (size_t)out * DD;

    float a0 = 0, a1 = 0, a2 = 0, a3 = 0, a4 = 0, a5 = 0, a6 = 0, a7 = 0;
#pragma unroll 4
    for (int i = 0; i < 32; ++i) {
        const int d = i * 32 + part * 4;
        const float4 wv = *(const float4*)&Wrow[d];
        float4 x0 = *(const float4*)&xs[0][d];
        float4 x1 = *(const float4*)&xs[1][d];
        float4 x2 = *(const float4*)&xs[2][d];
        float4 x3 = *(const float4*)&xs[3][d];
        float4 x4 = *(const float4*)&xs[4][d];
        float4 x5 = *(const float4*)&xs[5][d];
        float4 x6 = *(const float4*)&xs[6][d];
        float4 x7 = *(const float4*)&xs[7][d];
        a0 += DOT4(x0, wv); a1 += DOT4(x1, wv);
        a2 += DOT4(x2, wv); a3 += DOT4(x3, wv);
        a4 += DOT4(x4, wv); a5 += DOT4(x5, wv);
        a6 += DOT4(x6, wv); a7 += DOT4(x7, wv);
    }
#pragma unroll
    for (int s = 1; s <= 4; s <<= 1) {
        a0 += __shfl_xor(a0, s); a1 += __shfl_xor(a1, s);
        a2 += __shfl_xor(a2, s); a3 += __shfl_xor(a3, s);
        a4 += __shfl_xor(a4, s); a5 += __shfl_xor(a5, s);
        a6 += __shfl_xor(a6, s); a7 += __shfl_xor(a7, s);
    }

    if (part == 0) {
        float sv[8] = {a0, a1, a2, a3, a4, a5, a6, a7};
        if (out < 16) {
            const float ae = -expf(A_log[h]);
            const float db = dt_bias[h];
#pragma unroll
            for (int r = 0; r < 8; ++r) {
                float v = sv[r] + db;
                float sp = (v > 20.0f) ? v : log1pf(expf(v));
                g[((size_t)r0 + r) * HH + h] = ae * sp;
            }
        } else {
#pragma unroll
            for (int r = 0; r < 8; ++r)
                beta[((size_t)r0 + r) * HH + h] = sigmoidf_(sv[r]);
        }
    }
}

// ---------------------------------------------------------------------------
// Phase A1: stage normalized q,k (conv+silu+l2norm) and cumsum(g). (unchanged)
// ---------------------------------------------------------------------------
__global__ __launch_bounds__(64) void stage_k(const float* __restrict__ q_pre,
                                              const float* __restrict__ k_pre,
                                              const float* __restrict__ cq,
                                              const float* __restrict__ ck,
                                              const float* __restrict__ g,
                                              float* __restrict__ Qc,
                                              float* __restrict__ Kc,
                                              float* __restrict__ bcum) {
    const int blk = blockIdx.x;
    const int bh = blk >> 5;
    const int c = blk & 31;
    const int b = bh >> 4;
    const int h = bh & 15;
    const int lane = threadIdx.x;
    const int ch = h * DK + lane;

    const float4 wq4 = *(const float4*)&cq[ch * 4];
    const float4 wk4 = *(const float4*)&ck[ch * 4];

    float qw0 = 0, qw1 = 0, qw2 = 0, kw0 = 0, kw1 = 0, kw2 = 0;
    {
        const int t0 = c * CL;
        if (t0 - 3 >= 0) { size_t bi = ((size_t)b * TT + t0 - 3) * HD + ch; qw0 = q_pre[bi]; kw0 = k_pre[bi]; }
        if (t0 - 2 >= 0) { size_t bi = ((size_t)b * TT + t0 - 2) * HD + ch; qw1 = q_pre[bi]; kw1 = k_pre[bi]; }
        if (t0 - 1 >= 0) { size_t bi = ((size_t)b * TT + t0 - 1) * HD + ch; qw2 = q_pre[bi]; kw2 = k_pre[bi]; }
    }
    float* Qo = Qc + (size_t)blk * 4096;
    float* Ko = Kc + (size_t)blk * 4096;

    for (int tt = 0; tt < CL; ++tt) {
        const int t = c * CL + tt;
        const size_t bi = ((size_t)b * TT + t) * HD + ch;
        const float qc_ = q_pre[bi];
        const float kc_ = k_pre[bi];
        float qa = qw0 * wq4.x + qw1 * wq4.y + qw2 * wq4.z + qc_ * wq4.w;
        float ka = kw0 * wk4.x + kw1 * wk4.y + kw2 * wk4.z + kc_ * wk4.w;
        qw0 = qw1; qw1 = qw2; qw2 = qc_;
        kw0 = kw1; kw1 = kw2; kw2 = kc_;
        qa = siluf_(qa);
        ka = siluf_(ka);
        float qs2 = qa * qa, ks2 = ka * ka;
#pragma unroll
        for (int s = 32; s > 0; s >>= 1) {
            qs2 += __shfl_xor(qs2, s);
            ks2 += __shfl_xor(ks2, s);
        }
        Qo[tt * 64 + lane] = qa * rsqrtf(qs2 + 1e-6f) * 0.125f;
        Ko[tt * 64 + lane] = ka * rsqrtf(ks2 + 1e-6f);
    }

    float cum = g[((size_t)b * TT + c * CL + lane) * HH + h];
#pragma unroll
    for (int s = 1; s < 64; s <<= 1) {
        float u = __shfl_up(cum, s);
        if (lane >= s) cum += u;
    }
    bcum[(size_t)blk * 64 + lane] = cum;
}

// ---------------------------------------------------------------------------
// Phase A2 (R21): triangular solve + fused ab at 52 KB LDS -> 3 blocks/CU.
// R20 profile: VALUBusy 47%, Occ 19% (2 blocks/CU @ 74.7KB). Two overlays:
//  1) A_s ALIASES k_s — QK^T reads all of k_s before the existing barrier
//     that precedes the A-writes; K is RE-STAGED from Kc (L2-warm) for the
//     ab tail after the apply phase.
//  2) T (16x16 block inverses) is stored INTO A_s's block-diagonal — the
//     apply phase reads only strictly-off-diagonal A rows (s < tb*16),
//     so the diagonal blocks are dead after the inverse. T_s eliminated.
// Pure memory relocation; all arithmetic/order identical -> bit-identical.
// ---------------------------------------------------------------------------
__global__ __launch_bounds__(256) void prep_k(const float* __restrict__ Kc,
                                              const float* __restrict__ v_pre,
                                              const float* __restrict__ cv,
                                              const float* __restrict__ bcum,
                                              const float* __restrict__ bbuf,
                                              float* __restrict__ Wv,
                                              float* __restrict__ Wk,
                                              float* __restrict__ Ab,
                                              float* __restrict__ Bb) {
    __shared__ __align__(16) float kA_s[CL * PAD];   // k_s / A_s / k_s again
    __shared__ __align__(16) float wv_s[CL * PAD];
    __shared__ __align__(16) float wk_s[CL * PAD];
    __shared__ float b_s[CL], beta_s[CL], bk_s[CL], e_s[CL];

    float* const k_s = kA_s;   // stride PAD, chunk-swizzled
    float* const A_s = kA_s;   // stride PADA (fits: 64*67 <= 64*68)

    const int blk = blockIdx.x;
    const int bh = blk >> 5;
    const int c = blk & 31;
    const int b = bh >> 4;
    const int h = bh & 15;
    const int tid = threadIdx.x;

    if (tid < 64) {
        float bv = bcum[(size_t)blk * 64 + tid];
        float bC = bcum[(size_t)blk * 64 + 63];
        float be = bbuf[((size_t)b * TT + c * CL + tid) * HH + h];
        b_s[tid] = bv;
        beta_s[tid] = be;
        bk_s[tid] = be * __expf(bv);
        e_s[tid] = __expf(bC - bv);
    }
    __syncthreads();

    {
        const float4* Kg = (const float4*)(Kc + (size_t)blk * 4096);
#pragma unroll
        for (int i = 0; i < 4; ++i) {
            int f = tid + i * 256;
            int t = f >> 4;
            int c4 = f & 15;
            int d = t * PAD + c4 * 4;                        // wk_s: plain
            int dsz = t * PAD + ((c4 ^ (t >> 2)) << 2);      // k_s: swizzled
            float4 kv = Kg[f];
            *(float4*)&k_s[dsz] = kv;
            float sk = bk_s[t];
            *(float4*)&wk_s[d] = make_float4(kv.x * sk, kv.y * sk, kv.z * sk, kv.w * sk);
        }
    }

    {
        const int lane = tid & 63;
        const int q4 = tid >> 6;
        const int ch = h * DK + lane;
        const float4 wv4 = *(const float4*)&cv[ch * 4];
        const int T0 = c * CL + q4 * 16;
        float w0 = 0, w1 = 0, w2 = 0;
        if (T0 - 3 >= 0) w0 = v_pre[((size_t)b * TT + T0 - 3) * HD + ch];
        if (T0 - 2 >= 0) w1 = v_pre[((size_t)b * TT + T0 - 2) * HD + ch];
        if (T0 - 1 >= 0) w2 = v_pre[((size_t)b * TT + T0 - 1) * HD + ch];
#pragma unroll 1
        for (int i = 0; i < 16; ++i) {
            const int t = T0 + i;
            const float vc_ = v_pre[((size_t)b * TT + t) * HD + ch];
            float va = w0 * wv4.x + w1 * wv4.y + w2 * wv4.z + vc_ * wv4.w;
            w0 = w1; w1 = w2; w2 = vc_;
            va = siluf_(va);
            wv_s[(q4 * 16 + i) * PAD + lane] = va * beta_s[q4 * 16 + i];
        }
    }
    __syncthreads();

    // QK^T: all k_s reads complete before the barrier, then A_s (aliasing
    // k_s) is written — safe write-after-read (R21).
    {
        const int qrow = tid >> 4;          // = (t0+i)>>2 for i in 0..3
        const int qcol = tid & 15;          // = (s0+j)>>2 for j in 0..3
        const int t0 = qrow * 4, s0 = qcol * 4;
        float acc[4][4] = {};
        for (int kk = 0; kk < 64; kk += 4) {
            const int ka = ((kk >> 2) ^ qrow) << 2;
            const int kb = ((kk >> 2) ^ qcol) << 2;
            float4 ta0 = *(const float4*)&k_s[(t0 + 0) * PAD + ka];
            float4 ta1 = *(const float4*)&k_s[(t0 + 1) * PAD + ka];
            float4 ta2 = *(const float4*)&k_s[(t0 + 2) * PAD + ka];
            float4 ta3 = *(const float4*)&k_s[(t0 + 3) * PAD + ka];
            float4 sb0 = *(const float4*)&k_s[(s0 + 0) * PAD + kb];
            float4 sb1 = *(const float4*)&k_s[(s0 + 1) * PAD + kb];
            float4 sb2 = *(const float4*)&k_s[(s0 + 2) * PAD + kb];
            float4 sb3 = *(const float4*)&k_s[(s0 + 3) * PAD + kb];
            acc[0][0] += DOT4(ta0, sb0); acc[0][1] += DOT4(ta0, sb1);
            acc[0][2] += DOT4(ta0, sb2); acc[0][3] += DOT4(ta0, sb3);
            acc[1][0] += DOT4(ta1, sb0); acc[1][1] += DOT4(ta1, sb1);
            acc[1][2] += DOT4(ta1, sb2); acc[1][3] += DOT4(ta1, sb3);
            acc[2][0] += DOT4(ta2, sb0); acc[2][1] += DOT4(ta2, sb1);
            acc[2][2] += DOT4(ta2, sb2); acc[2][3] += DOT4(ta2, sb3);
            acc[3][0] += DOT4(ta3, sb0); acc[3][1] += DOT4(ta3, sb1);
            acc[3][2] += DOT4(ta3, sb2); acc[3][3] += DOT4(ta3, sb3);
        }
        __syncthreads();   // every thread's k_s reads done before A_s writes
#pragma unroll
        for (int i = 0; i < 4; ++i)
#pragma unroll
            for (int j = 0; j < 4; ++j) {
                const int t = t0 + i, s = s0 + j;
                A_s[t * PADA + s] = (s < t) ? acc[i][j] * beta_s[t] * __expf(b_s[t] - b_s[s]) : 0.0f;
            }
    }
    __syncthreads();

    // Block inverse; T stored into A_s's block-diagonal (R21). Within the
    // single wave, all A reads (tcol loop) complete before the T stores.
    if (tid < 64) {
        const int d = tid >> 4;
        const int col = tid & 15;
        const int base = d * 16;
        float tcol[16];
#pragma unroll
        for (int s = 0; s < 16; ++s) tcol[s] = (s == col) ? 1.0f : 0.0f;
#pragma unroll
        for (int t = 1; t < 16; ++t) {
            float a = 0.0f;
#pragma unroll
            for (int s = 0; s < 16; ++s)
                if (s < t) a += A_s[(base + t) * PADA + base + s] * tcol[s];
            tcol[t] -= a;
        }
#pragma unroll
        for (int t = 0; t < 16; ++t)
            A_s[(base + t) * PADA + base + col] = tcol[t];   // T -> diag block
    }
    __syncthreads();

    // Blocked triangular apply; T read from A_s block-diagonal (R21).
    // Off-diag reads (s < tb*16) never touch diag blocks -> intact.
    {
        const int r = tid >> 4;
        const int cg = tid & 15;
        float* Wc = (cg < 8) ? wv_s : wk_s;
        const int cc = (cg & 7) * 8;

        for (int tb = 0; tb < 4; ++tb) {
            const int t = tb * 16 + r;
            if (tb > 0) {
                float4 lo = *(const float4*)&Wc[t * PAD + cc];
                float4 hi = *(const float4*)&Wc[t * PAD + cc + 4];
#pragma unroll 4
                for (int s = 0; s < tb * 16; ++s) {
                    const float a = A_s[t * PADA + s];
                    float4 wlo = *(const float4*)&Wc[s * PAD + cc];
                    float4 whi = *(const float4*)&Wc[s * PAD + cc + 4];
                    lo.x -= a * wlo.x; lo.y -= a * wlo.y; lo.z -= a * wlo.z; lo.w -= a * wlo.w;
                    hi.x -= a * whi.x; hi.y -= a * whi.y; hi.z -= a * whi.z; hi.w -= a * whi.w;
                }
                *(float4*)&Wc[t * PAD + cc] = lo;
                *(float4*)&Wc[t * PAD + cc + 4] = hi;
            }
            __syncthreads();
            float4 alo = make_float4(0, 0, 0, 0);
            float4 ahi = make_float4(0, 0, 0, 0);
#pragma unroll 4
            for (int s = 0; s < 16; ++s) {
                const float tv = A_s[(tb * 16 + r) * PADA + tb * 16 + s];   // T
                float4 wlo = *(const float4*)&Wc[(tb * 16 + s) * PAD + cc];
                float4 whi = *(const float4*)&Wc[(tb * 16 + s) * PAD + cc + 4];
                alo.x += tv * wlo.x; alo.y += tv * wlo.y; alo.z += tv * wlo.z; alo.w += tv * wlo.w;
                ahi.x += tv * whi.x; ahi.y += tv * whi.y; ahi.z += tv * whi.z; ahi.w += tv * whi.w;
            }
            __syncthreads();
            *(float4*)&Wc[t * PAD + cc] = alo;
            *(float4*)&Wc[t * PAD + cc + 4] = ahi;
            __syncthreads();
        }
    }

    // Re-stage K (A_s dead after apply's final barrier) for the ab tail (R21)
    {
        const float4* Kg = (const float4*)(Kc + (size_t)blk * 4096);
#pragma unroll
        for (int i = 0; i < 4; ++i) {
            int f = tid + i * 256;
            int t = f >> 4;
            int c4 = f & 15;
            int dsz = t * PAD + ((c4 ^ (t >> 2)) << 2);
            *(float4*)&k_s[dsz] = Kg[f];
        }
    }

    // Wv/Wk writeback (reads wv_s/wk_s only — overlaps re-stage latency)
    float4* Wvg = (float4*)(Wv + (size_t)blk * 4096);
    float4* Wkg = (float4*)(Wk + (size_t)blk * 4096);
#pragma unroll
    for (int i = 0; i < 4; ++i) {
        int f = tid + i * 256;
        int d = (f >> 4) * PAD + (f & 15) * 4;
        Wvg[f] = *(float4*)&wv_s[d];
        Wkg[f] = *(float4*)&wk_s[d];
    }
    __syncthreads();   // K re-staged by all threads before ab reads

    // ---- fused ab (R17): A_c, B_c from LDS-resident k_s/wk_s/wv_s ----
    {
        const int k0q = tid >> 4;            // col chunk 0..15
        const int k0 = k0q * 4;
        const int m0 = (tid & 15) * 4;
        const int p = tid & 15;              // panel index = m0>>2
        const float ebC = __expf(b_s[63]);
        float aA[4][4] = {};
        float aB[4][4] = {};
        for (int ss = 0; ss < 64; ss += 4) {
            float4 kf0 = *(const float4*)&k_s[(ss + 0) * PAD + ((((ss + 0) >> 2) ^ k0q) << 2)];
            float4 kf1 = *(const float4*)&k_s[(ss + 1) * PAD + ((((ss + 1) >> 2) ^ k0q) << 2)];
            float4 kf2 = *(const float4*)&k_s[(ss + 2) * PAD + ((((ss + 2) >> 2) ^ k0q) << 2)];
            float4 kf3 = *(const float4*)&k_s[(ss + 3) * PAD + ((((ss + 3) >> 2) ^ k0q) << 2)];
            const float e0 = e_s[ss + 0], e1 = e_s[ss + 1];
            const float e2 = e_s[ss + 2], e3 = e_s[ss + 3];
            kf0.x *= e0; kf0.y *= e0; kf0.z *= e0; kf0.w *= e0;
            kf1.x *= e1; kf1.y *= e1; kf1.z *= e1; kf1.w *= e1;
            kf2.x *= e2; kf2.y *= e2; kf2.z *= e2; kf2.w *= e2;
            kf3.x *= e3; kf3.y *= e3; kf3.z *= e3; kf3.w *= e3;
            float4 wa0 = *(const float4*)&wk_s[(ss + 0) * PAD + m0];
            float4 wa1 = *(const float4*)&wk_s[(ss + 1) * PAD + m0];
            float4 wa2 = *(const float4*)&wk_s[(ss + 2) * PAD + m0];
            float4 wa3 = *(const float4*)&wk_s[(ss + 3) * PAD + m0];
            float4 wb0 = *(const float4*)&wv_s[(ss + 0) * PAD + m0];
            float4 wb1 = *(const float4*)&wv_s[(ss + 1) * PAD + m0];
            float4 wb2 = *(const float4*)&wv_s[(ss + 2) * PAD + m0];
            float4 wb3 = *(const float4*)&wv_s[(ss + 3) * PAD + m0];
            OUT16(aA, kf0, wa0); OUT16(aA, kf1, wa1); OUT16(aA, kf2, wa2); OUT16(aA, kf3, wa3);
            OUT16(aB, kf0, wb0); OUT16(aB, kf1, wb1); OUT16(aB, kf2, wb2); OUT16(aB, kf3, wb3);
        }

        float* Ag = Ab + (size_t)blk * 4096;
        float* Bg = Bb + (size_t)blk * 4096;
#pragma unroll
        for (int i = 0; i < 4; ++i) {
            const int kk = k0 + i;
            float4 av = make_float4(-aA[i][0], -aA[i][1], -aA[i][2], -aA[i][3]);
            if (kk - m0 == 0) av.x += ebC;
            if (kk - m0 == 1) av.y += ebC;
            if (kk - m0 == 2) av.z += ebC;
            if (kk - m0 == 3) av.w += ebC;
            *(float4*)&Ag[p * 256 + kk * 4] = av;   // panel-transposed (R11)
            *(float4*)&Bg[kk * 64 + m0] = make_float4(aB[i][0], aB[i][1], aB[i][2], aB[i][3]);
        }
    }
}

// ---------------------------------------------------------------------------
// Phase B2 (R15): serial chunk recurrence h' = A_c h + B_c. (unchanged)
// ---------------------------------------------------------------------------
__global__ __launch_bounds__(64, 1) void hrec_k(const float* __restrict__ Ab,
                                                const float* __restrict__ Bb,
                                                float* __restrict__ Hst) {
    const int blk = blockIdx.x;
    const int bh = blk & 31;          // vs-major: same-bh blocks -> same XCD
    const int vs = blk >> 5;          // 0..VS-1
    const int k = threadIdx.x;

    __shared__ __align__(16) float A_lds[2][4096];
    __shared__ __align__(16) float h_s[4][64];

#pragma unroll
    for (int j = 0; j < 4; ++j) h_s[j][k] = 0.0f;
    float h0 = 0, h1 = 0, h2 = 0, h3 = 0;

    const float* Abase = Ab + (size_t)bh * NC * 4096;
    const float* Bbase = Bb + (size_t)bh * NC * 4096 + k * 64 + vs * 4;
    float* Hbase = Hst + (size_t)bh * NC * 4096 + k * 64 + vs * 4;

    // per-lane LDS read pointers (AS3, 32-bit)
    const LAS float* rd_cur = (const LAS float*)&A_lds[0][0] + k * 4;
    const LAS float* rd_nxt = (const LAS float*)&A_lds[1][0] + k * 4;
    const LAS float* hp = (const LAS float*)&h_s[0][0];   // uniform h base

    // prologue: stage A(0) into buf0, B(0) -> register
#pragma unroll
    for (int i = 0; i < 16; ++i)
        __builtin_amdgcn_global_load_lds((const GAS unsigned int*)(Abase + i * 256 + k * 4),
                                         (LAS unsigned int*)&A_lds[0][i * 256], 16, 0, 0);
    float4 bn = *(const float4*)&Bbase[0];

#define ARD(DST, OFF) asm volatile("ds_read_b128 %0, %1 offset:" OFF \
                                   : "=v"(DST) : "v"(rd_cur))
#define HRD(DST, OFF) asm volatile("ds_read_b128 %0, %1 offset:" OFF \
                                   : "=v"(DST) : "v"(hp) : "memory")
#define FMAG(AR, H0, H1, H2, H3) \
    a0 += AR[0]*H0[0] + AR[1]*H0[1] + AR[2]*H0[2] + AR[3]*H0[3]; \
    a1 += AR[0]*H1[0] + AR[1]*H1[1] + AR[2]*H1[2] + AR[3]*H1[3]; \
    a2 += AR[0]*H2[0] + AR[1]*H2[1] + AR[2]*H2[2] + AR[3]*H2[3]; \
    a3 += AR[0]*H3[0] + AR[1]*H3[1] + AR[2]*H3[2] + AR[3]*H3[3];
#define WAIT10 asm volatile("s_waitcnt lgkmcnt(10)" ::: "memory"); \
               __builtin_amdgcn_sched_barrier(0);

#pragma unroll 1
    for (int c = 0; c < NC; ++c) {
        float4 b0 = bn;

        // chunk-start state (pre-update); fire-and-forget store
        *(float4*)&Hbase[(size_t)c * 4096] = make_float4(h0, h1, h2, h3);

        if (c + 1 < NC) {
            const float* An = Abase + (size_t)(c + 1) * 4096;
#pragma unroll
            for (int i = 0; i < 16; ++i)
                __builtin_amdgcn_global_load_lds((const GAS unsigned int*)(An + i * 256 + k * 4),
                                                 (LAS unsigned int*)(rd_nxt - (size_t)k * 4 + i * 256),
                                                 16, 0, 0);
            bn = *(const float4*)&Bbase[(size_t)(c + 1) * 4096];
            // newest 18 (H-store + 16 A-lds + 1 B) stay in flight
            asm volatile("s_waitcnt vmcnt(18)" ::: "memory");
        } else {
            asm volatile("s_waitcnt vmcnt(1)" ::: "memory");
        }
        __builtin_amdgcn_sched_barrier(0);

        f32x4 ar0, ar1, ar2, ar3, ar4, ar5, ar6, ar7;
        f32x4 ar8, ar9, ar10, ar11, ar12, ar13, ar14, ar15;
        f32x4 ha0, ha1, ha2, ha3, ha4, ha5, ha6, ha7;   // bank A (even batch)
        f32x4 hb0, hb1, hb2, hb3, hb4, hb5, hb6, hb7;   // bank B (odd batch)

        // batch0 (m4 0,1) + ar0,ar1 ; batch1 (m4 2,3) + ar2,ar3  -> 20 out
        HRD(ha0, "0");   HRD(ha1, "256"); HRD(ha2, "512"); HRD(ha3, "768");
        HRD(ha4, "16");  HRD(ha5, "272"); HRD(ha6, "528"); HRD(ha7, "784");
        ARD(ar0, "0");   ARD(ar1, "1024");
        HRD(hb0, "32");  HRD(hb1, "288"); HRD(hb2, "544"); HRD(hb3, "800");
        HRD(hb4, "48");  HRD(hb5, "304"); HRD(hb6, "560"); HRD(hb7, "816");
        ARD(ar2, "2048"); ARD(ar3, "3072");
        WAIT10   // batch0 + ar0,ar1 done; batch1+ar2,ar3 in flight

        float a0 = b0.x, a1 = b0.y, a2 = b0.z, a3 = b0.w;
        // sub0: m4 0,1
        FMAG(ar0, ha0, ha1, ha2, ha3)
        FMAG(ar1, ha4, ha5, ha6, ha7)
        HRD(ha0, "64");  HRD(ha1, "320"); HRD(ha2, "576"); HRD(ha3, "832");
        HRD(ha4, "80");  HRD(ha5, "336"); HRD(ha6, "592"); HRD(ha7, "848");
        ARD(ar4, "4096"); ARD(ar5, "5120");
        WAIT10
        // sub1: m4 2,3
        FMAG(ar2, hb0, hb1, hb2, hb3)
        FMAG(ar3, hb4, hb5, hb6, hb7)
        HRD(hb0, "96");  HRD(hb1, "352"); HRD(hb2, "608"); HRD(hb3, "864");
        HRD(hb4, "112"); HRD(hb5, "368"); HRD(hb6, "624"); HRD(hb7, "880");
        ARD(ar6, "6144"); ARD(ar7, "7168");
        WAIT10
        // sub2: m4 4,5
        FMAG(ar4, ha0, ha1, ha2, ha3)
        FMAG(ar5, ha4, ha5, ha6, ha7)
        HRD(ha0, "128"); HRD(ha1, "384"); HRD(ha2, "640"); HRD(ha3, "896");
        HRD(ha4, "144"); HRD(ha5, "400"); HRD(ha6, "656"); HRD(ha7, "912");
        ARD(ar8, "8192"); ARD(ar9, "9216");
        WAIT10
        // sub3: m4 6,7
        FMAG(ar6, hb0, hb1, hb2, hb3)
        FMAG(ar7, hb4, hb5, hb6, hb7)
        HRD(hb0, "160"); HRD(hb1, "416"); HRD(hb2, "672"); HRD(hb3, "928");
        HRD(hb4, "176"); HRD(hb5, "432"); HRD(hb6, "688"); HRD(hb7, "944");
        ARD(ar10, "10240"); ARD(ar11, "11264");
        WAIT10
        // sub4: m4 8,9
        FMAG(ar8, ha0, ha1, ha2, ha3)
        FMAG(ar9, ha4, ha5, ha6, ha7)
        HRD(ha0, "192"); HRD(ha1, "448"); HRD(ha2, "704"); HRD(ha3, "960");
        HRD(ha4, "208"); HRD(ha5, "464"); HRD(ha6, "720"); HRD(ha7, "976");
        ARD(ar12, "12288"); ARD(ar13, "13312");
        WAIT10
        // sub5: m4 10,11
        FMAG(ar10, hb0, hb1, hb2, hb3)
        FMAG(ar11, hb4, hb5, hb6, hb7)
        HRD(hb0, "224"); HRD(hb1, "480"); HRD(hb2, "736"); HRD(hb3, "992");
        HRD(hb4, "240"); HRD(hb5, "496"); HRD(hb6, "752"); HRD(hb7, "1008");
        ARD(ar14, "14336"); ARD(ar15, "15360");
        WAIT10
        // sub6: m4 12,13
        FMAG(ar12, ha0, ha1, ha2, ha3)
        FMAG(ar13, ha4, ha5, ha6, ha7)
        asm volatile("s_waitcnt lgkmcnt(0)" ::: "memory");
        __builtin_amdgcn_sched_barrier(0);
        // sub7: m4 14,15
        FMAG(ar14, hb0, hb1, hb2, hb3)
        FMAG(ar15, hb4, hb5, hb6, hb7)

        h0 = a0; h1 = a1; h2 = a2; h3 = a3;
        h_s[0][k] = h0; h_s[1][k] = h1; h_s[2][k] = h2; h_s[3][k] = h3;
        // per-wave DS ops execute in order at the LDS unit: next iteration's
        // HRD reads (memory-clobbered asm) see these writes.

        const LAS float* t = rd_cur; rd_cur = rd_nxt; rd_nxt = (LAS float*)t;
    }
#undef ARD
#undef HRD
#undef FMAG
#undef WAIT10
}

// ---------------------------------------------------------------------------
// Phase C (R20): fused wfix + QK^T/S + output + gated RMSNorm. (unchanged)
// ---------------------------------------------------------------------------
__global__ __launch_bounds__(256) void out_k(const float* __restrict__ Qc,
                                             const float* __restrict__ Kc,
                                             const float* __restrict__ Wv,
                                             const float* __restrict__ Wk,
                                             const float* __restrict__ Hst,
                                             const float* __restrict__ bcum,
                                             const float* __restrict__ gate,
                                             const float* __restrict__ rms_w,
                                             unsigned short* __restrict__ o2) {
    __shared__ __align__(16) float q_s[CL * PAD];
    __shared__ __align__(16) float s_s[CL * PAD];   // Wk, then K, then S (swizzled)
    __shared__ __align__(16) float h_s[CL * PAD];
    __shared__ __align__(16) float w_s[CL * PAD];   // Wv -> W
    __shared__ float b_s[64];

    const int blk = blockIdx.x;
    const int bh = blk >> 5;
    const int c = blk & 31;
    const int b = bh >> 4;
    const int h = bh & 15;
    const int tid = threadIdx.x;

    const int qrow = tid >> 4;          // row chunk 0..15
    const int qcol = tid & 15;          // col chunk 0..15

    if (tid < 64) b_s[tid] = bcum[(size_t)blk * 64 + tid];
    {
        const float4* Qg = (const float4*)(Qc + (size_t)blk * 4096);
        const float4* Wkg = (const float4*)(Wk + (size_t)blk * 4096);
        const float4* Hg = (const float4*)(Hst + (size_t)blk * 4096);
        const float4* Wvg = (const float4*)(Wv + (size_t)blk * 4096);
#pragma unroll
        for (int i = 0; i < 4; ++i) {
            int f = tid + i * 256;
            int t = f >> 4;
            int c4 = f & 15;
            int d = t * PAD + c4 * 4;
            int dsz = t * PAD + ((c4 ^ (t >> 2)) << 2);     // s_s swizzled
            *(float4*)&q_s[d] = Qg[f];
            *(float4*)&s_s[dsz] = Wkg[f];                   // Wk (swizzled)
            *(float4*)&h_s[d] = Hg[f];
            *(float4*)&w_s[d] = Wvg[f];                     // Wv (plain)
        }
    }
    __syncthreads();

    // Phase 0 (fused wfix): W[t][v] = Wv[t][v] − Σ_kk Wk[t][kk]·H[kk][v].
    {
        const int t0 = qrow * 4, v0 = qcol * 4;
        float acc[4][4];
#pragma unroll
        for (int i = 0; i < 4; ++i) {
            float4 wv = *(const float4*)&w_s[(t0 + i) * PAD + v0];
            acc[i][0] = wv.x; acc[i][1] = wv.y; acc[i][2] = wv.z; acc[i][3] = wv.w;
        }
        for (int kk = 0; kk < 64; kk += 4) {
            const int ka = ((kk >> 2) ^ qrow) << 2;         // swizzled Wk read
            float4 wa0 = *(const float4*)&s_s[(t0 + 0) * PAD + ka];
            float4 wa1 = *(const float4*)&s_s[(t0 + 1) * PAD + ka];
            float4 wa2 = *(const float4*)&s_s[(t0 + 2) * PAD + ka];
            float4 wa3 = *(const float4*)&s_s[(t0 + 3) * PAD + ka];
            float4 hb0 = *(const float4*)&h_s[(kk + 0) * PAD + v0];
            float4 hb1 = *(const float4*)&h_s[(kk + 1) * PAD + v0];
            float4 hb2 = *(const float4*)&h_s[(kk + 2) * PAD + v0];
            float4 hb3 = *(const float4*)&h_s[(kk + 3) * PAD + v0];
            WSUB(x, hb0); WSUB(y, hb1); WSUB(z, hb2); WSUB(w, hb3);
        }
#pragma unroll
        for (int i = 0; i < 4; ++i)
            *(float4*)&w_s[(t0 + i) * PAD + v0] =
                make_float4(acc[i][0], acc[i][1], acc[i][2], acc[i][3]);
    }
    __syncthreads();   // all Wk reads done before s_s is overwritten with K

    // stage K into s_s (swizzled)
    {
        const float4* Kg = (const float4*)(Kc + (size_t)blk * 4096);
#pragma unroll
        for (int i = 0; i < 4; ++i) {
            int f = tid + i * 256;
            int t = f >> 4;
            int c4 = f & 15;
            int dsz = t * PAD + ((c4 ^ (t >> 2)) << 2);
            *(float4*)&s_s[dsz] = Kg[f];
        }
    }
    __syncthreads();

    // Phase 1: S = (Q K^T) ⊙ exp(b_t - b_s) [s<=t], overwrite s_s
    {
        const int t0 = qrow * 4, s0 = qcol * 4;
        float acc[4][4] = {};
        for (int kk = 0; kk < 64; kk += 4) {
            const int kb = ((kk >> 2) ^ qcol) << 2;
            float4 ta0 = *(const float4*)&q_s[(t0 + 0) * PAD + kk];
            float4 ta1 = *(const float4*)&q_s[(t0 + 1) * PAD + kk];
            float4 ta2 = *(const float4*)&q_s[(t0 + 2) * PAD + kk];
            float4 ta3 = *(const float4*)&q_s[(t0 + 3) * PAD + kk];
            float4 sb0 = *(const float4*)&s_s[(s0 + 0) * PAD + kb];
            float4 sb1 = *(const float4*)&s_s[(s0 + 1) * PAD + kb];
            float4 sb2 = *(const float4*)&s_s[(s0 + 2) * PAD + kb];
            float4 sb3 = *(const float4*)&s_s[(s0 + 3) * PAD + kb];
            acc[0][0] += DOT4(ta0, sb0); acc[0][1] += DOT4(ta0, sb1);
            acc[0][2] += DOT4(ta0, sb2); acc[0][3] += DOT4(ta0, sb3);
            acc[1][0] += DOT4(ta1, sb0); acc[1][1] += DOT4(ta1, sb1);
            acc[1][2] += DOT4(ta1, sb2); acc[1][3] += DOT4(ta1, sb3);
            acc[2][0] += DOT4(ta2, sb0); acc[2][1] += DOT4(ta2, sb1);
            acc[2][2] += DOT4(ta2, sb2); acc[2][3] += DOT4(ta2, sb3);
            acc[3][0] += DOT4(ta3, sb0); acc[3][1] += DOT4(ta3, sb1);
            acc[3][2] += DOT4(ta3, sb2); acc[3][3] += DOT4(ta3, sb3);
        }
        __syncthreads();   // all Q,K reads done before overwrite
#pragma unroll
        for (int i = 0; i < 4; ++i)
#pragma unroll
            for (int j = 0; j < 4; ++j) {
                const int t = t0 + i, s = s0 + j;
                // swizzled scalar store: chunk (s>>2)=qcol XOR (t>>2)=qrow
                s_s[t * PAD + ((qcol ^ qrow) << 2) + (s & 3)] =
                    (s <= t) ? acc[i][j] * __expf(b_s[t] - b_s[s]) : 0.0f;
            }
    }
    // scale q rows by e^{b_t}  (q_s plain)
#pragma unroll
    for (int i = 0; i < 16; ++i) {
        const int e = tid + i * 256;
        const int t = e >> 6;
        q_s[t * PAD + (e & 63)] *= __expf(b_s[t]);
    }
    __syncthreads();

    // Phase 2: O = S @ W + Qs @ H, then fused gated RMSNorm -> bf16
    {
        const int t0 = qrow * 4, v0 = qcol * 4;
        float acc[4][4] = {};
        for (int ss = 0; ss < 64; ss += 4) {
            const int ks = ((ss >> 2) ^ qrow) << 2;   // s_s swizzled read
            float4 sa0 = *(const float4*)&s_s[(t0 + 0) * PAD + ks];
            float4 sa1 = *(const float4*)&s_s[(t0 + 1) * PAD + ks];
            float4 sa2 = *(const float4*)&s_s[(t0 + 2) * PAD + ks];
            float4 sa3 = *(const float4*)&s_s[(t0 + 3) * PAD + ks];
            float4 wb0 = *(const float4*)&w_s[(ss + 0) * PAD + v0];
            float4 wb1 = *(const float4*)&w_s[(ss + 1) * PAD + v0];
            float4 wb2 = *(const float4*)&w_s[(ss + 2) * PAD + v0];
            float4 wb3 = *(const float4*)&w_s[(ss + 3) * PAD + v0];
            ACC16(x, wb0); ACC16(y, wb1); ACC16(z, wb2); ACC16(w, wb3);
        }
        for (int kk = 0; kk < 64; kk += 4) {
            float4 sa0 = *(const float4*)&q_s[(t0 + 0) * PAD + kk];
            float4 sa1 = *(const float4*)&q_s[(t0 + 1) * PAD + kk];
            float4 sa2 = *(const float4*)&q_s[(t0 + 2) * PAD + kk];
            float4 sa3 = *(const float4*)&q_s[(t0 + 3) * PAD + kk];
            float4 wb0 = *(const float4*)&h_s[(kk + 0) * PAD + v0];
            float4 wb1 = *(const float4*)&h_s[(kk + 1) * PAD + v0];
            float4 wb2 = *(const float4*)&h_s[(kk + 2) * PAD + v0];
            float4 wb3 = *(const float4*)&h_s[(kk + 3) * PAD + v0];
            ACC16(x, wb0); ACC16(y, wb1); ACC16(z, wb2); ACC16(w, wb3);
        }

        // fused gated RMSNorm epilogue (R19)
        const float4 rw = *(const float4*)&rms_w[v0];
#pragma unroll
        for (int i = 0; i < 4; ++i) {
            float ss2 = acc[i][0] * acc[i][0] + acc[i][1] * acc[i][1]
                      + acc[i][2] * acc[i][2] + acc[i][3] * acc[i][3];
            ss2 += __shfl_xor(ss2, 1);
            ss2 += __shfl_xor(ss2, 2);
            ss2 += __shfl_xor(ss2, 4);
            ss2 += __shfl_xor(ss2, 8);
            const float r = rsqrtf(ss2 * (1.0f / 64.0f) + 1e-5f);
            const int t = c * CL + t0 + i;
            const size_t row = (size_t)b * TT + t;
            const float4 gt = *(const float4*)&gate[row * HD + h * DK + v0];
            u16x4 o;
            o[0] = f2bf(acc[i][0] * r * rw.x * siluf_(gt.x));
            o[1] = f2bf(acc[i][1] * r * rw.y * siluf_(gt.y));
            o[2] = f2bf(acc[i][2] * r * rw.z * siluf_(gt.z));
            o[3] = f2bf(acc[i][3] * r * rw.w * siluf_(gt.w));
            *(u16x4*)&o2[row * HD + h * DK + v0] = o;
        }
    }
}

// ---------------------------------------------------------------------------
extern "C" void kernel_launch(void* const* d_in, const int* in_sizes, int n_in,
                              void* d_out, int out_size, void* d_ws, size_t ws_size,
                              hipStream_t stream) {
    (void)in_sizes; (void)n_in; (void)out_size; (void)ws_size;

    const float* x       = (const float*)d_in[0];
    const float* Wq      = (const float*)d_in[1];
    const float* Wk_     = (const float*)d_in[2];
    const float* Wv_     = (const float*)d_in[3];
    const float* Wa      = (const float*)d_in[4];
    const float* Wb      = (const float*)d_in[5];
    const float* Wg      = (const float*)d_in[6];
    const float* Wo      = (const float*)d_in[7];
    const float* conv_q  = (const float*)d_in[8];
    const float* conv_k  = (const float*)d_in[9];
    const float* conv_v  = (const float*)d_in[10];
    const float* A_log   = (const float*)d_in[11];
    const float* dt_bias = (const float*)d_in[12];
    const float* rms_w   = (const float*)d_in[13];
    float* out = (float*)d_out;

    float* ws = (float*)d_ws;
    const size_t NTOK = (size_t)BB * TT;     // 4096
    const size_t BIG = NTOK * HD;            // 4 Mi floats

    float* q_pre = ws + 0 * BIG;
    float* k_pre = ws + 1 * BIG;
    float* v_pre = ws + 2 * BIG;
    float* gatep = ws + 3 * BIG;
    float* Qc    = ws + 4 * BIG;
    float* Kc    = ws + 5 * BIG;
    float* gbuf  = ws + 6 * BIG;
    float* bbuf  = gbuf + NTOK * HH;
    float* bcumb = bbuf + NTOK * HH;

    // bf16 buffers after the fp32 region (wqt..wgt contiguous = fused B matrix)
    unsigned short* xb  = (unsigned short*)(bcumb + NTOK * HH);
    unsigned short* wqt = xb + (size_t)NTOK * DD;
    unsigned short* wkt = wqt + (size_t)DD * HD;
    unsigned short* wvt = wkt + (size_t)DD * HD;
    unsigned short* wgt = wvt + (size_t)DD * HD;
    unsigned short* wot = wgt + (size_t)DD * HD;

    // fp32 buffers after bf16 region: Bb + Hst (32 MB) + Wab_t (128 KB)
    float* Bbuf = (float*)(wot + (size_t)DD * HD);
    float* HstB = Bbuf + BIG;
    float* Wabt = HstB + BIG;

    // aliases (stream-ordered lifetimes):
    float* Wvb    = q_pre;   // prep_k out (Wv half, pre-fix)
    float* Wkb    = k_pre;   // prep_k out (Wk half)
    // A buffer aliases the xb/wqt region (dead after gemm_qkvg_k).
    float* Abuf   = (float*)xb;
    // o2 (bf16 output of fused out_k) aliases Abuf (dead after hrec_k);
    // disjoint from wot and from Qc/Kc (still read).
    unsigned short* o2b = (unsigned short*)Abuf;

    // casts
    castx_k<<<(int)(NTOK * DD / (256 * 8)), 256, 0, stream>>>(x, xb);
    dim3 tg(16, 16);
    castw_k<<<tg, 256, 0, stream>>>(Wq, wqt);
    castw_k<<<tg, 256, 0, stream>>>(Wk_, wkt);
    castw_k<<<tg, 256, 0, stream>>>(Wv_, wvt);
    castw_k<<<tg, 256, 0, stream>>>(Wg, wgt);
    castw_k<<<tg, 256, 0, stream>>>(Wo, wot);
    tw_k<<<32, 256, 0, stream>>>(Wa, Wb, Wabt);

    // fused QKVG projection: 256 blocks x 512 threads (256^2 8-phase, R13)
    gemm_qkvg_k<<<256, 512, 0, stream>>>(xb, wqt, q_pre, k_pre, v_pre, gatep);

    gbeta_k<<<(int)(NTOK / 8), 256, 0, stream>>>(x, Wabt, A_log, dt_bias, gbuf, bbuf);

    stage_k<<<BB * HH * NC, 64, 0, stream>>>(q_pre, k_pre, conv_q, conv_k, gbuf,
                                             Qc, Kc, bcumb);

    // prep_k (256 threads, 52KB LDS -> 3 blocks/CU, R21) emits A_c/B_c
    prep_k<<<BB * HH * NC, 256, 0, stream>>>(Kc, v_pre, conv_v, bcumb, bbuf,
                                             Wvb, Wkb, Abuf, Bbuf);

    hrec_k<<<BB * HH * VS, 64, 0, stream>>>(Abuf, Bbuf, HstB);

    // out_k fuses wfix + QK^T/S + output + gated RMSNorm (R20)
    out_k<<<BB * HH * NC, 256, 0, stream>>>(Qc, Kc, Wvb, Wkb, HstB, bcumb,
                                            gatep, rms_w, o2b);

    gemm_bf16_k<<<dim3(HD / 128, NTOK / 128), 256, 0, stream>>>(o2b, wot, out,
                                                                (int)NTOK, HD, DD);
}

// Round 13
// 386.393 us; speedup vs baseline: 1.3540x; 1.0637x over previous
//
#include <hip/hip_runtime.h>
#include <hip/hip_bf16.h>
#include <math.h>
#include <stdint.h>

// Problem constants
#define BB 2
#define TT 2048
#define DD 1024
#define HH 16
#define DK 64
#define HD 1024   // H*DK
#define NC 32     // chunks per sequence (TT/64)
#define CL 64     // chunk length
#define PAD 68    // padded LDS row stride (floats)
#define PADA 67   // A_s row stride (R16)
#define VS 16     // v-splits in hrec_k

typedef short bf16x8 __attribute__((ext_vector_type(8)));     // 8 bf16 (4 VGPRs)
typedef float f32x4 __attribute__((ext_vector_type(4)));      // MFMA acc
typedef unsigned short u16x8 __attribute__((ext_vector_type(8)));
typedef unsigned short u16x4 __attribute__((ext_vector_type(4)));

#define GAS __attribute__((address_space(1)))
#define LAS __attribute__((address_space(3)))

#define DOT4(a, b) ((a).x*(b).x + (a).y*(b).y + (a).z*(b).z + (a).w*(b).w)

// acc[i][j] += kf[i-component] * wv[j-component]   (one contraction step)
#define OUT16(acc, kf, wv) \
    acc[0][0] += kf.x * wv.x; acc[0][1] += kf.x * wv.y; acc[0][2] += kf.x * wv.z; acc[0][3] += kf.x * wv.w; \
    acc[1][0] += kf.y * wv.x; acc[1][1] += kf.y * wv.y; acc[1][2] += kf.y * wv.z; acc[1][3] += kf.y * wv.w; \
    acc[2][0] += kf.z * wv.x; acc[2][1] += kf.z * wv.y; acc[2][2] += kf.z * wv.z; acc[2][3] += kf.z * wv.w; \
    acc[3][0] += kf.w * wv.x; acc[3][1] += kf.w * wv.y; acc[3][2] += kf.w * wv.z; acc[3][3] += kf.w * wv.w;

// acc[i][j] -= wa_i.c * hv[j]   (c = component selecting m)
#define WSUB(c, hv) \
    acc[0][0] -= wa0.c * hv.x; acc[0][1] -= wa0.c * hv.y; acc[0][2] -= wa0.c * hv.z; acc[0][3] -= wa0.c * hv.w; \
    acc[1][0] -= wa1.c * hv.x; acc[1][1] -= wa1.c * hv.y; acc[1][2] -= wa1.c * hv.z; acc[1][3] -= wa1.c * hv.w; \
    acc[2][0] -= wa2.c * hv.x; acc[2][1] -= wa2.c * hv.y; acc[2][2] -= wa2.c * hv.z; acc[2][3] -= wa2.c * hv.w; \
    acc[3][0] -= wa3.c * hv.x; acc[3][1] -= wa3.c * hv.y; acc[3][2] -= wa3.c * hv.z; acc[3][3] -= wa3.c * hv.w;

// acc[i][j] += sa_i.c * wv[j]   (c = component selecting the contraction idx)
#define ACC16(c, wv) \
    acc[0][0] += sa0.c * wv.x; acc[0][1] += sa0.c * wv.y; acc[0][2] += sa0.c * wv.z; acc[0][3] += sa0.c * wv.w; \
    acc[1][0] += sa1.c * wv.x; acc[1][1] += sa1.c * wv.y; acc[1][2] += sa1.c * wv.z; acc[1][3] += sa1.c * wv.w; \
    acc[2][0] += sa2.c * wv.x; acc[2][1] += sa2.c * wv.y; acc[2][2] += sa2.c * wv.z; acc[2][3] += sa2.c * wv.w; \
    acc[3][0] += sa3.c * wv.x; acc[3][1] += sa3.c * wv.y; acc[3][2] += sa3.c * wv.z; acc[3][3] += sa3.c * wv.w;

__device__ __forceinline__ float sigmoidf_(float x) { return 1.0f / (1.0f + expf(-x)); }
__device__ __forceinline__ float siluf_(float x) { return x * sigmoidf_(x); }

// round-to-nearest-even fp32 -> bf16
__device__ __forceinline__ unsigned short f2bf(float f) {
    unsigned int u = __builtin_bit_cast(unsigned int, f);
    u = (u + 0x7fffu + ((u >> 16) & 1u)) >> 16;
    return (unsigned short)u;
}

// ---------------------------------------------------------------------------
// Cast x (fp32) -> bf16, flat.
// ---------------------------------------------------------------------------
__global__ __launch_bounds__(256) void castx_k(const float* __restrict__ src,
                                               unsigned short* __restrict__ dst) {
    const size_t idx = (size_t)blockIdx.x * 256 + threadIdx.x;
    float4 a = *(const float4*)&src[idx * 8];
    float4 b = *(const float4*)&src[idx * 8 + 4];
    u16x8 o;
    o[0] = f2bf(a.x); o[1] = f2bf(a.y); o[2] = f2bf(a.z); o[3] = f2bf(a.w);
    o[4] = f2bf(b.x); o[5] = f2bf(b.y); o[6] = f2bf(b.z); o[7] = f2bf(b.w);
    *(u16x8*)&dst[idx * 8] = o;
}

// ---------------------------------------------------------------------------
// Transpose+cast weight: W[K=1024][N=1024] fp32 -> Wt[N][K] bf16.
// ---------------------------------------------------------------------------
__global__ __launch_bounds__(256) void castw_k(const float* __restrict__ W,
                                               unsigned short* __restrict__ Wt) {
    __shared__ float t_s[64][65];
    const int tid = threadIdx.x;
    const int rr = tid >> 4;
    const int cc = tid & 15;
    const int r0 = blockIdx.y * 64;
    const int c0 = blockIdx.x * 64;
#pragma unroll
    for (int i = 0; i < 4; ++i) {
        const int row = rr + i * 16;
        float4 v = *(const float4*)&W[(size_t)(r0 + row) * 1024 + c0 + cc * 4];
        t_s[row][cc * 4 + 0] = v.x;
        t_s[row][cc * 4 + 1] = v.y;
        t_s[row][cc * 4 + 2] = v.z;
        t_s[row][cc * 4 + 3] = v.w;
    }
    __syncthreads();
#pragma unroll
    for (int i = 0; i < 4; ++i) {
        const int nr = rr + i * 16;
        u16x4 o;
#pragma unroll
        for (int d = 0; d < 4; ++d) o[d] = f2bf(t_s[cc * 4 + d][nr]);
        *(u16x4*)&Wt[(size_t)(c0 + nr) * 1024 + r0 + cc * 4] = o;
    }
}

// ---------------------------------------------------------------------------
// transpose Wa|Wb [1024][16] -> Wab_t [32][1024] fp32 (R8)
// ---------------------------------------------------------------------------
__global__ __launch_bounds__(256) void tw_k(const float* __restrict__ Wa,
                                            const float* __restrict__ Wb,
                                            float* __restrict__ Wt) {
    const int o = blockIdx.x;          // 0..31
    const int h = o & 15;
    const float* W = (o < 16) ? Wa : Wb;
    const int tid = threadIdx.x;
    float4 v;
    v.x = W[(size_t)(tid * 4 + 0) * HH + h];
    v.y = W[(size_t)(tid * 4 + 1) * HH + h];
    v.z = W[(size_t)(tid * 4 + 2) * HH + h];
    v.w = W[(size_t)(tid * 4 + 3) * HH + h];
    *(float4*)&Wt[(size_t)o * DD + tid * 4] = v;
}

// ---------------------------------------------------------------------------
// bf16 MFMA GEMM (m97 structure) — generic single-output (used for Wo).
// ---------------------------------------------------------------------------
__global__ __launch_bounds__(256) void gemm_bf16_k(const unsigned short* __restrict__ A,
                                                   const unsigned short* __restrict__ Bt,
                                                   float* __restrict__ C,
                                                   int M, int N, int Kd) {
    __shared__ unsigned short a_s[128 * 32];
    __shared__ unsigned short b_s[128 * 32];

    const int tid = threadIdx.x;
    const int wave = tid >> 6;
    const int lane = tid & 63;
    const int m0 = blockIdx.y * 128;
    const int n0 = blockIdx.x * 128;

    const int quad = lane >> 4;
    const int l16 = lane & 15;
    const int wr = wave >> 1;
    const int wc = wave & 1;

    const int srow = lane >> 2;
    const int sseg = lane & 3;

    f32x4 acc[4][4];
#pragma unroll
    for (int i = 0; i < 4; ++i)
#pragma unroll
        for (int j = 0; j < 4; ++j) acc[i][j] = (f32x4){0.f, 0.f, 0.f, 0.f};

    for (int k0 = 0; k0 < Kd; k0 += 32) {
        __syncthreads();
#pragma unroll
        for (int c = 0; c < 2; ++c) {
            const int region = wave * 2 + c;
            const int r0t = region * 16;
            const int ra = r0t + srow;
            const unsigned short* ga = A + (size_t)(m0 + ra) * Kd + k0 + sseg * 8;
            const unsigned short* gb = Bt + (size_t)(n0 + ra) * Kd + k0 + sseg * 8;
            __builtin_amdgcn_global_load_lds((const GAS unsigned int*)ga,
                                             (LAS unsigned int*)&a_s[r0t * 32], 16, 0, 0);
            __builtin_amdgcn_global_load_lds((const GAS unsigned int*)gb,
                                             (LAS unsigned int*)&b_s[r0t * 32], 16, 0, 0);
        }
        __syncthreads();

        bf16x8 af[4], bfr[4];
#pragma unroll
        for (int i = 0; i < 4; ++i)
            af[i] = *(const bf16x8*)&a_s[(wr * 64 + i * 16 + l16) * 32 + quad * 8];
#pragma unroll
        for (int j = 0; j < 4; ++j)
            bfr[j] = *(const bf16x8*)&b_s[(wc * 64 + j * 16 + l16) * 32 + quad * 8];
#pragma unroll
        for (int i = 0; i < 4; ++i)
#pragma unroll
            for (int j = 0; j < 4; ++j)
                acc[i][j] = __builtin_amdgcn_mfma_f32_16x16x32_bf16(af[i], bfr[j], acc[i][j], 0, 0, 0);
    }

#pragma unroll
    for (int i = 0; i < 4; ++i)
#pragma unroll
        for (int j = 0; j < 4; ++j) {
            const int col = n0 + wc * 64 + j * 16 + l16;
#pragma unroll
            for (int r = 0; r < 4; ++r) {
                const int row = m0 + wr * 64 + i * 16 + quad * 4 + r;
                C[(size_t)row * N + col] = acc[i][j][r];
            }
        }
}

// ---------------------------------------------------------------------------
// Fused QKVG projection GEMM — R13 structure (unchanged): 256x256 tile,
// 8 waves, BK=64, swizzled LDS, counted vmcnt/lgkmcnt, setprio.
// ---------------------------------------------------------------------------
#define DSRQ(D, P, OFF) asm volatile("ds_read_b128 %0, %1 offset:" OFF \
                                     : "=v"(D) : "v"(P))

__global__ __launch_bounds__(512, 2) void gemm_qkvg_k(const unsigned short* __restrict__ A,
                                                      const unsigned short* __restrict__ Bt,
                                                      float* __restrict__ Oq,
                                                      float* __restrict__ Ok,
                                                      float* __restrict__ Ov,
                                                      float* __restrict__ Og) {
    __shared__ __align__(16) unsigned char lds_all[131072];   // 128 KiB

    const int tid = threadIdx.x;
    const int w = tid >> 6;           // wave 0..7
    const int lane = tid & 63;
    const int l16 = lane & 15;
    const int quad = lane >> 4;
    const int wr = w >> 2;            // 0..1 : 128-row half
    const int wc = w & 3;             // 0..3 : 64-col quarter

    // XCD-aware block swizzle (bijective: 256 % 8 == 0)
    const int bid = blockIdx.x;
    const int wg = (bid & 7) * 32 + (bid >> 3);
    const int m0 = (wg >> 4) * 256;
    const int n0 = (wg & 15) * 256;

    // staging: lane (lr,ls) sources the PRE-SWIZZLED slot ls^lr so the
    // swizzled read finds logical data (rule #21).
    const int lr = lane >> 3;
    const int ls = lane & 7;
    const int sslot = ls ^ lr;
    const unsigned short* srcA = A + (size_t)(m0 + lr) * DD + sslot * 8 + (size_t)w * 8 * DD;
    const unsigned short* srcB = Bt + (size_t)(n0 + lr) * DD + sslot * 8 + (size_t)w * 8 * DD;

    const LAS unsigned char* LB = (const LAS unsigned char*)&lds_all[0];

    // swizzled read base (buf0, ksub0); ^64 toggles ksub, +32768 toggles buf
    const unsigned int xq = (unsigned int)((quad ^ (l16 & 7)) << 4);
    const unsigned int uA0 = (unsigned int)((wr * 128 + l16) * 128) + xq;
    const unsigned int uB0 = 65536u + (unsigned int)((wc * 64 + l16) * 128) + xq;

    f32x4 acc[8][4];
#pragma unroll
    for (int i = 0; i < 8; ++i)
#pragma unroll
        for (int j = 0; j < 4; ++j) acc[i][j] = (f32x4){0.f, 0.f, 0.f, 0.f};

#define STG1Q(T, IA) \
    __builtin_amdgcn_global_load_lds( \
        (const GAS unsigned int*)(srcA + (size_t)(IA) * 65536 + (size_t)(T) * 64), \
        (LAS unsigned int*)(LB + (((unsigned)((T) & 1)) << 15) + ((IA) * 8 + w) * 1024), 16, 0, 0); \
    __builtin_amdgcn_global_load_lds( \
        (const GAS unsigned int*)(srcB + (size_t)(IA) * 65536 + (size_t)(T) * 64), \
        (LAS unsigned int*)(LB + 65536u + (((unsigned)((T) & 1)) << 15) + ((IA) * 8 + w) * 1024), 16, 0, 0);
#define STGQ(T) { STG1Q(T, 0) STG1Q(T, 1) STG1Q(T, 2) STG1Q(T, 3) }

    STGQ(0);                           // prologue: stage K-step 0 into buf0

    bf16x8 aG0[4], aG1[4], b0[4], b1[4];

#pragma unroll 1
    for (int t = 0; t < 16; ++t) {
        if (t + 1 < 16) {
            STGQ(t + 1);               // 8 loads for next K-step -> other buf
            asm volatile("s_waitcnt vmcnt(8)" ::: "memory");   // stage(t) done
        } else {
            asm volatile("s_waitcnt vmcnt(0)" ::: "memory");
        }
        __builtin_amdgcn_s_barrier();  // buf(t&1) staged by ALL waves

        const unsigned int boff = ((unsigned)(t & 1)) << 15;
        const LAS unsigned char* pA0 = LB + (uA0 + boff);
        const LAS unsigned char* pA1 = LB + ((uA0 ^ 64u) + boff);
        const LAS unsigned char* pB0 = LB + (uB0 + boff);
        const LAS unsigned char* pB1 = LB + ((uB0 ^ 64u) + boff);

        // issue 16 reads: b0, aG0(k0), aG1(k0), b1
        DSRQ(b0[0], pB0, "0");    DSRQ(b0[1], pB0, "2048");
        DSRQ(b0[2], pB0, "4096"); DSRQ(b0[3], pB0, "6144");
        DSRQ(aG0[0], pA0, "0");    DSRQ(aG0[1], pA0, "2048");
        DSRQ(aG0[2], pA0, "4096"); DSRQ(aG0[3], pA0, "6144");
        DSRQ(aG1[0], pA0, "8192");  DSRQ(aG1[1], pA0, "10240");
        DSRQ(aG1[2], pA0, "12288"); DSRQ(aG1[3], pA0, "14336");
        DSRQ(b1[0], pB1, "0");    DSRQ(b1[1], pB1, "2048");
        DSRQ(b1[2], pB1, "4096"); DSRQ(b1[3], pB1, "6144");

        asm volatile("s_waitcnt lgkmcnt(8)" ::: "memory");   // b0,aG0 ready
        __builtin_amdgcn_sched_barrier(0);
        __builtin_amdgcn_s_setprio(1);
#pragma unroll
        for (int ia = 0; ia < 4; ++ia)
#pragma unroll
            for (int j = 0; j < 4; ++j)
                acc[ia][j] = __builtin_amdgcn_mfma_f32_16x16x32_bf16(aG0[ia], b0[j], acc[ia][j], 0, 0, 0);
        __builtin_amdgcn_s_setprio(0);

        DSRQ(aG0[0], pA1, "0");    DSRQ(aG0[1], pA1, "2048");   // aG0 <- ksub1
        DSRQ(aG0[2], pA1, "4096"); DSRQ(aG0[3], pA1, "6144");
        asm volatile("s_waitcnt lgkmcnt(4)" ::: "memory");   // aG1(k0),b1 ready
        __builtin_amdgcn_sched_barrier(0);
        __builtin_amdgcn_s_setprio(1);
#pragma unroll
        for (int ia = 0; ia < 4; ++ia)
#pragma unroll
            for (int j = 0; j < 4; ++j)
                acc[4 + ia][j] = __builtin_amdgcn_mfma_f32_16x16x32_bf16(aG1[ia], b0[j], acc[4 + ia][j], 0, 0, 0);
        __builtin_amdgcn_s_setprio(0);

        DSRQ(aG1[0], pA1, "8192");  DSRQ(aG1[1], pA1, "10240"); // aG1 <- ksub1
        DSRQ(aG1[2], pA1, "12288"); DSRQ(aG1[3], pA1, "14336");
        asm volatile("s_waitcnt lgkmcnt(4)" ::: "memory");   // aG0(k1) ready
        __builtin_amdgcn_sched_barrier(0);
        __builtin_amdgcn_s_setprio(1);
#pragma unroll
        for (int ia = 0; ia < 4; ++ia)
#pragma unroll
            for (int j = 0; j < 4; ++j)
                acc[ia][j] = __builtin_amdgcn_mfma_f32_16x16x32_bf16(aG0[ia], b1[j], acc[ia][j], 0, 0, 0);
        __builtin_amdgcn_s_setprio(0);

        asm volatile("s_waitcnt lgkmcnt(0)" ::: "memory");   // aG1(k1) ready
        __builtin_amdgcn_sched_barrier(0);
        __builtin_amdgcn_s_setprio(1);
#pragma unroll
        for (int ia = 0; ia < 4; ++ia)
#pragma unroll
            for (int j = 0; j < 4; ++j)
                acc[4 + ia][j] = __builtin_amdgcn_mfma_f32_16x16x32_bf16(aG1[ia], b1[j], acc[4 + ia][j], 0, 0, 0);
        __builtin_amdgcn_s_setprio(0);

        __builtin_amdgcn_s_barrier();  // all reads of buf(t&1) done before
                                       // next iteration overwrites it
    }
#undef STGQ
#undef STG1Q

    float* Cd = (n0 < 1024) ? Oq : (n0 < 2048) ? Ok : (n0 < 3072) ? Ov : Og;
    const int nl = n0 & 1023;
    const int rbase = m0 + wr * 128 + quad * 4;
    const int cbase = nl + wc * 64 + l16;
#pragma unroll
    for (int ia = 0; ia < 8; ++ia)
#pragma unroll
        for (int j = 0; j < 4; ++j) {
            const int col = cbase + j * 16;
#pragma unroll
            for (int r = 0; r < 4; ++r)
                Cd[(size_t)(rbase + ia * 16 + r) * HD + col] = acc[ia][j][r];
        }
}

// ---------------------------------------------------------------------------
// g / beta kernel (R8, unchanged)
// ---------------------------------------------------------------------------
__global__ __launch_bounds__(256) void gbeta_k(const float* __restrict__ x,
                                               const float* __restrict__ Wt,
                                               const float* __restrict__ A_log,
                                               const float* __restrict__ dt_bias,
                                               float* __restrict__ g,
                                               float* __restrict__ beta) {
    __shared__ __align__(16) float xs[8][DD];
    const int r0 = blockIdx.x * 8;
    const int tid = threadIdx.x;

#pragma unroll
    for (int i = 0; i < 8; ++i) {
        const int f = tid + i * 256;
        const int r = f >> 8;
        const int col = (f & 255) * 4;
        *(float4*)&xs[r][col] = *(const float4*)&x[((size_t)r0 + r) * DD + col];
    }
    __syncthreads();

    const int out = tid >> 3;
    const int part = tid & 7;
    const int h = out & 15;
    const float* Wrow = Wt + (size_t)out * DD;

    float a0 = 0, a1 = 0, a2 = 0, a3 = 0, a4 = 0, a5 = 0, a6 = 0, a7 = 0;
#pragma unroll 4
    for (int i = 0; i < 32; ++i) {
        const int d = i * 32 + part * 4;
        const float4 wv = *(const float4*)&Wrow[d];
        float4 x0 = *(const float4*)&xs[0][d];
        float4 x1 = *(const float4*)&xs[1][d];
        float4 x2 = *(const float4*)&xs[2][d];
        float4 x3 = *(const float4*)&xs[3][d];
        float4 x4 = *(const float4*)&xs[4][d];
        float4 x5 = *(const float4*)&xs[5][d];
        float4 x6 = *(const float4*)&xs[6][d];
        float4 x7 = *(const float4*)&xs[7][d];
        a0 += DOT4(x0, wv); a1 += DOT4(x1, wv);
        a2 += DOT4(x2, wv); a3 += DOT4(x3, wv);
        a4 += DOT4(x4, wv); a5 += DOT4(x5, wv);
        a6 += DOT4(x6, wv); a7 += DOT4(x7, wv);
    }
#pragma unroll
    for (int s = 1; s <= 4; s <<= 1) {
        a0 += __shfl_xor(a0, s); a1 += __shfl_xor(a1, s);
        a2 += __shfl_xor(a2, s); a3 += __shfl_xor(a3, s);
        a4 += __shfl_xor(a4, s); a5 += __shfl_xor(a5, s);
        a6 += __shfl_xor(a6, s); a7 += __shfl_xor(a7, s);
    }

    if (part == 0) {
        float sv[8] = {a0, a1, a2, a3, a4, a5, a6, a7};
        if (out < 16) {
            const float ae = -expf(A_log[h]);
            const float db = dt_bias[h];
#pragma unroll
            for (int r = 0; r < 8; ++r) {
                float v = sv[r] + db;
                float sp = (v > 20.0f) ? v : log1pf(expf(v));
                g[((size_t)r0 + r) * HH + h] = ae * sp;
            }
        } else {
#pragma unroll
            for (int r = 0; r < 8; ++r)
                beta[((size_t)r0 + r) * HH + h] = sigmoidf_(sv[r]);
        }
    }
}

// ---------------------------------------------------------------------------
// Phase A (R23 = R22 + race fix): FUSED stage + triangular solve + ab.
// stage_k is absorbed: Q/K conv runs in the V-conv structure (4 waves x 16
// timesteps; warmup reads the same raw q_pre/k_pre values the sliding
// window held -> expression-identical); g-cumsum is the same shfl_up scan
// in wave 0. prep writes Qc/Kc/bcum, fills k_s/wk_s directly, and emits
// A_c/B_c. RACE FIX (R23): Wv/Wk now go to DEDICATED buffers (launcher) —
// in R22 they aliased q_pre/k_pre which this kernel still reads (cross-
// block RAW race). ab-tail re-stage reads back this block's own Kc write
// (visible via the intervening barriers' vmcnt drain). Bit-identical.
// LDS 52 KB (R21 overlays: A_s aliases k_s; T in A_s diag) -> 3 blocks/CU.
// ---------------------------------------------------------------------------
__global__ __launch_bounds__(256) void prep_k(const float* __restrict__ q_pre,
                                              const float* __restrict__ k_pre,
                                              const float* __restrict__ v_pre,
                                              const float* __restrict__ cq,
                                              const float* __restrict__ ck,
                                              const float* __restrict__ cv,
                                              const float* __restrict__ g,
                                              const float* __restrict__ bbuf,
                                              float* __restrict__ Qc,
                                              float* __restrict__ Kc,
                                              float* __restrict__ bcum,
                                              float* __restrict__ Wv,
                                              float* __restrict__ Wk,
                                              float* __restrict__ Ab,
                                              float* __restrict__ Bb) {
    __shared__ __align__(16) float kA_s[CL * PAD];   // k_s / A_s / k_s again
    __shared__ __align__(16) float wv_s[CL * PAD];
    __shared__ __align__(16) float wk_s[CL * PAD];
    __shared__ float b_s[CL], beta_s[CL], bk_s[CL], e_s[CL];

    float* const k_s = kA_s;   // stride PAD, chunk-swizzled
    float* const A_s = kA_s;   // stride PADA (fits: 64*67 <= 64*68)

    const int blk = blockIdx.x;
    const int bh = blk >> 5;
    const int c = blk & 31;
    const int b = bh >> 4;
    const int h = bh & 15;
    const int tid = threadIdx.x;

    // ---- fused stage: g-cumsum scan (wave 0; same shfl_up scan as stage_k)
    if (tid < 64) {
        float cum = g[((size_t)b * TT + c * CL + tid) * HH + h];
#pragma unroll
        for (int s = 1; s < 64; s <<= 1) {
            float u = __shfl_up(cum, s);
            if (tid >= s) cum += u;
        }
        b_s[tid] = cum;
        bcum[(size_t)blk * 64 + tid] = cum;    // for out_k
    }
    __syncthreads();
    if (tid < 64) {
        float bv = b_s[tid];
        float bC = b_s[63];
        float be = bbuf[((size_t)b * TT + c * CL + tid) * HH + h];
        beta_s[tid] = be;
        bk_s[tid] = be * __expf(bv);
        e_s[tid] = __expf(bC - bv);
    }
    __syncthreads();

    // ---- fused stage: Q/K conv + silu + l2norm (4 waves x 16 timesteps)
    {
        const int lane = tid & 63;
        const int q4 = tid >> 6;
        const int ch = h * DK + lane;
        const float4 wq4v = *(const float4*)&cq[ch * 4];
        const float4 wk4v = *(const float4*)&ck[ch * 4];
        const int T0 = c * CL + q4 * 16;
        float qw0 = 0, qw1 = 0, qw2 = 0, kw0 = 0, kw1 = 0, kw2 = 0;
        if (T0 - 3 >= 0) { size_t bi = ((size_t)b * TT + T0 - 3) * HD + ch; qw0 = q_pre[bi]; kw0 = k_pre[bi]; }
        if (T0 - 2 >= 0) { size_t bi = ((size_t)b * TT + T0 - 2) * HD + ch; qw1 = q_pre[bi]; kw1 = k_pre[bi]; }
        if (T0 - 1 >= 0) { size_t bi = ((size_t)b * TT + T0 - 1) * HD + ch; qw2 = q_pre[bi]; kw2 = k_pre[bi]; }
        float* Qo = Qc + (size_t)blk * 4096;
        float* Ko = Kc + (size_t)blk * 4096;
#pragma unroll 1
        for (int i = 0; i < 16; ++i) {
            const int tt = q4 * 16 + i;            // 0..63 within chunk
            const int t = T0 + i;
            const size_t bi = ((size_t)b * TT + t) * HD + ch;
            const float qc_ = q_pre[bi];
            const float kc_ = k_pre[bi];
            float qa = qw0 * wq4v.x + qw1 * wq4v.y + qw2 * wq4v.z + qc_ * wq4v.w;
            float ka = kw0 * wk4v.x + kw1 * wk4v.y + kw2 * wk4v.z + kc_ * wk4v.w;
            qw0 = qw1; qw1 = qw2; qw2 = qc_;
            kw0 = kw1; kw1 = kw2; kw2 = kc_;
            qa = siluf_(qa);
            ka = siluf_(ka);
            float qs2 = qa * qa, ks2 = ka * ka;
#pragma unroll
            for (int s = 32; s > 0; s >>= 1) {
                qs2 += __shfl_xor(qs2, s);
                ks2 += __shfl_xor(ks2, s);
            }
            const float qn = qa * rsqrtf(qs2 + 1e-6f) * 0.125f;
            const float kn = ka * rsqrtf(ks2 + 1e-6f);
            Qo[tt * 64 + lane] = qn;
            Ko[tt * 64 + lane] = kn;
            // LDS: k_s swizzled (scalar equiv of the chunk swizzle), wk_s plain
            const int scol = (((lane >> 2) ^ (tt >> 2)) << 2) + (lane & 3);
            k_s[tt * PAD + scol] = kn;
            wk_s[tt * PAD + lane] = kn * bk_s[tt];
        }
    }

    // ---- V conv (unchanged) -> wv_s
    {
        const int lane = tid & 63;
        const int q4 = tid >> 6;
        const int ch = h * DK + lane;
        const float4 wv4 = *(const float4*)&cv[ch * 4];
        const int T0 = c * CL + q4 * 16;
        float w0 = 0, w1 = 0, w2 = 0;
        if (T0 - 3 >= 0) w0 = v_pre[((size_t)b * TT + T0 - 3) * HD + ch];
        if (T0 - 2 >= 0) w1 = v_pre[((size_t)b * TT + T0 - 2) * HD + ch];
        if (T0 - 1 >= 0) w2 = v_pre[((size_t)b * TT + T0 - 1) * HD + ch];
#pragma unroll 1
        for (int i = 0; i < 16; ++i) {
            const int t = T0 + i;
            const float vc_ = v_pre[((size_t)b * TT + t) * HD + ch];
            float va = w0 * wv4.x + w1 * wv4.y + w2 * wv4.z + vc_ * wv4.w;
            w0 = w1; w1 = w2; w2 = vc_;
            va = siluf_(va);
            wv_s[(q4 * 16 + i) * PAD + lane] = va * beta_s[q4 * 16 + i];
        }
    }
    __syncthreads();

    // QK^T: all k_s reads complete before the barrier, then A_s (aliasing
    // k_s) is written — safe write-after-read (R21).
    {
        const int qrow = tid >> 4;          // = (t0+i)>>2 for i in 0..3
        const int qcol = tid & 15;          // = (s0+j)>>2 for j in 0..3
        const int t0 = qrow * 4, s0 = qcol * 4;
        float acc[4][4] = {};
        for (int kk = 0; kk < 64; kk += 4) {
            const int ka = ((kk >> 2) ^ qrow) << 2;
            const int kb = ((kk >> 2) ^ qcol) << 2;
            float4 ta0 = *(const float4*)&k_s[(t0 + 0) * PAD + ka];
            float4 ta1 = *(const float4*)&k_s[(t0 + 1) * PAD + ka];
            float4 ta2 = *(const float4*)&k_s[(t0 + 2) * PAD + ka];
            float4 ta3 = *(const float4*)&k_s[(t0 + 3) * PAD + ka];
            float4 sb0 = *(const float4*)&k_s[(s0 + 0) * PAD + kb];
            float4 sb1 = *(const float4*)&k_s[(s0 + 1) * PAD + kb];
            float4 sb2 = *(const float4*)&k_s[(s0 + 2) * PAD + kb];
            float4 sb3 = *(const float4*)&k_s[(s0 + 3) * PAD + kb];
            acc[0][0] += DOT4(ta0, sb0); acc[0][1] += DOT4(ta0, sb1);
            acc[0][2] += DOT4(ta0, sb2); acc[0][3] += DOT4(ta0, sb3);
            acc[1][0] += DOT4(ta1, sb0); acc[1][1] += DOT4(ta1, sb1);
            acc[1][2] += DOT4(ta1, sb2); acc[1][3] += DOT4(ta1, sb3);
            acc[2][0] += DOT4(ta2, sb0); acc[2][1] += DOT4(ta2, sb1);
            acc[2][2] += DOT4(ta2, sb2); acc[2][3] += DOT4(ta2, sb3);
            acc[3][0] += DOT4(ta3, sb0); acc[3][1] += DOT4(ta3, sb1);
            acc[3][2] += DOT4(ta3, sb2); acc[3][3] += DOT4(ta3, sb3);
        }
        __syncthreads();   // every thread's k_s reads done before A_s writes
#pragma unroll
        for (int i = 0; i < 4; ++i)
#pragma unroll
            for (int j = 0; j < 4; ++j) {
                const int t = t0 + i, s = s0 + j;
                A_s[t * PADA + s] = (s < t) ? acc[i][j] * beta_s[t] * __expf(b_s[t] - b_s[s]) : 0.0f;
            }
    }
    __syncthreads();

    // Block inverse; T stored into A_s's block-diagonal (R21).
    if (tid < 64) {
        const int d = tid >> 4;
        const int col = tid & 15;
        const int base = d * 16;
        float tcol[16];
#pragma unroll
        for (int s = 0; s < 16; ++s) tcol[s] = (s == col) ? 1.0f : 0.0f;
#pragma unroll
        for (int t = 1; t < 16; ++t) {
            float a = 0.0f;
#pragma unroll
            for (int s = 0; s < 16; ++s)
                if (s < t) a += A_s[(base + t) * PADA + base + s] * tcol[s];
            tcol[t] -= a;
        }
#pragma unroll
        for (int t = 0; t < 16; ++t)
            A_s[(base + t) * PADA + base + col] = tcol[t];   // T -> diag block
    }
    __syncthreads();

    // Blocked triangular apply; T read from A_s block-diagonal (R21).
    {
        const int r = tid >> 4;
        const int cg = tid & 15;
        float* Wc = (cg < 8) ? wv_s : wk_s;
        const int cc = (cg & 7) * 8;

        for (int tb = 0; tb < 4; ++tb) {
            const int t = tb * 16 + r;
            if (tb > 0) {
                float4 lo = *(const float4*)&Wc[t * PAD + cc];
                float4 hi = *(const float4*)&Wc[t * PAD + cc + 4];
#pragma unroll 4
                for (int s = 0; s < tb * 16; ++s) {
                    const float a = A_s[t * PADA + s];
                    float4 wlo = *(const float4*)&Wc[s * PAD + cc];
                    float4 whi = *(const float4*)&Wc[s * PAD + cc + 4];
                    lo.x -= a * wlo.x; lo.y -= a * wlo.y; lo.z -= a * wlo.z; lo.w -= a * wlo.w;
                    hi.x -= a * whi.x; hi.y -= a * whi.y; hi.z -= a * whi.z; hi.w -= a * whi.w;
                }
                *(float4*)&Wc[t * PAD + cc] = lo;
                *(float4*)&Wc[t * PAD + cc + 4] = hi;
            }
            __syncthreads();
            float4 alo = make_float4(0, 0, 0, 0);
            float4 ahi = make_float4(0, 0, 0, 0);
#pragma unroll 4
            for (int s = 0; s < 16; ++s) {
                const float tv = A_s[(tb * 16 + r) * PADA + tb * 16 + s];   // T
                float4 wlo = *(const float4*)&Wc[(tb * 16 + s) * PAD + cc];
                float4 whi = *(const float4*)&Wc[(tb * 16 + s) * PAD + cc + 4];
                alo.x += tv * wlo.x; alo.y += tv * wlo.y; alo.z += tv * wlo.z; alo.w += tv * wlo.w;
                ahi.x += tv * whi.x; ahi.y += tv * whi.y; ahi.z += tv * whi.z; ahi.w += tv * whi.w;
            }
            __syncthreads();
            *(float4*)&Wc[t * PAD + cc] = alo;
            *(float4*)&Wc[t * PAD + cc + 4] = ahi;
            __syncthreads();
        }
    }

    // Re-stage K (A_s dead) for the ab tail — reads back this block's own
    // Kc write (visible after the intervening barriers' vmcnt drain; this
    // block never read Kc before, so no stale L1 line)
    {
        const float4* Kg = (const float4*)(Kc + (size_t)blk * 4096);
#pragma unroll
        for (int i = 0; i < 4; ++i) {
            int f = tid + i * 256;
            int t = f >> 4;
            int c4 = f & 15;
            int dsz = t * PAD + ((c4 ^ (t >> 2)) << 2);
            *(float4*)&k_s[dsz] = Kg[f];
        }
    }

    // Wv/Wk writeback (reads wv_s/wk_s only — overlaps re-stage latency)
    float4* Wvg = (float4*)(Wv + (size_t)blk * 4096);
    float4* Wkg = (float4*)(Wk + (size_t)blk * 4096);
#pragma unroll
    for (int i = 0; i < 4; ++i) {
        int f = tid + i * 256;
        int d = (f >> 4) * PAD + (f & 15) * 4;
        Wvg[f] = *(float4*)&wv_s[d];
        Wkg[f] = *(float4*)&wk_s[d];
    }
    __syncthreads();   // K re-staged by all threads before ab reads

    // ---- fused ab (R17): A_c, B_c from LDS-resident k_s/wk_s/wv_s ----
    {
        const int k0q = tid >> 4;            // col chunk 0..15
        const int k0 = k0q * 4;
        const int m0 = (tid & 15) * 4;
        const int p = tid & 15;              // panel index = m0>>2
        const float ebC = __expf(b_s[63]);
        float aA[4][4] = {};
        float aB[4][4] = {};
        for (int ss = 0; ss < 64; ss += 4) {
            float4 kf0 = *(const float4*)&k_s[(ss + 0) * PAD + ((((ss + 0) >> 2) ^ k0q) << 2)];
            float4 kf1 = *(const float4*)&k_s[(ss + 1) * PAD + ((((ss + 1) >> 2) ^ k0q) << 2)];
            float4 kf2 = *(const float4*)&k_s[(ss + 2) * PAD + ((((ss + 2) >> 2) ^ k0q) << 2)];
            float4 kf3 = *(const float4*)&k_s[(ss + 3) * PAD + ((((ss + 3) >> 2) ^ k0q) << 2)];
            const float e0 = e_s[ss + 0], e1 = e_s[ss + 1];
            const float e2 = e_s[ss + 2], e3 = e_s[ss + 3];
            kf0.x *= e0; kf0.y *= e0; kf0.z *= e0; kf0.w *= e0;
            kf1.x *= e1; kf1.y *= e1; kf1.z *= e1; kf1.w *= e1;
            kf2.x *= e2; kf2.y *= e2; kf2.z *= e2; kf2.w *= e2;
            kf3.x *= e3; kf3.y *= e3; kf3.z *= e3; kf3.w *= e3;
            float4 wa0 = *(const float4*)&wk_s[(ss + 0) * PAD + m0];
            float4 wa1 = *(const float4*)&wk_s[(ss + 1) * PAD + m0];
            float4 wa2 = *(const float4*)&wk_s[(ss + 2) * PAD + m0];
            float4 wa3 = *(const float4*)&wk_s[(ss + 3) * PAD + m0];
            float4 wb0 = *(const float4*)&wv_s[(ss + 0) * PAD + m0];
            float4 wb1 = *(const float4*)&wv_s[(ss + 1) * PAD + m0];
            float4 wb2 = *(const float4*)&wv_s[(ss + 2) * PAD + m0];
            float4 wb3 = *(const float4*)&wv_s[(ss + 3) * PAD + m0];
            OUT16(aA, kf0, wa0); OUT16(aA, kf1, wa1); OUT16(aA, kf2, wa2); OUT16(aA, kf3, wa3);
            OUT16(aB, kf0, wb0); OUT16(aB, kf1, wb1); OUT16(aB, kf2, wb2); OUT16(aB, kf3, wb3);
        }

        float* Ag = Ab + (size_t)blk * 4096;
        float* Bg = Bb + (size_t)blk * 4096;
#pragma unroll
        for (int i = 0; i < 4; ++i) {
            const int kk = k0 + i;
            float4 av = make_float4(-aA[i][0], -aA[i][1], -aA[i][2], -aA[i][3]);
            if (kk - m0 == 0) av.x += ebC;
            if (kk - m0 == 1) av.y += ebC;
            if (kk - m0 == 2) av.z += ebC;
            if (kk - m0 == 3) av.w += ebC;
            *(float4*)&Ag[p * 256 + kk * 4] = av;   // panel-transposed (R11)
            *(float4*)&Bg[kk * 64 + m0] = make_float4(aB[i][0], aB[i][1], aB[i][2], aB[i][3]);
        }
    }
}

// ---------------------------------------------------------------------------
// Phase B2 (R15): serial chunk recurrence h' = A_c h + B_c. (unchanged)
// ---------------------------------------------------------------------------
__global__ __launch_bounds__(64, 1) void hrec_k(const float* __restrict__ Ab,
                                                const float* __restrict__ Bb,
                                                float* __restrict__ Hst) {
    const int blk = blockIdx.x;
    const int bh = blk & 31;          // vs-major: same-bh blocks -> same XCD
    const int vs = blk >> 5;          // 0..VS-1
    const int k = threadIdx.x;

    __shared__ __align__(16) float A_lds[2][4096];
    __shared__ __align__(16) float h_s[4][64];

#pragma unroll
    for (int j = 0; j < 4; ++j) h_s[j][k] = 0.0f;
    float h0 = 0, h1 = 0, h2 = 0, h3 = 0;

    const float* Abase = Ab + (size_t)bh * NC * 4096;
    const float* Bbase = Bb + (size_t)bh * NC * 4096 + k * 64 + vs * 4;
    float* Hbase = Hst + (size_t)bh * NC * 4096 + k * 64 + vs * 4;

    // per-lane LDS read pointers (AS3, 32-bit)
    const LAS float* rd_cur = (const LAS float*)&A_lds[0][0] + k * 4;
    const LAS float* rd_nxt = (const LAS float*)&A_lds[1][0] + k * 4;
    const LAS float* hp = (const LAS float*)&h_s[0][0];   // uniform h base

    // prologue: stage A(0) into buf0, B(0) -> register
#pragma unroll
    for (int i = 0; i < 16; ++i)
        __builtin_amdgcn_global_load_lds((const GAS unsigned int*)(Abase + i * 256 + k * 4),
                                         (LAS unsigned int*)&A_lds[0][i * 256], 16, 0, 0);
    float4 bn = *(const float4*)&Bbase[0];

#define ARD(DST, OFF) asm volatile("ds_read_b128 %0, %1 offset:" OFF \
                                   : "=v"(DST) : "v"(rd_cur))
#define HRD(DST, OFF) asm volatile("ds_read_b128 %0, %1 offset:" OFF \
                                   : "=v"(DST) : "v"(hp) : "memory")
#define FMAG(AR, H0, H1, H2, H3) \
    a0 += AR[0]*H0[0] + AR[1]*H0[1] + AR[2]*H0[2] + AR[3]*H0[3]; \
    a1 += AR[0]*H1[0] + AR[1]*H1[1] + AR[2]*H1[2] + AR[3]*H1[3]; \
    a2 += AR[0]*H2[0] + AR[1]*H2[1] + AR[2]*H2[2] + AR[3]*H2[3]; \
    a3 += AR[0]*H3[0] + AR[1]*H3[1] + AR[2]*H3[2] + AR[3]*H3[3];
#define WAIT10 asm volatile("s_waitcnt lgkmcnt(10)" ::: "memory"); \
               __builtin_amdgcn_sched_barrier(0);

#pragma unroll 1
    for (int c = 0; c < NC; ++c) {
        float4 b0 = bn;

        // chunk-start state (pre-update); fire-and-forget store
        *(float4*)&Hbase[(size_t)c * 4096] = make_float4(h0, h1, h2, h3);

        if (c + 1 < NC) {
            const float* An = Abase + (size_t)(c + 1) * 4096;
#pragma unroll
            for (int i = 0; i < 16; ++i)
                __builtin_amdgcn_global_load_lds((const GAS unsigned int*)(An + i * 256 + k * 4),
                                                 (LAS unsigned int*)(rd_nxt - (size_t)k * 4 + i * 256),
                                                 16, 0, 0);
            bn = *(const float4*)&Bbase[(size_t)(c + 1) * 4096];
            // newest 18 (H-store + 16 A-lds + 1 B) stay in flight
            asm volatile("s_waitcnt vmcnt(18)" ::: "memory");
        } else {
            asm volatile("s_waitcnt vmcnt(1)" ::: "memory");
        }
        __builtin_amdgcn_sched_barrier(0);

        f32x4 ar0, ar1, ar2, ar3, ar4, ar5, ar6, ar7;
        f32x4 ar8, ar9, ar10, ar11, ar12, ar13, ar14, ar15;
        f32x4 ha0, ha1, ha2, ha3, ha4, ha5, ha6, ha7;   // bank A (even batch)
        f32x4 hb0, hb1, hb2, hb3, hb4, hb5, hb6, hb7;   // bank B (odd batch)

        // batch0 (m4 0,1) + ar0,ar1 ; batch1 (m4 2,3) + ar2,ar3  -> 20 out
        HRD(ha0, "0");   HRD(ha1, "256"); HRD(ha2, "512"); HRD(ha3, "768");
        HRD(ha4, "16");  HRD(ha5, "272"); HRD(ha6, "528"); HRD(ha7, "784");
        ARD(ar0, "0");   ARD(ar1, "1024");
        HRD(hb0, "32");  HRD(hb1, "288"); HRD(hb2, "544"); HRD(hb3, "800");
        HRD(hb4, "48");  HRD(hb5, "304"); HRD(hb6, "560"); HRD(hb7, "816");
        ARD(ar2, "2048"); ARD(ar3, "3072");
        WAIT10   // batch0 + ar0,ar1 done; batch1+ar2,ar3 in flight

        float a0 = b0.x, a1 = b0.y, a2 = b0.z, a3 = b0.w;
        // sub0: m4 0,1
        FMAG(ar0, ha0, ha1, ha2, ha3)
        FMAG(ar1, ha4, ha5, ha6, ha7)
        HRD(ha0, "64");  HRD(ha1, "320"); HRD(ha2, "576"); HRD(ha3, "832");
        HRD(ha4, "80");  HRD(ha5, "336"); HRD(ha6, "592"); HRD(ha7, "848");
        ARD(ar4, "4096"); ARD(ar5, "5120");
        WAIT10
        // sub1: m4 2,3
        FMAG(ar2, hb0, hb1, hb2, hb3)
        FMAG(ar3, hb4, hb5, hb6, hb7)
        HRD(hb0, "96");  HRD(hb1, "352"); HRD(hb2, "608"); HRD(hb3, "864");
        HRD(hb4, "112"); HRD(hb5, "368"); HRD(hb6, "624"); HRD(hb7, "880");
        ARD(ar6, "6144"); ARD(ar7, "7168");
        WAIT10
        // sub2: m4 4,5
        FMAG(ar4, ha0, ha1, ha2, ha3)
        FMAG(ar5, ha4, ha5, ha6, ha7)
        HRD(ha0, "128"); HRD(ha1, "384"); HRD(ha2, "640"); HRD(ha3, "896");
        HRD(ha4, "144"); HRD(ha5, "400"); HRD(ha6, "656"); HRD(ha7, "912");
        ARD(ar8, "8192"); ARD(ar9, "9216");
        WAIT10
        // sub3: m4 6,7
        FMAG(ar6, hb0, hb1, hb2, hb3)
        FMAG(ar7, hb4, hb5, hb6, hb7)
        HRD(hb0, "160"); HRD(hb1, "416"); HRD(hb2, "672"); HRD(hb3, "928");
        HRD(hb4, "176"); HRD(hb5, "432"); HRD(hb6, "688"); HRD(hb7, "944");
        ARD(ar10, "10240"); ARD(ar11, "11264");
        WAIT10
        // sub4: m4 8,9
        FMAG(ar8, ha0, ha1, ha2, ha3)
        FMAG(ar9, ha4, ha5, ha6, ha7)
        HRD(ha0, "192"); HRD(ha1, "448"); HRD(ha2, "704"); HRD(ha3, "960");
        HRD(ha4, "208"); HRD(ha5, "464"); HRD(ha6, "720"); HRD(ha7, "976");
        ARD(ar12, "12288"); ARD(ar13, "13312");
        WAIT10
        // sub5: m4 10,11
        FMAG(ar10, hb0, hb1, hb2, hb3)
        FMAG(ar11, hb4, hb5, hb6, hb7)
        HRD(hb0, "224"); HRD(hb1, "480"); HRD(hb2, "736"); HRD(hb3, "992");
        HRD(hb4, "240"); HRD(hb5, "496"); HRD(hb6, "752"); HRD(hb7, "1008");
        ARD(ar14, "14336"); ARD(ar15, "15360");
        WAIT10
        // sub6: m4 12,13
        FMAG(ar12, ha0, ha1, ha2, ha3)
        FMAG(ar13, ha4, ha5, ha6, ha7)
        asm volatile("s_waitcnt lgkmcnt(0)" ::: "memory");
        __builtin_amdgcn_sched_barrier(0);
        // sub7: m4 14,15
        FMAG(ar14, hb0, hb1, hb2, hb3)
        FMAG(ar15, hb4, hb5, hb6, hb7)

        h0 = a0; h1 = a1; h2 = a2; h3 = a3;
        h_s[0][k] = h0; h_s[1][k] = h1; h_s[2][k] = h2; h_s[3][k] = h3;
        // per-wave DS ops execute in order at the LDS unit: next iteration's
        // HRD reads (memory-clobbered asm) see these writes.

        const LAS float* t = rd_cur; rd_cur = rd_nxt; rd_nxt = (LAS float*)t;
    }
#undef ARD
#undef HRD
#undef FMAG
#undef WAIT10
}

// ---------------------------------------------------------------------------
// Phase C (R20): fused wfix + QK^T/S + output + gated RMSNorm. (unchanged)
// ---------------------------------------------------------------------------
__global__ __launch_bounds__(256) void out_k(const float* __restrict__ Qc,
                                             const float* __restrict__ Kc,
                                             const float* __restrict__ Wv,
                                             const float* __restrict__ Wk,
                                             const float* __restrict__ Hst,
                                             const float* __restrict__ bcum,
                                             const float* __restrict__ gate,
                                             const float* __restrict__ rms_w,
                                             unsigned short* __restrict__ o2) {
    __shared__ __align__(16) float q_s[CL * PAD];
    __shared__ __align__(16) float s_s[CL * PAD];   // Wk, then K, then S (swizzled)
    __shared__ __align__(16) float h_s[CL * PAD];
    __shared__ __align__(16) float w_s[CL * PAD];   // Wv -> W
    __shared__ float b_s[64];

    const int blk = blockIdx.x;
    const int bh = blk >> 5;
    const int c = blk & 31;
    const int b = bh >> 4;
    const int h = bh & 15;
    const int tid = threadIdx.x;

    const int qrow = tid >> 4;          // row chunk 0..15
    const int qcol = tid & 15;          // col chunk 0..15

    if (tid < 64) b_s[tid] = bcum[(size_t)blk * 64 + tid];
    {
        const float4* Qg = (const float4*)(Qc + (size_t)blk * 4096);
        const float4* Wkg = (const float4*)(Wk + (size_t)blk * 4096);
        const float4* Hg = (const float4*)(Hst + (size_t)blk * 4096);
        const float4* Wvg = (const float4*)(Wv + (size_t)blk * 4096);
#pragma unroll
        for (int i = 0; i < 4; ++i) {
            int f = tid + i * 256;
            int t = f >> 4;
            int c4 = f & 15;
            int d = t * PAD + c4 * 4;
            int dsz = t * PAD + ((c4 ^ (t >> 2)) << 2);     // s_s swizzled
            *(float4*)&q_s[d] = Qg[f];
            *(float4*)&s_s[dsz] = Wkg[f];                   // Wk (swizzled)
            *(float4*)&h_s[d] = Hg[f];
            *(float4*)&w_s[d] = Wvg[f];                     // Wv (plain)
        }
    }
    __syncthreads();

    // Phase 0 (fused wfix): W[t][v] = Wv[t][v] − Σ_kk Wk[t][kk]·H[kk][v].
    {
        const int t0 = qrow * 4, v0 = qcol * 4;
        float acc[4][4];
#pragma unroll
        for (int i = 0; i < 4; ++i) {
            float4 wv = *(const float4*)&w_s[(t0 + i) * PAD + v0];
            acc[i][0] = wv.x; acc[i][1] = wv.y; acc[i][2] = wv.z; acc[i][3] = wv.w;
        }
        for (int kk = 0; kk < 64; kk += 4) {
            const int ka = ((kk >> 2) ^ qrow) << 2;         // swizzled Wk read
            float4 wa0 = *(const float4*)&s_s[(t0 + 0) * PAD + ka];
            float4 wa1 = *(const float4*)&s_s[(t0 + 1) * PAD + ka];
            float4 wa2 = *(const float4*)&s_s[(t0 + 2) * PAD + ka];
            float4 wa3 = *(const float4*)&s_s[(t0 + 3) * PAD + ka];
            float4 hb0 = *(const float4*)&h_s[(kk + 0) * PAD + v0];
            float4 hb1 = *(const float4*)&h_s[(kk + 1) * PAD + v0];
            float4 hb2 = *(const float4*)&h_s[(kk + 2) * PAD + v0];
            float4 hb3 = *(const float4*)&h_s[(kk + 3) * PAD + v0];
            WSUB(x, hb0); WSUB(y, hb1); WSUB(z, hb2); WSUB(w, hb3);
        }
#pragma unroll
        for (int i = 0; i < 4; ++i)
            *(float4*)&w_s[(t0 + i) * PAD + v0] =
                make_float4(acc[i][0], acc[i][1], acc[i][2], acc[i][3]);
    }
    __syncthreads();   // all Wk reads done before s_s is overwritten with K

    // stage K into s_s (swizzled)
    {
        const float4* Kg = (const float4*)(Kc + (size_t)blk * 4096);
#pragma unroll
        for (int i = 0; i < 4; ++i) {
            int f = tid + i * 256;
            int t = f >> 4;
            int c4 = f & 15;
            int dsz = t * PAD + ((c4 ^ (t >> 2)) << 2);
            *(float4*)&s_s[dsz] = Kg[f];
        }
    }
    __syncthreads();

    // Phase 1: S = (Q K^T) ⊙ exp(b_t - b_s) [s<=t], overwrite s_s
    {
        const int t0 = qrow * 4, s0 = qcol * 4;
        float acc[4][4] = {};
        for (int kk = 0; kk < 64; kk += 4) {
            const int kb = ((kk >> 2) ^ qcol) << 2;
            float4 ta0 = *(const float4*)&q_s[(t0 + 0) * PAD + kk];
            float4 ta1 = *(const float4*)&q_s[(t0 + 1) * PAD + kk];
            float4 ta2 = *(const float4*)&q_s[(t0 + 2) * PAD + kk];
            float4 ta3 = *(const float4*)&q_s[(t0 + 3) * PAD + kk];
            float4 sb0 = *(const float4*)&s_s[(s0 + 0) * PAD + kb];
            float4 sb1 = *(const float4*)&s_s[(s0 + 1) * PAD + kb];
            float4 sb2 = *(const float4*)&s_s[(s0 + 2) * PAD + kb];
            float4 sb3 = *(const float4*)&s_s[(s0 + 3) * PAD + kb];
            acc[0][0] += DOT4(ta0, sb0); acc[0][1] += DOT4(ta0, sb1);
            acc[0][2] += DOT4(ta0, sb2); acc[0][3] += DOT4(ta0, sb3);
            acc[1][0] += DOT4(ta1, sb0); acc[1][1] += DOT4(ta1, sb1);
            acc[1][2] += DOT4(ta1, sb2); acc[1][3] += DOT4(ta1, sb3);
            acc[2][0] += DOT4(ta2, sb0); acc[2][1] += DOT4(ta2, sb1);
            acc[2][2] += DOT4(ta2, sb2); acc[2][3] += DOT4(ta2, sb3);
            acc[3][0] += DOT4(ta3, sb0); acc[3][1] += DOT4(ta3, sb1);
            acc[3][2] += DOT4(ta3, sb2); acc[3][3] += DOT4(ta3, sb3);
        }
        __syncthreads();   // all Q,K reads done before overwrite
#pragma unroll
        for (int i = 0; i < 4; ++i)
#pragma unroll
            for (int j = 0; j < 4; ++j) {
                const int t = t0 + i, s = s0 + j;
                // swizzled scalar store: chunk (s>>2)=qcol XOR (t>>2)=qrow
                s_s[t * PAD + ((qcol ^ qrow) << 2) + (s & 3)] =
                    (s <= t) ? acc[i][j] * __expf(b_s[t] - b_s[s]) : 0.0f;
            }
    }
    // scale q rows by e^{b_t}  (q_s plain)
#pragma unroll
    for (int i = 0; i < 16; ++i) {
        const int e = tid + i * 256;
        const int t = e >> 6;
        q_s[t * PAD + (e & 63)] *= __expf(b_s[t]);
    }
    __syncthreads();

    // Phase 2: O = S @ W + Qs @ H, then fused gated RMSNorm -> bf16
    {
        const int t0 = qrow * 4, v0 = qcol * 4;
        float acc[4][4] = {};
        for (int ss = 0; ss < 64; ss += 4) {
            const int ks = ((ss >> 2) ^ qrow) << 2;   // s_s swizzled read
            float4 sa0 = *(const float4*)&s_s[(t0 + 0) * PAD + ks];
            float4 sa1 = *(const float4*)&s_s[(t0 + 1) * PAD + ks];
            float4 sa2 = *(const float4*)&s_s[(t0 + 2) * PAD + ks];
            float4 sa3 = *(const float4*)&s_s[(t0 + 3) * PAD + ks];
            float4 wb0 = *(const float4*)&w_s[(ss + 0) * PAD + v0];
            float4 wb1 = *(const float4*)&w_s[(ss + 1) * PAD + v0];
            float4 wb2 = *(const float4*)&w_s[(ss + 2) * PAD + v0];
            float4 wb3 = *(const float4*)&w_s[(ss + 3) * PAD + v0];
            ACC16(x, wb0); ACC16(y, wb1); ACC16(z, wb2); ACC16(w, wb3);
        }
        for (int kk = 0; kk < 64; kk += 4) {
            float4 sa0 = *(const float4*)&q_s[(t0 + 0) * PAD + kk];
            float4 sa1 = *(const float4*)&q_s[(t0 + 1) * PAD + kk];
            float4 sa2 = *(const float4*)&q_s[(t0 + 2) * PAD + kk];
            float4 sa3 = *(const float4*)&q_s[(t0 + 3) * PAD + kk];
            float4 wb0 = *(const float4*)&h_s[(kk + 0) * PAD + v0];
            float4 wb1 = *(const float4*)&h_s[(kk + 1) * PAD + v0];
            float4 wb2 = *(const float4*)&h_s[(kk + 2) * PAD + v0];
            float4 wb3 = *(const float4*)&h_s[(kk + 3) * PAD + v0];
            ACC16(x, wb0); ACC16(y, wb1); ACC16(z, wb2); ACC16(w, wb3);
        }

        // fused gated RMSNorm epilogue (R19)
        const float4 rw = *(const float4*)&rms_w[v0];
#pragma unroll
        for (int i = 0; i < 4; ++i) {
            float ss2 = acc[i][0] * acc[i][0] + acc[i][1] * acc[i][1]
                      + acc[i][2] * acc[i][2] + acc[i][3] * acc[i][3];
            ss2 += __shfl_xor(ss2, 1);
            ss2 += __shfl_xor(ss2, 2);
            ss2 += __shfl_xor(ss2, 4);
            ss2 += __shfl_xor(ss2, 8);
            const float r = rsqrtf(ss2 * (1.0f / 64.0f) + 1e-5f);
            const int t = c * CL + t0 + i;
            const size_t row = (size_t)b * TT + t;
            const float4 gt = *(const float4*)&gate[row * HD + h * DK + v0];
            u16x4 o;
            o[0] = f2bf(acc[i][0] * r * rw.x * siluf_(gt.x));
            o[1] = f2bf(acc[i][1] * r * rw.y * siluf_(gt.y));
            o[2] = f2bf(acc[i][2] * r * rw.z * siluf_(gt.z));
            o[3] = f2bf(acc[i][3] * r * rw.w * siluf_(gt.w));
            *(u16x4*)&o2[row * HD + h * DK + v0] = o;
        }
    }
}

// ---------------------------------------------------------------------------
extern "C" void kernel_launch(void* const* d_in, const int* in_sizes, int n_in,
                              void* d_out, int out_size, void* d_ws, size_t ws_size,
                              hipStream_t stream) {
    (void)in_sizes; (void)n_in; (void)out_size; (void)ws_size;

    const float* x       = (const float*)d_in[0];
    const float* Wq      = (const float*)d_in[1];
    const float* Wk_     = (const float*)d_in[2];
    const float* Wv_     = (const float*)d_in[3];
    const float* Wa      = (const float*)d_in[4];
    const float* Wb      = (const float*)d_in[5];
    const float* Wg      = (const float*)d_in[6];
    const float* Wo      = (const float*)d_in[7];
    const float* conv_q  = (const float*)d_in[8];
    const float* conv_k  = (const float*)d_in[9];
    const float* conv_v  = (const float*)d_in[10];
    const float* A_log   = (const float*)d_in[11];
    const float* dt_bias = (const float*)d_in[12];
    const float* rms_w   = (const float*)d_in[13];
    float* out = (float*)d_out;

    float* ws = (float*)d_ws;
    const size_t NTOK = (size_t)BB * TT;     // 4096
    const size_t BIG = NTOK * HD;            // 4 Mi floats

    float* q_pre = ws + 0 * BIG;
    float* k_pre = ws + 1 * BIG;
    float* v_pre = ws + 2 * BIG;
    float* gatep = ws + 3 * BIG;
    float* Qc    = ws + 4 * BIG;
    float* Kc    = ws + 5 * BIG;
    float* gbuf  = ws + 6 * BIG;
    float* bbuf  = gbuf + NTOK * HH;
    float* bcumb = bbuf + NTOK * HH;

    // bf16 buffers after the fp32 region (wqt..wgt contiguous = fused B matrix)
    unsigned short* xb  = (unsigned short*)(bcumb + NTOK * HH);
    unsigned short* wqt = xb + (size_t)NTOK * DD;
    unsigned short* wkt = wqt + (size_t)DD * HD;
    unsigned short* wvt = wkt + (size_t)DD * HD;
    unsigned short* wgt = wvt + (size_t)DD * HD;
    unsigned short* wot = wgt + (size_t)DD * HD;

    // fp32 buffers after bf16 region: Bb + Hst + Wab_t + Wv/Wk (R23)
    float* Bbuf = (float*)(wot + (size_t)DD * HD);
    float* HstB = Bbuf + BIG;
    float* Wabt = HstB + BIG;
    // R23 race fix: prep_k now READS q_pre/k_pre (fused conv) while writing
    // Wv/Wk — the old q_pre/k_pre aliasing is a cross-block RAW race.
    // Dedicated buffers after Wabt (+32 MB workspace).
    float* Wvb  = Wabt + 32 * DD;
    float* Wkb  = Wvb + BIG;

    // aliases (stream-ordered lifetimes):
    // A buffer aliases the xb/wqt region (dead after gemm_qkvg_k).
    float* Abuf   = (float*)xb;
    // o2 (bf16 output of fused out_k) aliases Abuf (dead after hrec_k);
    // disjoint from wot and from Qc/Kc (still read).
    unsigned short* o2b = (unsigned short*)Abuf;

    // casts
    castx_k<<<(int)(NTOK * DD / (256 * 8)), 256, 0, stream>>>(x, xb);
    dim3 tg(16, 16);
    castw_k<<<tg, 256, 0, stream>>>(Wq, wqt);
    castw_k<<<tg, 256, 0, stream>>>(Wk_, wkt);
    castw_k<<<tg, 256, 0, stream>>>(Wv_, wvt);
    castw_k<<<tg, 256, 0, stream>>>(Wg, wgt);
    castw_k<<<tg, 256, 0, stream>>>(Wo, wot);
    tw_k<<<32, 256, 0, stream>>>(Wa, Wb, Wabt);

    // fused QKVG projection: 256 blocks x 512 threads (256^2 8-phase, R13)
    gemm_qkvg_k<<<256, 512, 0, stream>>>(xb, wqt, q_pre, k_pre, v_pre, gatep);

    gbeta_k<<<(int)(NTOK / 8), 256, 0, stream>>>(x, Wabt, A_log, dt_bias, gbuf, bbuf);

    // prep_k (R23): absorbs stage_k — computes Q/K conv + cumsum itself,
    // writes Qc/Kc/bcumb, solves, and emits A_c/B_c. Wv/Wk dedicated.
    prep_k<<<BB * HH * NC, 256, 0, stream>>>(q_pre, k_pre, v_pre,
                                             conv_q, conv_k, conv_v,
                                             gbuf, bbuf,
                                             Qc, Kc, bcumb,
                                             Wvb, Wkb, Abuf, Bbuf);

    hrec_k<<<BB * HH * VS, 64, 0, stream>>>(Abuf, Bbuf, HstB);

    // out_k fuses wfix + QK^T/S + output + gated RMSNorm (R20)
    out_k<<<BB * HH * NC, 256, 0, stream>>>(Qc, Kc, Wvb, Wkb, HstB, bcumb,
                                            gatep, rms_w, o2b);

    gemm_bf16_k<<<dim3(HD / 128, NTOK / 128), 256, 0, stream>>>(o2b, wot, out,
                                                                (int)NTOK, HD, DD);
}